// Round 5
// baseline (534.683 us; speedup 1.0000x reference)
//
#include <hip/hip_runtime.h>
#include <cstdint>

typedef __bf16 bf16;
typedef __bf16 bf16x8 __attribute__((ext_vector_type(8)));
typedef float f32x4 __attribute__((ext_vector_type(4)));

#define AS1 __attribute__((address_space(1)))
#define AS3 __attribute__((address_space(3)))

// Async global->LDS, 16B per lane. LDS dest must be wave-uniform base;
// HW writes lane i at base + i*16 (m97/m104 semantics).
__device__ __forceinline__ void load16_lds(const void* gp, void* lds_base_wave_uniform) {
    __builtin_amdgcn_global_load_lds((AS1 void*)((void*)gp),
                                     (AS3 void*)lds_base_wave_uniform, 16, 0, 0);
}

// ---------------------------------------------------------------------------
// fp32 -> (hi, lo) bf16 planes.
// ---------------------------------------------------------------------------
__global__ __launch_bounds__(256) void split_planes(const float* __restrict__ src,
                                                    bf16* __restrict__ h,
                                                    bf16* __restrict__ l, int n)
{
    const int stride = gridDim.x * blockDim.x;
    for (int i = blockIdx.x * blockDim.x + threadIdx.x; i < n; i += stride) {
        float v = src[i];
        bf16 hh = (bf16)v;
        h[i] = hh;
        l[i] = (bf16)(v - (float)hh);
    }
}

// ---------------------------------------------------------------------------
// LN1 -> xres (fp32, x rows only); LN_att(LN1) -> h hi/lo planes (all rows).
// ---------------------------------------------------------------------------
__global__ __launch_bounds__(256) void prep_ln(
    const float* __restrict__ x, const float* __restrict__ memory,
    const float* __restrict__ g1, const float* __restrict__ b1,
    const float* __restrict__ ga, const float* __restrict__ ba,
    float* __restrict__ xres, bf16* __restrict__ hH, bf16* __restrict__ hL)
{
    const int row = blockIdx.x;            // 0..6271
    const int b = row / 1568, l = row - b * 1568;
    const float* src = (l < 784) ? (memory + ((size_t)b * 1024 + l) * 768)
                                 : (x + ((size_t)b * 784 + (l - 784)) * 768);
    const int t = threadIdx.x, lane = t & 63, wv = t >> 6;
    __shared__ float red[8];

    float v[3];
#pragma unroll
    for (int i = 0; i < 3; ++i) v[i] = src[i * 256 + t];

    float s = v[0] + v[1] + v[2];
    float s2 = v[0] * v[0] + v[1] * v[1] + v[2] * v[2];
#pragma unroll
    for (int off = 1; off < 64; off <<= 1) { s += __shfl_xor(s, off, 64); s2 += __shfl_xor(s2, off, 64); }
    if (lane == 0) { red[wv] = s; red[4 + wv] = s2; }
    __syncthreads();
    s = red[0] + red[1] + red[2] + red[3];
    s2 = red[4] + red[5] + red[6] + red[7];
    float mu = s * (1.0f / 768.0f);
    float var = s2 * (1.0f / 768.0f) - mu * mu;
    float rs = rsqrtf(fmaxf(var, 0.0f) + 1e-5f);

    float w[3];
#pragma unroll
    for (int i = 0; i < 3; ++i) {
        int c = i * 256 + t;
        w[i] = (v[i] - mu) * rs * g1[c] + b1[c];
    }
    if (l >= 784) {
        float* xr = xres + ((size_t)b * 784 + (l - 784)) * 768;
#pragma unroll
        for (int i = 0; i < 3; ++i) xr[i * 256 + t] = w[i];
    }

    s = w[0] + w[1] + w[2];
    s2 = w[0] * w[0] + w[1] * w[1] + w[2] * w[2];
#pragma unroll
    for (int off = 1; off < 64; off <<= 1) { s += __shfl_xor(s, off, 64); s2 += __shfl_xor(s2, off, 64); }
    __syncthreads();
    if (lane == 0) { red[wv] = s; red[4 + wv] = s2; }
    __syncthreads();
    s = red[0] + red[1] + red[2] + red[3];
    s2 = red[4] + red[5] + red[6] + red[7];
    float mu2 = s * (1.0f / 768.0f);
    float var2 = s2 * (1.0f / 768.0f) - mu2 * mu2;
    float rs2 = rsqrtf(fmaxf(var2, 0.0f) + 1e-5f);

    bf16* hh_ = hH + (size_t)row * 768;
    bf16* hl_ = hL + (size_t)row * 768;
#pragma unroll
    for (int i = 0; i < 3; ++i) {
        int c = i * 256 + t;
        float hv = (w[i] - mu2) * rs2 * ga[c] + ba[c];
        bf16 hvh = (bf16)hv;
        hh_[c] = hvh;
        hl_[c] = (bf16)(hv - (float)hvh);
    }
}

// ---------------------------------------------------------------------------
// Plane GEMM with async global->LDS staging (width 16, m97 single-buffer
// structure -- the measured-best schedule; R3's explicit dbuf regressed).
// vs R2:
//  * chunk-major LDS window layout: each wave's 16row x 32col window stored
//    [kc][r] so both the HW staging write AND the fragment ds_read_b128 are
//    fully linear 1024B per wave -> zero bank conflicts (was 8-way).
//  * bijective XCD chunking (m204): each XCD gets a contiguous grid span
//    (ORD=0 row-chunks for A-heavy, ORD=1 col-chunks for B-heavy) -> operand
//    panels stay in the XCD-private L2.
// C = A*B^T; 128x128 tile, BK=32, 4 waves x 64x64. Split-K via gridDim.z.
// MODE 0: planes out. 1: fp32 partial -> Cf + z*M*N. 2: silu planes out.
// 3: atomic fp32 += into prefilled Cf.
// ---------------------------------------------------------------------------
template <int MODE, int ORD>
__global__ __launch_bounds__(256, 2) void gemm_pl(
    const bf16* __restrict__ Ah, const bf16* __restrict__ Al,
    const bf16* __restrict__ Bh, const bf16* __restrict__ Bl,
    int M, int N, int K,
    const float* __restrict__ bias, const float* __restrict__ resid,
    float* __restrict__ Cf, bf16* __restrict__ Ch, bf16* __restrict__ Cl)
{
    __shared__ __align__(16) bf16 Ahs[128 * 32], Als[128 * 32];
    __shared__ __align__(16) bf16 Bhs[128 * 32], Bls[128 * 32];
    const int t = threadIdx.x, lane = t & 63, wv = t >> 6;

    // ---- bijective XCD chunking (m204) ----
    const int nx = gridDim.x, ny = gridDim.y;
    int orig = blockIdx.x + nx * blockIdx.y;
    int nwg = nx * ny;
    int q = nwg >> 3, rr8 = nwg & 7;
    int xcd = orig & 7, pos = orig >> 3;
    int wgid = (xcd < rr8 ? xcd * (q + 1) : rr8 * (q + 1) + (xcd - rr8) * q) + pos;
    int bx, by;
    if (ORD == 0) { bx = wgid % nx; by = wgid / nx; }   // row chunks (A-heavy)
    else          { by = wgid % ny; bx = wgid / ny; }   // col chunks (B-heavy)

    const int row0 = by * 128, col0 = bx * 128;
    const int ro = (wv >> 1) * 64, co = (wv & 1) * 64;
    const int Kc = K / gridDim.z;
    const int kbeg = blockIdx.z * Kc, kend = kbeg + Kc;
    const int l15 = lane & 15, q8 = lane >> 4;

    f32x4 acc[4][4] = {};

    for (int k0 = kbeg; k0 < kend; k0 += 32) {
#pragma unroll
        for (int it = 0; it < 2; ++it) {
            // chunk-major window: lane = q8*16 + l15 -> [kc][r_loc]
            int rr = it * 64 + wv * 16 + l15;      // tile row this lane fetches
            int kc8 = q8 * 8;                      // k-chunk this lane fetches
            int ra = row0 + rr; if (ra >= M) ra = M - 1;
            size_t oa = (size_t)ra * K + k0 + kc8;
            size_t ob = (size_t)(col0 + rr) * K + k0 + kc8;
            // wave-uniform LDS base (lane offset applied by HW: +lane*16B)
            size_t lb = (size_t)(it * 256 + wv * 64) * 8;
            load16_lds(Ah + oa, Ahs + lb);
            load16_lds(Al + oa, Als + lb);
            load16_lds(Bh + ob, Bhs + lb);
            load16_lds(Bl + ob, Bls + lb);
        }
        asm volatile("s_waitcnt vmcnt(0)" ::: "memory");
        __syncthreads();
        bf16x8 ah[4], al[4], bh[4], bl[4];
#pragma unroll
        for (int i = 0; i < 4; ++i) {
            // window (ro>>4)+i holds rows [win*16, win*16+16) chunk-major
            int o = ((ro >> 4) + i) * 512 + q8 * 128 + l15 * 8;
            ah[i] = *(const bf16x8*)&Ahs[o];
            al[i] = *(const bf16x8*)&Als[o];
        }
#pragma unroll
        for (int j = 0; j < 4; ++j) {
            int o = ((co >> 4) + j) * 512 + q8 * 128 + l15 * 8;
            bh[j] = *(const bf16x8*)&Bhs[o];
            bl[j] = *(const bf16x8*)&Bls[o];
        }
#pragma unroll
        for (int i = 0; i < 4; ++i)
#pragma unroll
            for (int j = 0; j < 4; ++j) {
                acc[i][j] = __builtin_amdgcn_mfma_f32_16x16x32_bf16(al[i], bh[j], acc[i][j], 0, 0, 0);
                acc[i][j] = __builtin_amdgcn_mfma_f32_16x16x32_bf16(ah[i], bl[j], acc[i][j], 0, 0, 0);
                acc[i][j] = __builtin_amdgcn_mfma_f32_16x16x32_bf16(ah[i], bh[j], acc[i][j], 0, 0, 0);
            }
        __syncthreads();
    }

    const size_t zoff = (size_t)blockIdx.z * M * N;
#pragma unroll
    for (int i = 0; i < 4; ++i)
#pragma unroll
        for (int j = 0; j < 4; ++j)
#pragma unroll
            for (int r = 0; r < 4; ++r) {
                int row = row0 + ro + i * 16 + (lane >> 4) * 4 + r;
                int col = col0 + co + j * 16 + (lane & 15);
                if (row >= M) continue;
                float v = acc[i][j][r];
                size_t idx = (size_t)row * N + col;
                if (MODE == 0) {
                    bf16 hh = (bf16)v;
                    Ch[idx] = hh; Cl[idx] = (bf16)(v - (float)hh);
                } else if (MODE == 1) {
                    Cf[zoff + idx] = v;               // partial, bias added later
                } else if (MODE == 2) {
                    v += bias[col];
                    v = v / (1.0f + __expf(-v));
                    bf16 hh = (bf16)v;
                    Ch[idx] = hh; Cl[idx] = (bf16)(v - (float)hh);
                } else {
                    unsafeAtomicAdd(&Cf[idx], v);     // HW f32 atomic, prefilled dest
                }
            }
}

// ---------------------------------------------------------------------------
// Flash attention, pipelined. Grid: x = hh + 12*b (48), y = w*4+g (16).
// Deferred softmax (bounded logits), single barrier per K-tile, swizzled K
// via pre-swizzled global_load_lds source, V reg-prefetch + 2-way-bank
// transposed write.
// ---------------------------------------------------------------------------
__global__ __launch_bounds__(256, 3) void attn_kernel(
    const bf16* __restrict__ qh_, const bf16* __restrict__ ql_,
    bf16* __restrict__ oh_, bf16* __restrict__ ol_)
{
    const int hh = blockIdx.x % 12, b = blockIdx.x / 12;
    const int w = blockIdx.y >> 2, g = blockIdx.y & 3;
    const int kmax = (5 + w) * 196, nkt = (kmax + 31) / 32;
    const int t = threadIdx.x, lane = t & 63, wv = t >> 6;
    const int tile = g * 4 + wv;                  // 0..15; >12 idle (wave-uniform)
    const int l15 = lane & 15, q8 = lane >> 4;

    __shared__ __align__(16) bf16 Ks_h[2][32 * 64], Ks_l[2][32 * 64];
    __shared__ __align__(16) bf16 Vt_h[2][64 * 40];
    __shared__ __align__(16) bf16 Pl_h[4][16 * 40];

    const size_t bbase = (size_t)b * 1568 * 2304;

    // staging geometry: thread t covers K/V row srow, col chunk sc8.
    const int srow = t >> 3;                      // 0..31 (wave wv: rows wv*8..+7)
    const int sc8 = (t & 7) * 8;
    // K: LDS dest is linear (global_load_lds), so pre-swizzle the SOURCE col.
    const int scsrc = sc8 ^ ((srow & 7) * 8);

    // Q fragments (held in registers for the whole kernel)
    int tcl = tile > 12 ? 12 : tile;
    int qr0 = tcl * 16 + l15; if (qr0 > 195) qr0 = 195;
    const size_t qoff = bbase + (size_t)(784 + w * 196 + qr0) * 2304 + hh * 64 + q8 * 8;
    bf16x8 qfh[2], qfl[2];
#pragma unroll
    for (int p = 0; p < 2; ++p) {
        qfh[p] = *(const bf16x8*)(qh_ + qoff + p * 32);
        qfl[p] = *(const bf16x8*)(ql_ + qoff + p * 32);
    }

    float l_i[4] = {0.f, 0.f, 0.f, 0.f};
    f32x4 oacc[4];
#pragma unroll
    for (int nd = 0; nd < 4; ++nd) oacc[nd] = f32x4{0.f, 0.f, 0.f, 0.f};

    // issue staging for K-tile kt2 into buffer bufn; V -> vreg (not yet in LDS)
    auto stage_issue = [&](int kt2, int bufn, bf16x8& vreg) {
        const size_t kb = bbase + (size_t)(kt2 * 32 + srow) * 2304 + 768 + (size_t)hh * 64;
        load16_lds(qh_ + kb + scsrc, &Ks_h[bufn][wv * 512]);
        load16_lds(ql_ + kb + scsrc, &Ks_l[bufn][wv * 512]);
        vreg = *(const bf16x8*)(qh_ + kb + 768 + sc8);
    };
    // transposed V write, key-XOR swizzled (2-way banks instead of 16-way)
    auto write_V = [&](int bufn, const bf16x8& vreg) {
#pragma unroll
        for (int j = 0; j < 8; ++j) {
            int d = sc8 + j;
            int keyx = srow ^ (((d >> 3) & 3) * 8);
            Vt_h[bufn][d * 40 + keyx] = vreg[j];
        }
    };

    // ---- prologue: stage tile 0 into buffer 0
    {
        bf16x8 v0;
        stage_issue(0, 0, v0);
        write_V(0, v0);                            // data dep inserts vmcnt wait
        asm volatile("s_waitcnt vmcnt(0)" ::: "memory");
        __syncthreads();
    }

    const float CEXP = 0.18033688011112042f;       // 0.125 * log2(e)

    for (int kt = 0; kt < nkt; ++kt) {
        const int cur = kt & 1, nxt = cur ^ 1;
        int kt2 = kt + 1; if (kt2 >= nkt) kt2 = nkt - 1;   // clamp (no OOB)
        bf16x8 vnext;
        stage_issue(kt2, nxt, vnext);              // overlaps with compute below

        if (tile <= 12) {
            bf16x8 kfh[2][2], kfl[2][2], vth[4];
#pragma unroll
            for (int nb = 0; nb < 2; ++nb)
#pragma unroll
                for (int p = 0; p < 2; ++p) {
                    int row = nb * 16 + l15;
                    int c = (p * 32 + q8 * 8) ^ ((row & 7) * 8);
                    kfh[nb][p] = *(const bf16x8*)&Ks_h[cur][row * 64 + c];
                    kfl[nb][p] = *(const bf16x8*)&Ks_l[cur][row * 64 + c];
                }
#pragma unroll
            for (int nd = 0; nd < 4; ++nd) {
                int d = nd * 16 + l15;
                int k8 = (q8 * 8) ^ (((d >> 3) & 3) * 8);
                vth[nd] = *(const bf16x8*)&Vt_h[cur][d * 40 + k8];
            }

            // QK^T: 4 independent depth-3 MFMA chains
            f32x4 s0a = {0.f,0.f,0.f,0.f}, s0b = {0.f,0.f,0.f,0.f};
            f32x4 s1a = {0.f,0.f,0.f,0.f}, s1b = {0.f,0.f,0.f,0.f};
            s0a = __builtin_amdgcn_mfma_f32_16x16x32_bf16(qfl[0], kfh[0][0], s0a, 0, 0, 0);
            s1a = __builtin_amdgcn_mfma_f32_16x16x32_bf16(qfl[0], kfh[1][0], s1a, 0, 0, 0);
            s0b = __builtin_amdgcn_mfma_f32_16x16x32_bf16(qfl[1], kfh[0][1], s0b, 0, 0, 0);
            s1b = __builtin_amdgcn_mfma_f32_16x16x32_bf16(qfl[1], kfh[1][1], s1b, 0, 0, 0);
            s0a = __builtin_amdgcn_mfma_f32_16x16x32_bf16(qfh[0], kfl[0][0], s0a, 0, 0, 0);
            s1a = __builtin_amdgcn_mfma_f32_16x16x32_bf16(qfh[0], kfl[1][0], s1a, 0, 0, 0);
            s0b = __builtin_amdgcn_mfma_f32_16x16x32_bf16(qfh[1], kfl[0][1], s0b, 0, 0, 0);
            s1b = __builtin_amdgcn_mfma_f32_16x16x32_bf16(qfh[1], kfl[1][1], s1b, 0, 0, 0);
            s0a = __builtin_amdgcn_mfma_f32_16x16x32_bf16(qfh[0], kfh[0][0], s0a, 0, 0, 0);
            s1a = __builtin_amdgcn_mfma_f32_16x16x32_bf16(qfh[0], kfh[1][0], s1a, 0, 0, 0);
            s0b = __builtin_amdgcn_mfma_f32_16x16x32_bf16(qfh[1], kfh[0][1], s0b, 0, 0, 0);
            s1b = __builtin_amdgcn_mfma_f32_16x16x32_bf16(qfh[1], kfh[1][1], s1b, 0, 0, 0);
            f32x4 s0 = s0a + s0b, s1 = s1a + s1b;

            // deferred softmax: p = exp(S/8), no max subtraction, no rescale
            const int key0 = kt * 32 + l15;
            const bool m0 = (key0 >= kmax), m1 = (key0 + 16 >= kmax);
#pragma unroll
            for (int r = 0; r < 4; ++r) {
                float p0 = m0 ? 0.0f : exp2f(s0[r] * CEXP);
                float p1 = m1 ? 0.0f : exp2f(s1[r] * CEXP);
                l_i[r] += p0 + p1;
                int pr = q8 * 4 + r;
                Pl_h[wv][pr * 40 + l15] = (bf16)p0;
                Pl_h[wv][pr * 40 + 16 + l15] = (bf16)p1;
            }
            asm volatile("s_waitcnt lgkmcnt(0)" ::: "memory");   // wave-private Pl RAW
            bf16x8 pfh = *(const bf16x8*)&Pl_h[wv][l15 * 40 + q8 * 8];
#pragma unroll
            for (int nd = 0; nd < 4; ++nd)
                oacc[nd] = __builtin_amdgcn_mfma_f32_16x16x32_bf16(pfh, vth[nd], oacc[nd], 0, 0, 0);
        }

        write_V(nxt, vnext);                       // waits vmcnt for vnext only here
        asm volatile("s_waitcnt vmcnt(0)" ::: "memory");
        __syncthreads();
    }

    if (tile <= 12) {
#pragma unroll
        for (int r = 0; r < 4; ++r) {
            float s = l_i[r];
#pragma unroll
            for (int off = 1; off < 16; off <<= 1) s += __shfl_xor(s, off, 64);
            int qr = tile * 16 + q8 * 4 + r;
            if (qr >= 196) continue;
            float inv = 1.0f / s;
            size_t row = (size_t)b * 784 + w * 196 + qr;
#pragma unroll
            for (int nd = 0; nd < 4; ++nd) {
                float ov = oacc[nd][r] * inv;
                bf16 oh = (bf16)ov;
                size_t idx = row * 768 + hh * 64 + nd * 16 + l15;
                oh_[idx] = oh;
                ol_[idx] = (bf16)(ov - (float)oh);
            }
        }
    }
}

// ---------------------------------------------------------------------------
// y = xres + p0 + p1 + b_out (fp32), y2 = LN2(y) planes, dout = y + b2ff
// (prefill for the atomic split-K w2 GEMM). Block per x-row (3136).
// ---------------------------------------------------------------------------
__global__ __launch_bounds__(256) void ln2_resid(
    const float* __restrict__ xres, const float* __restrict__ attP,
    const float* __restrict__ bo,
    const float* __restrict__ g2, const float* __restrict__ b2,
    const float* __restrict__ b2ff,
    float* __restrict__ y, bf16* __restrict__ y2H, bf16* __restrict__ y2L,
    float* __restrict__ dout)
{
    const int row = blockIdx.x;
    const size_t MN = (size_t)3136 * 768;
    const float* xr = xres + (size_t)row * 768;
    const float* a0 = attP + (size_t)row * 768;
    const float* a1 = attP + MN + (size_t)row * 768;
    const int t = threadIdx.x, lane = t & 63, wv = t >> 6;
    __shared__ float red[8];

    float v[3];
    float* yr = y + (size_t)row * 768;
    float* dr = dout + (size_t)row * 768;
#pragma unroll
    for (int i = 0; i < 3; ++i) {
        int c = i * 256 + t;
        v[i] = xr[c] + a0[c] + a1[c] + bo[c];
        yr[c] = v[i];
        dr[c] = v[i] + b2ff[c];
    }
    float s = v[0] + v[1] + v[2];
    float s2 = v[0] * v[0] + v[1] * v[1] + v[2] * v[2];
#pragma unroll
    for (int off = 1; off < 64; off <<= 1) { s += __shfl_xor(s, off, 64); s2 += __shfl_xor(s2, off, 64); }
    if (lane == 0) { red[wv] = s; red[4 + wv] = s2; }
    __syncthreads();
    s = red[0] + red[1] + red[2] + red[3];
    s2 = red[4] + red[5] + red[6] + red[7];
    float mu = s * (1.0f / 768.0f);
    float var = s2 * (1.0f / 768.0f) - mu * mu;
    float rs = rsqrtf(fmaxf(var, 0.0f) + 1e-5f);

    bf16* yh = y2H + (size_t)row * 768;
    bf16* yl = y2L + (size_t)row * 768;
#pragma unroll
    for (int i = 0; i < 3; ++i) {
        int c = i * 256 + t;
        float yv = (v[i] - mu) * rs * g2[c] + b2[c];
        bf16 yvh = (bf16)yv;
        yh[c] = yvh;
        yl[c] = (bf16)(yv - (float)yvh);
    }
}

// ---------------------------------------------------------------------------
extern "C" void kernel_launch(void* const* d_in, const int* in_sizes, int n_in,
                              void* d_out, int out_size, void* d_ws, size_t ws_size,
                              hipStream_t stream)
{
    (void)in_sizes; (void)n_in; (void)out_size; (void)ws_size;
    const float* x        = (const float*)d_in[0];
    const float* memory   = (const float*)d_in[1];
    const float* ln_att_g = (const float*)d_in[2];
    const float* ln_att_b = (const float*)d_in[3];
    const float* w_qkv    = (const float*)d_in[4];
    const float* w_out    = (const float*)d_in[5];
    const float* b_out    = (const float*)d_in[6];
    const float* ln1_g    = (const float*)d_in[7];
    const float* ln1_b    = (const float*)d_in[8];
    const float* ln2_g    = (const float*)d_in[9];
    const float* ln2_b    = (const float*)d_in[10];
    const float* w1       = (const float*)d_in[11];
    const float* b1       = (const float*)d_in[12];
    const float* w2       = (const float*)d_in[13];
    const float* b2       = (const float*)d_in[14];

    // ---- workspace layout (~109.7 MiB, same footprint) ----
    char* ws = (char*)d_ws;
    const size_t SZF  = (size_t)3136 * 768 * 4;
    const size_t SZP  = (size_t)3136 * 768 * 2;
    const size_t SZHP = (size_t)6272 * 768 * 2;
    const size_t SZQP = (size_t)6272 * 2304 * 2;
    const size_t SZFP = (size_t)3136 * 3072 * 2;

    float* xres = (float*)(ws);
    bf16* hH  = (bf16*)(ws + SZF);
    bf16* hL  = (bf16*)(ws + SZF + SZHP);
    bf16* aoH = (bf16*)(ws + SZF);
    bf16* aoL = (bf16*)(ws + SZF + SZP);
    bf16* y2H = (bf16*)(ws + SZF);
    bf16* y2L = (bf16*)(ws + SZF + SZP);
    const size_t OQ = SZF + 2 * SZHP;
    bf16* qkvH = (bf16*)(ws + OQ);
    bf16* qkvL = (bf16*)(ws + OQ + SZQP);
    float* y    = (float*)(ws + OQ);
    float* attP = (float*)(ws + OQ + SZF);   // 2 partials (dead qkv region; ffH overwrites later)
    bf16* ffH  = (bf16*)(ws + OQ + SZF);
    bf16* ffL  = (bf16*)(ws + OQ + SZF + SZFP);
    const size_t OW = OQ + 2 * SZQP;
    bf16* wqH = (bf16*)(ws + OW);
    bf16* wqL = (bf16*)(ws + OW + 3538944);
    bf16* woH = (bf16*)(ws + OW + 2 * 3538944);
    bf16* woL = (bf16*)(ws + OW + 2 * 3538944 + 1179648);
    bf16* w1H = (bf16*)(ws + OW + 2 * 3538944 + 2 * 1179648);
    bf16* w1L = (bf16*)(ws + OW + 2 * 3538944 + 2 * 1179648 + 4718592);
    bf16* w2H = (bf16*)(ws + OW + 2 * 3538944 + 2 * 1179648 + 2 * 4718592);
    bf16* w2L = (bf16*)(ws + OW + 2 * 3538944 + 2 * 1179648 + 3 * 4718592);

    // 0) pre-split weights into hi/lo planes
    split_planes<<<512, 256, 0, stream>>>(w_qkv, wqH, wqL, 1769472);
    split_planes<<<512, 256, 0, stream>>>(w_out, woH, woL, 589824);
    split_planes<<<512, 256, 0, stream>>>(w1,    w1H, w1L, 2359296);
    split_planes<<<512, 256, 0, stream>>>(w2,    w2H, w2L, 2359296);

    // 1) LN1 + LN_att
    prep_ln<<<6272, 256, 0, stream>>>(x, memory, ln1_g, ln1_b, ln_att_g, ln_att_b, xres, hH, hL);

    // 2) qkv planes = h @ w_qkv^T  (M=6272, N=2304, K=768) — row-chunked XCDs
    gemm_pl<0, 0><<<dim3(18, 49), 256, 0, stream>>>(hH, hL, wqH, wqL, 6272, 2304, 768,
                                                    nullptr, nullptr, nullptr, qkvH, qkvL);

    // 3) attention  (grid: x = hh+12*b, y = w*4+g  -> XCD-local K/V sharing)
    attn_kernel<<<dim3(48, 16), 256, 0, stream>>>(qkvH, qkvL, aoH, aoL);

    // 4) att partials = ao @ w_out^T  (M=3136, N=768, K=768, split-K=2) — row-chunked
    gemm_pl<1, 0><<<dim3(6, 25, 2), 256, 0, stream>>>(aoH, aoL, woH, woL, 3136, 768, 768,
                                                      nullptr, nullptr, attP, nullptr, nullptr);

    // 5) y = xres + p0 + p1 + b_out ; y2 planes = LN2(y) ; dout prefill = y + b2
    ln2_resid<<<3136, 256, 0, stream>>>(xres, attP, b_out, ln2_g, ln2_b, b2,
                                        y, y2H, y2L, (float*)d_out);

    // 6) ff planes = silu(y2 @ w1^T + b1)  (M=3136, N=3072, K=768) — col-chunked (w1-heavy)
    gemm_pl<2, 1><<<dim3(24, 25), 256, 0, stream>>>(y2H, y2L, w1H, w1L, 3136, 3072, 768,
                                                    b1, nullptr, nullptr, ffH, ffL);

    // 7) d_out += ff @ w2^T  (M=3136, N=768, K=3072, split-K=4, atomic) — row-chunked
    gemm_pl<3, 0><<<dim3(6, 25, 4), 256, 0, stream>>>(ffH, ffL, w2H, w2L, 3136, 768, 3072,
                                                      nullptr, nullptr, (float*)d_out, nullptr, nullptr);
}

// Round 6
// 466.361 us; speedup vs baseline: 1.1465x; 1.1465x over previous
//
#include <hip/hip_runtime.h>
#include <cstdint>

typedef __bf16 bf16;
typedef __bf16 bf16x8 __attribute__((ext_vector_type(8)));
typedef float f32x4 __attribute__((ext_vector_type(4)));

#define AS1 __attribute__((address_space(1)))
#define AS3 __attribute__((address_space(3)))

// Async global->LDS, 16B per lane. LDS dest must be wave-uniform base;
// HW writes lane i at base + i*16 (m97/m104 semantics).
__device__ __forceinline__ void load16_lds(const void* gp, void* lds_base_wave_uniform) {
    __builtin_amdgcn_global_load_lds((AS1 void*)((void*)gp),
                                     (AS3 void*)lds_base_wave_uniform, 16, 0, 0);
}

// ---------------------------------------------------------------------------
// fp32 -> (hi, lo) bf16 planes.
// ---------------------------------------------------------------------------
__global__ __launch_bounds__(256) void split_planes(const float* __restrict__ src,
                                                    bf16* __restrict__ h,
                                                    bf16* __restrict__ l, int n)
{
    const int stride = gridDim.x * blockDim.x;
    for (int i = blockIdx.x * blockDim.x + threadIdx.x; i < n; i += stride) {
        float v = src[i];
        bf16 hh = (bf16)v;
        h[i] = hh;
        l[i] = (bf16)(v - (float)hh);
    }
}

// ---------------------------------------------------------------------------
// LN1 -> xres (fp32, x rows only); LN_att(LN1) -> h hi/lo planes (all rows).
// ---------------------------------------------------------------------------
__global__ __launch_bounds__(256) void prep_ln(
    const float* __restrict__ x, const float* __restrict__ memory,
    const float* __restrict__ g1, const float* __restrict__ b1,
    const float* __restrict__ ga, const float* __restrict__ ba,
    float* __restrict__ xres, bf16* __restrict__ hH, bf16* __restrict__ hL)
{
    const int row = blockIdx.x;            // 0..6271
    const int b = row / 1568, l = row - b * 1568;
    const float* src = (l < 784) ? (memory + ((size_t)b * 1024 + l) * 768)
                                 : (x + ((size_t)b * 784 + (l - 784)) * 768);
    const int t = threadIdx.x, lane = t & 63, wv = t >> 6;
    __shared__ float red[8];

    float v[3];
#pragma unroll
    for (int i = 0; i < 3; ++i) v[i] = src[i * 256 + t];

    float s = v[0] + v[1] + v[2];
    float s2 = v[0] * v[0] + v[1] * v[1] + v[2] * v[2];
#pragma unroll
    for (int off = 1; off < 64; off <<= 1) { s += __shfl_xor(s, off, 64); s2 += __shfl_xor(s2, off, 64); }
    if (lane == 0) { red[wv] = s; red[4 + wv] = s2; }
    __syncthreads();
    s = red[0] + red[1] + red[2] + red[3];
    s2 = red[4] + red[5] + red[6] + red[7];
    float mu = s * (1.0f / 768.0f);
    float var = s2 * (1.0f / 768.0f) - mu * mu;
    float rs = rsqrtf(fmaxf(var, 0.0f) + 1e-5f);

    float w[3];
#pragma unroll
    for (int i = 0; i < 3; ++i) {
        int c = i * 256 + t;
        w[i] = (v[i] - mu) * rs * g1[c] + b1[c];
    }
    if (l >= 784) {
        float* xr = xres + ((size_t)b * 784 + (l - 784)) * 768;
#pragma unroll
        for (int i = 0; i < 3; ++i) xr[i * 256 + t] = w[i];
    }

    s = w[0] + w[1] + w[2];
    s2 = w[0] * w[0] + w[1] * w[1] + w[2] * w[2];
#pragma unroll
    for (int off = 1; off < 64; off <<= 1) { s += __shfl_xor(s, off, 64); s2 += __shfl_xor(s2, off, 64); }
    __syncthreads();
    if (lane == 0) { red[wv] = s; red[4 + wv] = s2; }
    __syncthreads();
    s = red[0] + red[1] + red[2] + red[3];
    s2 = red[4] + red[5] + red[6] + red[7];
    float mu2 = s * (1.0f / 768.0f);
    float var2 = s2 * (1.0f / 768.0f) - mu2 * mu2;
    float rs2 = rsqrtf(fmaxf(var2, 0.0f) + 1e-5f);

    bf16* hh_ = hH + (size_t)row * 768;
    bf16* hl_ = hL + (size_t)row * 768;
#pragma unroll
    for (int i = 0; i < 3; ++i) {
        int c = i * 256 + t;
        float hv = (w[i] - mu2) * rs2 * ga[c] + ba[c];
        bf16 hvh = (bf16)hv;
        hh_[c] = hvh;
        hl_[c] = (bf16)(hv - (float)hvh);
    }
}

// ---------------------------------------------------------------------------
// Plane GEMM, m97 single-buffer schedule (measured best).
// vs R5 (which killed coalescing): staging reverted to the contiguous lane
// map (4 lanes = one 64B row segment), with a k-chunk INVOLUTION
// (chunk ^= row&3) applied on BOTH the global source and the fragment read:
//  * global bursts stay 64B-contiguous (involution permutes within the line)
//  * fragment ds_read_b128 becomes a bijection onto a contiguous 1KB LDS
//    region per wave -> zero excess bank conflicts (was 8-way in R2).
// Plus bijective XCD chunking (m204; FETCH 127->84MB verified in R5).
// C = A*B^T; 128x128 tile, BK=32, 4 waves x 64x64. Split-K via gridDim.z.
// MODE 0: planes out. 1: fp32 partial -> Cf + z*M*N. 2: silu planes out.
// 3: atomic fp32 += into prefilled Cf.
// ---------------------------------------------------------------------------
template <int MODE, int ORD>
__global__ __launch_bounds__(256, 2) void gemm_pl(
    const bf16* __restrict__ Ah, const bf16* __restrict__ Al,
    const bf16* __restrict__ Bh, const bf16* __restrict__ Bl,
    int M, int N, int K,
    const float* __restrict__ bias, const float* __restrict__ resid,
    float* __restrict__ Cf, bf16* __restrict__ Ch, bf16* __restrict__ Cl)
{
    __shared__ __align__(16) bf16 Ahs[128 * 32], Als[128 * 32];
    __shared__ __align__(16) bf16 Bhs[128 * 32], Bls[128 * 32];
    const int t = threadIdx.x, lane = t & 63, wv = t >> 6;

    // ---- bijective XCD chunking (m204) ----
    const int nx = gridDim.x, ny = gridDim.y;
    int orig = blockIdx.x + nx * blockIdx.y;
    int nwg = nx * ny;
    int q = nwg >> 3, rr8 = nwg & 7;
    int xcd = orig & 7, pos = orig >> 3;
    int wgid = (xcd < rr8 ? xcd * (q + 1) : rr8 * (q + 1) + (xcd - rr8) * q) + pos;
    int bx, by;
    if (ORD == 0) { bx = wgid % nx; by = wgid / nx; }   // row chunks (A-heavy)
    else          { by = wgid % ny; bx = wgid / ny; }   // col chunks (B-heavy)

    const int row0 = by * 128, col0 = bx * 128;
    const int ro = (wv >> 1) * 64, co = (wv & 1) * 64;
    const int Kc = K / gridDim.z;
    const int kbeg = blockIdx.z * Kc, kend = kbeg + Kc;
    const int l15 = lane & 15, q8 = lane >> 4;
    const int cs = (q8 ^ (l15 & 3)) * 8;     // involution chunk for fragment reads

    f32x4 acc[4][4] = {};

    for (int k0 = kbeg; k0 < kend; k0 += 32) {
#pragma unroll
        for (int it = 0; it < 2; ++it) {
            int f = it * 256 + t;
            int r = f >> 2;                          // tile row (4 lanes per row)
            int kc = ((f & 3) ^ (r & 3)) * 8;        // involution within 64B line
            int ra = row0 + r; if (ra >= M) ra = M - 1;
            size_t oa = (size_t)ra * K + k0 + kc;
            size_t ob = (size_t)(col0 + r) * K + k0 + kc;
            // wave-uniform LDS base (lane offset applied by HW: +lane*16B)
            size_t lb = (size_t)(it * 256 + wv * 64) * 8;
            load16_lds(Ah + oa, Ahs + lb);
            load16_lds(Al + oa, Als + lb);
            load16_lds(Bh + ob, Bhs + lb);
            load16_lds(Bl + ob, Bls + lb);
        }
        asm volatile("s_waitcnt vmcnt(0)" ::: "memory");
        __syncthreads();
        bf16x8 ah[4], al[4], bh[4], bl[4];
#pragma unroll
        for (int i = 0; i < 4; ++i) {
            int o = (ro + i * 16 + l15) * 32 + cs;   // (row&3)==(l15&3)
            ah[i] = *(const bf16x8*)&Ahs[o];
            al[i] = *(const bf16x8*)&Als[o];
        }
#pragma unroll
        for (int j = 0; j < 4; ++j) {
            int o = (co + j * 16 + l15) * 32 + cs;
            bh[j] = *(const bf16x8*)&Bhs[o];
            bl[j] = *(const bf16x8*)&Bls[o];
        }
#pragma unroll
        for (int i = 0; i < 4; ++i)
#pragma unroll
            for (int j = 0; j < 4; ++j) {
                acc[i][j] = __builtin_amdgcn_mfma_f32_16x16x32_bf16(al[i], bh[j], acc[i][j], 0, 0, 0);
                acc[i][j] = __builtin_amdgcn_mfma_f32_16x16x32_bf16(ah[i], bl[j], acc[i][j], 0, 0, 0);
                acc[i][j] = __builtin_amdgcn_mfma_f32_16x16x32_bf16(ah[i], bh[j], acc[i][j], 0, 0, 0);
            }
        __syncthreads();
    }

    const size_t zoff = (size_t)blockIdx.z * M * N;
#pragma unroll
    for (int i = 0; i < 4; ++i)
#pragma unroll
        for (int j = 0; j < 4; ++j)
#pragma unroll
            for (int r = 0; r < 4; ++r) {
                int row = row0 + ro + i * 16 + (lane >> 4) * 4 + r;
                int col = col0 + co + j * 16 + (lane & 15);
                if (row >= M) continue;
                float v = acc[i][j][r];
                size_t idx = (size_t)row * N + col;
                if (MODE == 0) {
                    bf16 hh = (bf16)v;
                    Ch[idx] = hh; Cl[idx] = (bf16)(v - (float)hh);
                } else if (MODE == 1) {
                    Cf[zoff + idx] = v;               // partial, bias added later
                } else if (MODE == 2) {
                    v += bias[col];
                    v = v / (1.0f + __expf(-v));
                    bf16 hh = (bf16)v;
                    Ch[idx] = hh; Cl[idx] = (bf16)(v - (float)hh);
                } else {
                    unsafeAtomicAdd(&Cf[idx], v);     // HW f32 atomic, prefilled dest
                }
            }
}

// ---------------------------------------------------------------------------
// Flash attention, pipelined. Grid: x = hh + 12*b (48), y = w*4+g (16).
// Deferred softmax (bounded logits), single barrier per K-tile, swizzled K
// via pre-swizzled global_load_lds source, V reg-prefetch + 2-way-bank
// transposed write.
// ---------------------------------------------------------------------------
__global__ __launch_bounds__(256, 3) void attn_kernel(
    const bf16* __restrict__ qh_, const bf16* __restrict__ ql_,
    bf16* __restrict__ oh_, bf16* __restrict__ ol_)
{
    const int hh = blockIdx.x % 12, b = blockIdx.x / 12;
    const int w = blockIdx.y >> 2, g = blockIdx.y & 3;
    const int kmax = (5 + w) * 196, nkt = (kmax + 31) / 32;
    const int t = threadIdx.x, lane = t & 63, wv = t >> 6;
    const int tile = g * 4 + wv;                  // 0..15; >12 idle (wave-uniform)
    const int l15 = lane & 15, q8 = lane >> 4;

    __shared__ __align__(16) bf16 Ks_h[2][32 * 64], Ks_l[2][32 * 64];
    __shared__ __align__(16) bf16 Vt_h[2][64 * 40];
    __shared__ __align__(16) bf16 Pl_h[4][16 * 40];

    const size_t bbase = (size_t)b * 1568 * 2304;

    // staging geometry: thread t covers K/V row srow, col chunk sc8.
    const int srow = t >> 3;                      // 0..31 (wave wv: rows wv*8..+7)
    const int sc8 = (t & 7) * 8;
    // K: LDS dest is linear (global_load_lds), so pre-swizzle the SOURCE col.
    const int scsrc = sc8 ^ ((srow & 7) * 8);

    // Q fragments (held in registers for the whole kernel)
    int tcl = tile > 12 ? 12 : tile;
    int qr0 = tcl * 16 + l15; if (qr0 > 195) qr0 = 195;
    const size_t qoff = bbase + (size_t)(784 + w * 196 + qr0) * 2304 + hh * 64 + q8 * 8;
    bf16x8 qfh[2], qfl[2];
#pragma unroll
    for (int p = 0; p < 2; ++p) {
        qfh[p] = *(const bf16x8*)(qh_ + qoff + p * 32);
        qfl[p] = *(const bf16x8*)(ql_ + qoff + p * 32);
    }

    float l_i[4] = {0.f, 0.f, 0.f, 0.f};
    f32x4 oacc[4];
#pragma unroll
    for (int nd = 0; nd < 4; ++nd) oacc[nd] = f32x4{0.f, 0.f, 0.f, 0.f};

    // issue staging for K-tile kt2 into buffer bufn; V -> vreg (not yet in LDS)
    auto stage_issue = [&](int kt2, int bufn, bf16x8& vreg) {
        const size_t kb = bbase + (size_t)(kt2 * 32 + srow) * 2304 + 768 + (size_t)hh * 64;
        load16_lds(qh_ + kb + scsrc, &Ks_h[bufn][wv * 512]);
        load16_lds(ql_ + kb + scsrc, &Ks_l[bufn][wv * 512]);
        vreg = *(const bf16x8*)(qh_ + kb + 768 + sc8);
    };
    // transposed V write, key-XOR swizzled (2-way banks instead of 16-way)
    auto write_V = [&](int bufn, const bf16x8& vreg) {
#pragma unroll
        for (int j = 0; j < 8; ++j) {
            int d = sc8 + j;
            int keyx = srow ^ (((d >> 3) & 3) * 8);
            Vt_h[bufn][d * 40 + keyx] = vreg[j];
        }
    };

    // ---- prologue: stage tile 0 into buffer 0
    {
        bf16x8 v0;
        stage_issue(0, 0, v0);
        write_V(0, v0);                            // data dep inserts vmcnt wait
        asm volatile("s_waitcnt vmcnt(0)" ::: "memory");
        __syncthreads();
    }

    const float CEXP = 0.18033688011112042f;       // 0.125 * log2(e)

    for (int kt = 0; kt < nkt; ++kt) {
        const int cur = kt & 1, nxt = cur ^ 1;
        int kt2 = kt + 1; if (kt2 >= nkt) kt2 = nkt - 1;   // clamp (no OOB)
        bf16x8 vnext;
        stage_issue(kt2, nxt, vnext);              // overlaps with compute below

        if (tile <= 12) {
            bf16x8 kfh[2][2], kfl[2][2], vth[4];
#pragma unroll
            for (int nb = 0; nb < 2; ++nb)
#pragma unroll
                for (int p = 0; p < 2; ++p) {
                    int row = nb * 16 + l15;
                    int c = (p * 32 + q8 * 8) ^ ((row & 7) * 8);
                    kfh[nb][p] = *(const bf16x8*)&Ks_h[cur][row * 64 + c];
                    kfl[nb][p] = *(const bf16x8*)&Ks_l[cur][row * 64 + c];
                }
#pragma unroll
            for (int nd = 0; nd < 4; ++nd) {
                int d = nd * 16 + l15;
                int k8 = (q8 * 8) ^ (((d >> 3) & 3) * 8);
                vth[nd] = *(const bf16x8*)&Vt_h[cur][d * 40 + k8];
            }

            // QK^T: 4 independent depth-3 MFMA chains
            f32x4 s0a = {0.f,0.f,0.f,0.f}, s0b = {0.f,0.f,0.f,0.f};
            f32x4 s1a = {0.f,0.f,0.f,0.f}, s1b = {0.f,0.f,0.f,0.f};
            s0a = __builtin_amdgcn_mfma_f32_16x16x32_bf16(qfl[0], kfh[0][0], s0a, 0, 0, 0);
            s1a = __builtin_amdgcn_mfma_f32_16x16x32_bf16(qfl[0], kfh[1][0], s1a, 0, 0, 0);
            s0b = __builtin_amdgcn_mfma_f32_16x16x32_bf16(qfl[1], kfh[0][1], s0b, 0, 0, 0);
            s1b = __builtin_amdgcn_mfma_f32_16x16x32_bf16(qfl[1], kfh[1][1], s1b, 0, 0, 0);
            s0a = __builtin_amdgcn_mfma_f32_16x16x32_bf16(qfh[0], kfl[0][0], s0a, 0, 0, 0);
            s1a = __builtin_amdgcn_mfma_f32_16x16x32_bf16(qfh[0], kfl[1][0], s1a, 0, 0, 0);
            s0b = __builtin_amdgcn_mfma_f32_16x16x32_bf16(qfh[1], kfl[0][1], s0b, 0, 0, 0);
            s1b = __builtin_amdgcn_mfma_f32_16x16x32_bf16(qfh[1], kfl[1][1], s1b, 0, 0, 0);
            s0a = __builtin_amdgcn_mfma_f32_16x16x32_bf16(qfh[0], kfh[0][0], s0a, 0, 0, 0);
            s1a = __builtin_amdgcn_mfma_f32_16x16x32_bf16(qfh[0], kfh[1][0], s1a, 0, 0, 0);
            s0b = __builtin_amdgcn_mfma_f32_16x16x32_bf16(qfh[1], kfh[0][1], s0b, 0, 0, 0);
            s1b = __builtin_amdgcn_mfma_f32_16x16x32_bf16(qfh[1], kfh[1][1], s1b, 0, 0, 0);
            f32x4 s0 = s0a + s0b, s1 = s1a + s1b;

            // deferred softmax: p = exp(S/8), no max subtraction, no rescale
            const int key0 = kt * 32 + l15;
            const bool m0 = (key0 >= kmax), m1 = (key0 + 16 >= kmax);
#pragma unroll
            for (int r = 0; r < 4; ++r) {
                float p0 = m0 ? 0.0f : exp2f(s0[r] * CEXP);
                float p1 = m1 ? 0.0f : exp2f(s1[r] * CEXP);
                l_i[r] += p0 + p1;
                int pr = q8 * 4 + r;
                Pl_h[wv][pr * 40 + l15] = (bf16)p0;
                Pl_h[wv][pr * 40 + 16 + l15] = (bf16)p1;
            }
            asm volatile("s_waitcnt lgkmcnt(0)" ::: "memory");   // wave-private Pl RAW
            bf16x8 pfh = *(const bf16x8*)&Pl_h[wv][l15 * 40 + q8 * 8];
#pragma unroll
            for (int nd = 0; nd < 4; ++nd)
                oacc[nd] = __builtin_amdgcn_mfma_f32_16x16x32_bf16(pfh, vth[nd], oacc[nd], 0, 0, 0);
        }

        write_V(nxt, vnext);                       // waits vmcnt for vnext only here
        asm volatile("s_waitcnt vmcnt(0)" ::: "memory");
        __syncthreads();
    }

    if (tile <= 12) {
#pragma unroll
        for (int r = 0; r < 4; ++r) {
            float s = l_i[r];
#pragma unroll
            for (int off = 1; off < 16; off <<= 1) s += __shfl_xor(s, off, 64);
            int qr = tile * 16 + q8 * 4 + r;
            if (qr >= 196) continue;
            float inv = 1.0f / s;
            size_t row = (size_t)b * 784 + w * 196 + qr;
#pragma unroll
            for (int nd = 0; nd < 4; ++nd) {
                float ov = oacc[nd][r] * inv;
                bf16 oh = (bf16)ov;
                size_t idx = row * 768 + hh * 64 + nd * 16 + l15;
                oh_[idx] = oh;
                ol_[idx] = (bf16)(ov - (float)oh);
            }
        }
    }
}

// ---------------------------------------------------------------------------
// y = xres + p0 + p1 + b_out (fp32), y2 = LN2(y) planes, dout = y + b2ff
// (prefill for the atomic split-K w2 GEMM). Block per x-row (3136).
// ---------------------------------------------------------------------------
__global__ __launch_bounds__(256) void ln2_resid(
    const float* __restrict__ xres, const float* __restrict__ attP,
    const float* __restrict__ bo,
    const float* __restrict__ g2, const float* __restrict__ b2,
    const float* __restrict__ b2ff,
    float* __restrict__ y, bf16* __restrict__ y2H, bf16* __restrict__ y2L,
    float* __restrict__ dout)
{
    const int row = blockIdx.x;
    const size_t MN = (size_t)3136 * 768;
    const float* xr = xres + (size_t)row * 768;
    const float* a0 = attP + (size_t)row * 768;
    const float* a1 = attP + MN + (size_t)row * 768;
    const int t = threadIdx.x, lane = t & 63, wv = t >> 6;
    __shared__ float red[8];

    float v[3];
    float* yr = y + (size_t)row * 768;
    float* dr = dout + (size_t)row * 768;
#pragma unroll
    for (int i = 0; i < 3; ++i) {
        int c = i * 256 + t;
        v[i] = xr[c] + a0[c] + a1[c] + bo[c];
        yr[c] = v[i];
        dr[c] = v[i] + b2ff[c];
    }
    float s = v[0] + v[1] + v[2];
    float s2 = v[0] * v[0] + v[1] * v[1] + v[2] * v[2];
#pragma unroll
    for (int off = 1; off < 64; off <<= 1) { s += __shfl_xor(s, off, 64); s2 += __shfl_xor(s2, off, 64); }
    if (lane == 0) { red[wv] = s; red[4 + wv] = s2; }
    __syncthreads();
    s = red[0] + red[1] + red[2] + red[3];
    s2 = red[4] + red[5] + red[6] + red[7];
    float mu = s * (1.0f / 768.0f);
    float var = s2 * (1.0f / 768.0f) - mu * mu;
    float rs = rsqrtf(fmaxf(var, 0.0f) + 1e-5f);

    bf16* yh = y2H + (size_t)row * 768;
    bf16* yl = y2L + (size_t)row * 768;
#pragma unroll
    for (int i = 0; i < 3; ++i) {
        int c = i * 256 + t;
        float yv = (v[i] - mu) * rs * g2[c] + b2[c];
        bf16 yvh = (bf16)yv;
        yh[c] = yvh;
        yl[c] = (bf16)(yv - (float)yvh);
    }
}

// ---------------------------------------------------------------------------
extern "C" void kernel_launch(void* const* d_in, const int* in_sizes, int n_in,
                              void* d_out, int out_size, void* d_ws, size_t ws_size,
                              hipStream_t stream)
{
    (void)in_sizes; (void)n_in; (void)out_size; (void)ws_size;
    const float* x        = (const float*)d_in[0];
    const float* memory   = (const float*)d_in[1];
    const float* ln_att_g = (const float*)d_in[2];
    const float* ln_att_b = (const float*)d_in[3];
    const float* w_qkv    = (const float*)d_in[4];
    const float* w_out    = (const float*)d_in[5];
    const float* b_out    = (const float*)d_in[6];
    const float* ln1_g    = (const float*)d_in[7];
    const float* ln1_b    = (const float*)d_in[8];
    const float* ln2_g    = (const float*)d_in[9];
    const float* ln2_b    = (const float*)d_in[10];
    const float* w1       = (const float*)d_in[11];
    const float* b1       = (const float*)d_in[12];
    const float* w2       = (const float*)d_in[13];
    const float* b2       = (const float*)d_in[14];

    // ---- workspace layout (~109.7 MiB, same footprint) ----
    char* ws = (char*)d_ws;
    const size_t SZF  = (size_t)3136 * 768 * 4;
    const size_t SZP  = (size_t)3136 * 768 * 2;
    const size_t SZHP = (size_t)6272 * 768 * 2;
    const size_t SZQP = (size_t)6272 * 2304 * 2;
    const size_t SZFP = (size_t)3136 * 3072 * 2;

    float* xres = (float*)(ws);
    bf16* hH  = (bf16*)(ws + SZF);
    bf16* hL  = (bf16*)(ws + SZF + SZHP);
    bf16* aoH = (bf16*)(ws + SZF);
    bf16* aoL = (bf16*)(ws + SZF + SZP);
    bf16* y2H = (bf16*)(ws + SZF);
    bf16* y2L = (bf16*)(ws + SZF + SZP);
    const size_t OQ = SZF + 2 * SZHP;
    bf16* qkvH = (bf16*)(ws + OQ);
    bf16* qkvL = (bf16*)(ws + OQ + SZQP);
    float* y    = (float*)(ws + OQ);
    float* attP = (float*)(ws + OQ + SZF);   // 2 partials (dead qkv region; ffH overwrites later)
    bf16* ffH  = (bf16*)(ws + OQ + SZF);
    bf16* ffL  = (bf16*)(ws + OQ + SZF + SZFP);
    const size_t OW = OQ + 2 * SZQP;
    bf16* wqH = (bf16*)(ws + OW);
    bf16* wqL = (bf16*)(ws + OW + 3538944);
    bf16* woH = (bf16*)(ws + OW + 2 * 3538944);
    bf16* woL = (bf16*)(ws + OW + 2 * 3538944 + 1179648);
    bf16* w1H = (bf16*)(ws + OW + 2 * 3538944 + 2 * 1179648);
    bf16* w1L = (bf16*)(ws + OW + 2 * 3538944 + 2 * 1179648 + 4718592);
    bf16* w2H = (bf16*)(ws + OW + 2 * 3538944 + 2 * 1179648 + 2 * 4718592);
    bf16* w2L = (bf16*)(ws + OW + 2 * 3538944 + 2 * 1179648 + 3 * 4718592);

    // 0) pre-split weights into hi/lo planes
    split_planes<<<512, 256, 0, stream>>>(w_qkv, wqH, wqL, 1769472);
    split_planes<<<512, 256, 0, stream>>>(w_out, woH, woL, 589824);
    split_planes<<<512, 256, 0, stream>>>(w1,    w1H, w1L, 2359296);
    split_planes<<<512, 256, 0, stream>>>(w2,    w2H, w2L, 2359296);

    // 1) LN1 + LN_att
    prep_ln<<<6272, 256, 0, stream>>>(x, memory, ln1_g, ln1_b, ln_att_g, ln_att_b, xres, hH, hL);

    // 2) qkv planes = h @ w_qkv^T  (M=6272, N=2304, K=768) — row-chunked XCDs
    gemm_pl<0, 0><<<dim3(18, 49), 256, 0, stream>>>(hH, hL, wqH, wqL, 6272, 2304, 768,
                                                    nullptr, nullptr, nullptr, qkvH, qkvL);

    // 3) attention  (grid: x = hh+12*b, y = w*4+g  -> XCD-local K/V sharing)
    attn_kernel<<<dim3(48, 16), 256, 0, stream>>>(qkvH, qkvL, aoH, aoL);

    // 4) att partials = ao @ w_out^T  (M=3136, N=768, K=768, split-K=2) — row-chunked
    gemm_pl<1, 0><<<dim3(6, 25, 2), 256, 0, stream>>>(aoH, aoL, woH, woL, 3136, 768, 768,
                                                      nullptr, nullptr, attP, nullptr, nullptr);

    // 5) y = xres + p0 + p1 + b_out ; y2 planes = LN2(y) ; dout prefill = y + b2
    ln2_resid<<<3136, 256, 0, stream>>>(xres, attP, b_out, ln2_g, ln2_b, b2,
                                        y, y2H, y2L, (float*)d_out);

    // 6) ff planes = silu(y2 @ w1^T + b1)  (M=3136, N=3072, K=768) — col-chunked (w1-heavy)
    gemm_pl<2, 1><<<dim3(24, 25), 256, 0, stream>>>(y2H, y2L, w1H, w1L, 3136, 3072, 768,
                                                    b1, nullptr, nullptr, ffH, ffL);

    // 7) d_out += ff @ w2^T  (M=3136, N=768, K=3072, split-K=4, atomic) — row-chunked
    gemm_pl<3, 0><<<dim3(6, 25, 4), 256, 0, stream>>>(ffH, ffL, w2H, w2L, 3136, 768, 3072,
                                                      nullptr, nullptr, (float*)d_out, nullptr, nullptr);
}

// Round 7
// 435.244 us; speedup vs baseline: 1.2285x; 1.0715x over previous
//
#include <hip/hip_runtime.h>
#include <cstdint>

typedef __bf16 bf16;
typedef __bf16 bf16x4 __attribute__((ext_vector_type(4)));
typedef __bf16 bf16x8 __attribute__((ext_vector_type(8)));
typedef float f32x4 __attribute__((ext_vector_type(4)));

#define AS1 __attribute__((address_space(1)))
#define AS3 __attribute__((address_space(3)))

// Async global->LDS, 16B per lane. LDS dest must be wave-uniform base;
// HW writes lane i at base + i*16 (m97/m104 semantics).
__device__ __forceinline__ void load16_lds(const void* gp, void* lds_base_wave_uniform) {
    __builtin_amdgcn_global_load_lds((AS1 void*)((void*)gp),
                                     (AS3 void*)lds_base_wave_uniform, 16, 0, 0);
}

// ---------------------------------------------------------------------------
// All 4 weight tensors -> (hi, lo) bf16 planes in ONE dispatch (float4 loads).
// Quad counts: w_qkv 442368, w_out 147456, w1 589824, w2 589824 (total 1769472).
// ---------------------------------------------------------------------------
__global__ __launch_bounds__(256) void split_all(
    const float* __restrict__ s0, bf16* __restrict__ h0, bf16* __restrict__ l0,
    const float* __restrict__ s1, bf16* __restrict__ h1, bf16* __restrict__ l1,
    const float* __restrict__ s2, bf16* __restrict__ h2, bf16* __restrict__ l2,
    const float* __restrict__ s3, bf16* __restrict__ h3, bf16* __restrict__ l3)
{
    const int n0q = 442368, n1q = 147456, n2q = 589824;
    const int total = 1769472;
    const int stride = gridDim.x * blockDim.x;
    for (int i = blockIdx.x * blockDim.x + threadIdx.x; i < total; i += stride) {
        const float* s; bf16 *h, *l; int j = i;
        if (j < n0q) { s = s0; h = h0; l = l0; }
        else if ((j -= n0q) < n1q) { s = s1; h = h1; l = l1; }
        else if ((j -= n1q) < n2q) { s = s2; h = h2; l = l2; }
        else { j -= n2q; s = s3; h = h3; l = l3; }
        float4 v = reinterpret_cast<const float4*>(s)[j];
        bf16x4 hi, lo;
        hi[0] = (bf16)v.x; lo[0] = (bf16)(v.x - (float)hi[0]);
        hi[1] = (bf16)v.y; lo[1] = (bf16)(v.y - (float)hi[1]);
        hi[2] = (bf16)v.z; lo[2] = (bf16)(v.z - (float)hi[2]);
        hi[3] = (bf16)v.w; lo[3] = (bf16)(v.w - (float)hi[3]);
        reinterpret_cast<bf16x4*>(h)[j] = hi;
        reinterpret_cast<bf16x4*>(l)[j] = lo;
    }
}

// ---------------------------------------------------------------------------
// LN1 -> xres (fp32, x rows only); LN_att(LN1) -> h hi/lo planes (all rows).
// ---------------------------------------------------------------------------
__global__ __launch_bounds__(256) void prep_ln(
    const float* __restrict__ x, const float* __restrict__ memory,
    const float* __restrict__ g1, const float* __restrict__ b1,
    const float* __restrict__ ga, const float* __restrict__ ba,
    float* __restrict__ xres, bf16* __restrict__ hH, bf16* __restrict__ hL)
{
    const int row = blockIdx.x;            // 0..6271
    const int b = row / 1568, l = row - b * 1568;
    const float* src = (l < 784) ? (memory + ((size_t)b * 1024 + l) * 768)
                                 : (x + ((size_t)b * 784 + (l - 784)) * 768);
    const int t = threadIdx.x, lane = t & 63, wv = t >> 6;
    __shared__ float red[8];

    float v[3];
#pragma unroll
    for (int i = 0; i < 3; ++i) v[i] = src[i * 256 + t];

    float s = v[0] + v[1] + v[2];
    float s2 = v[0] * v[0] + v[1] * v[1] + v[2] * v[2];
#pragma unroll
    for (int off = 1; off < 64; off <<= 1) { s += __shfl_xor(s, off, 64); s2 += __shfl_xor(s2, off, 64); }
    if (lane == 0) { red[wv] = s; red[4 + wv] = s2; }
    __syncthreads();
    s = red[0] + red[1] + red[2] + red[3];
    s2 = red[4] + red[5] + red[6] + red[7];
    float mu = s * (1.0f / 768.0f);
    float var = s2 * (1.0f / 768.0f) - mu * mu;
    float rs = rsqrtf(fmaxf(var, 0.0f) + 1e-5f);

    float w[3];
#pragma unroll
    for (int i = 0; i < 3; ++i) {
        int c = i * 256 + t;
        w[i] = (v[i] - mu) * rs * g1[c] + b1[c];
    }
    if (l >= 784) {
        float* xr = xres + ((size_t)b * 784 + (l - 784)) * 768;
#pragma unroll
        for (int i = 0; i < 3; ++i) xr[i * 256 + t] = w[i];
    }

    s = w[0] + w[1] + w[2];
    s2 = w[0] * w[0] + w[1] * w[1] + w[2] * w[2];
#pragma unroll
    for (int off = 1; off < 64; off <<= 1) { s += __shfl_xor(s, off, 64); s2 += __shfl_xor(s2, off, 64); }
    __syncthreads();
    if (lane == 0) { red[wv] = s; red[4 + wv] = s2; }
    __syncthreads();
    s = red[0] + red[1] + red[2] + red[3];
    s2 = red[4] + red[5] + red[6] + red[7];
    float mu2 = s * (1.0f / 768.0f);
    float var2 = s2 * (1.0f / 768.0f) - mu2 * mu2;
    float rs2 = rsqrtf(fmaxf(var2, 0.0f) + 1e-5f);

    bf16* hh_ = hH + (size_t)row * 768;
    bf16* hl_ = hL + (size_t)row * 768;
#pragma unroll
    for (int i = 0; i < 3; ++i) {
        int c = i * 256 + t;
        float hv = (w[i] - mu2) * rs2 * ga[c] + ba[c];
        bf16 hvh = (bf16)hv;
        hh_[c] = hvh;
        hl_[c] = (bf16)(hv - (float)hvh);
    }
}

// ---------------------------------------------------------------------------
// QKV GEMM, 256x128 tile (4 waves x 128x64), m97 single-buffer schedule with
// R6's involution staging (coalesced 64B bursts) + bijective XCD row-chunking.
// Per K-step: 96 MFMA / (12 stage + 24 ds_read) vs 128-tile's 48/(8+16).
// A-frags loaded per-i inside the MFMA loop (VGPR ~190, no spill at 256 cap).
// Skips the never-read V-lo plane store (cols >= 1536).
// ---------------------------------------------------------------------------
__global__ __launch_bounds__(256, 2) void gemm_qkv(
    const bf16* __restrict__ Ah, const bf16* __restrict__ Al,
    const bf16* __restrict__ Bh, const bf16* __restrict__ Bl,
    int M, int N, int K,
    bf16* __restrict__ Ch, bf16* __restrict__ Cl)
{
    __shared__ __align__(16) bf16 Ahs[256 * 32], Als[256 * 32];
    __shared__ __align__(16) bf16 Bhs[128 * 32], Bls[128 * 32];
    const int t = threadIdx.x, lane = t & 63, wv = t >> 6;

    // bijective XCD chunking (m204), row-chunk order
    const int nx = gridDim.x, ny = gridDim.y;
    int orig = blockIdx.x + nx * blockIdx.y;
    int nwg = nx * ny;
    int q = nwg >> 3, rr8 = nwg & 7;
    int xcd = orig & 7, pos = orig >> 3;
    int wgid = (xcd < rr8 ? xcd * (q + 1) : rr8 * (q + 1) + (xcd - rr8) * q) + pos;
    int bx = wgid % nx, by = wgid / nx;

    const int row0 = by * 256, col0 = bx * 128;
    const int ro = (wv >> 1) * 128, co = (wv & 1) * 64;
    const int l15 = lane & 15, q8 = lane >> 4;
    const int cs = (q8 ^ (l15 & 3)) * 8;     // involution chunk for fragment reads

    f32x4 acc[8][4] = {};

    for (int k0 = 0; k0 < K; k0 += 32) {
#pragma unroll
        for (int it = 0; it < 4; ++it) {              // A: 256 rows
            int f = it * 256 + t;
            int r = f >> 2;
            int kc = ((f & 3) ^ (r & 3)) * 8;
            int ra = row0 + r; if (ra >= M) ra = M - 1;
            size_t oa = (size_t)ra * K + k0 + kc;
            size_t lb = (size_t)(it * 256 + wv * 64) * 8;
            load16_lds(Ah + oa, Ahs + lb);
            load16_lds(Al + oa, Als + lb);
        }
#pragma unroll
        for (int it = 0; it < 2; ++it) {              // B: 128 rows
            int f = it * 256 + t;
            int r = f >> 2;
            int kc = ((f & 3) ^ (r & 3)) * 8;
            size_t ob = (size_t)(col0 + r) * K + k0 + kc;
            size_t lb = (size_t)(it * 256 + wv * 64) * 8;
            load16_lds(Bh + ob, Bhs + lb);
            load16_lds(Bl + ob, Bls + lb);
        }
        asm volatile("s_waitcnt vmcnt(0)" ::: "memory");
        __syncthreads();

        bf16x8 bh[4], bl[4];
#pragma unroll
        for (int j = 0; j < 4; ++j) {
            int o = (co + j * 16 + l15) * 32 + cs;
            bh[j] = *(const bf16x8*)&Bhs[o];
            bl[j] = *(const bf16x8*)&Bls[o];
        }
#pragma unroll
        for (int i = 0; i < 8; ++i) {
            int o = (ro + i * 16 + l15) * 32 + cs;
            bf16x8 ah = *(const bf16x8*)&Ahs[o];
            bf16x8 al = *(const bf16x8*)&Als[o];
#pragma unroll
            for (int j = 0; j < 4; ++j) {
                acc[i][j] = __builtin_amdgcn_mfma_f32_16x16x32_bf16(al, bh[j], acc[i][j], 0, 0, 0);
                acc[i][j] = __builtin_amdgcn_mfma_f32_16x16x32_bf16(ah, bl[j], acc[i][j], 0, 0, 0);
                acc[i][j] = __builtin_amdgcn_mfma_f32_16x16x32_bf16(ah, bh[j], acc[i][j], 0, 0, 0);
            }
        }
        __syncthreads();
    }

#pragma unroll
    for (int i = 0; i < 8; ++i)
#pragma unroll
        for (int j = 0; j < 4; ++j)
#pragma unroll
            for (int r = 0; r < 4; ++r) {
                int row = row0 + ro + i * 16 + q8 * 4 + r;
                int col = col0 + co + j * 16 + l15;
                if (row >= M) continue;
                float v = acc[i][j][r];
                size_t idx = (size_t)row * N + col;
                bf16 hh = (bf16)v;
                Ch[idx] = hh;
                if (col < 1536) Cl[idx] = (bf16)(v - (float)hh);  // V-lo never read
            }
}

// ---------------------------------------------------------------------------
// Plane GEMM, m97 single-buffer schedule + involution staging + XCD chunking
// (R6-verified). 128x128 tile, BK=32, 4 waves x 64x64. Split-K via gridDim.z.
// MODE 1: fp32 partial -> Cf + z*M*N. 2: silu planes out. 3: atomic += Cf.
// ---------------------------------------------------------------------------
template <int MODE, int ORD>
__global__ __launch_bounds__(256, 2) void gemm_pl(
    const bf16* __restrict__ Ah, const bf16* __restrict__ Al,
    const bf16* __restrict__ Bh, const bf16* __restrict__ Bl,
    int M, int N, int K,
    const float* __restrict__ bias, const float* __restrict__ resid,
    float* __restrict__ Cf, bf16* __restrict__ Ch, bf16* __restrict__ Cl)
{
    __shared__ __align__(16) bf16 Ahs[128 * 32], Als[128 * 32];
    __shared__ __align__(16) bf16 Bhs[128 * 32], Bls[128 * 32];
    const int t = threadIdx.x, lane = t & 63, wv = t >> 6;

    // ---- bijective XCD chunking (m204) ----
    const int nx = gridDim.x, ny = gridDim.y;
    int orig = blockIdx.x + nx * blockIdx.y;
    int nwg = nx * ny;
    int q = nwg >> 3, rr8 = nwg & 7;
    int xcd = orig & 7, pos = orig >> 3;
    int wgid = (xcd < rr8 ? xcd * (q + 1) : rr8 * (q + 1) + (xcd - rr8) * q) + pos;
    int bx, by;
    if (ORD == 0) { bx = wgid % nx; by = wgid / nx; }   // row chunks (A-heavy)
    else          { by = wgid % ny; bx = wgid / ny; }   // col chunks (B-heavy)

    const int row0 = by * 128, col0 = bx * 128;
    const int ro = (wv >> 1) * 64, co = (wv & 1) * 64;
    const int Kc = K / gridDim.z;
    const int kbeg = blockIdx.z * Kc, kend = kbeg + Kc;
    const int l15 = lane & 15, q8 = lane >> 4;
    const int cs = (q8 ^ (l15 & 3)) * 8;     // involution chunk for fragment reads

    f32x4 acc[4][4] = {};

    for (int k0 = kbeg; k0 < kend; k0 += 32) {
#pragma unroll
        for (int it = 0; it < 2; ++it) {
            int f = it * 256 + t;
            int r = f >> 2;                          // tile row (4 lanes per row)
            int kc = ((f & 3) ^ (r & 3)) * 8;        // involution within 64B line
            int ra = row0 + r; if (ra >= M) ra = M - 1;
            size_t oa = (size_t)ra * K + k0 + kc;
            size_t ob = (size_t)(col0 + r) * K + k0 + kc;
            size_t lb = (size_t)(it * 256 + wv * 64) * 8;
            load16_lds(Ah + oa, Ahs + lb);
            load16_lds(Al + oa, Als + lb);
            load16_lds(Bh + ob, Bhs + lb);
            load16_lds(Bl + ob, Bls + lb);
        }
        asm volatile("s_waitcnt vmcnt(0)" ::: "memory");
        __syncthreads();
        bf16x8 ah[4], al[4], bh[4], bl[4];
#pragma unroll
        for (int i = 0; i < 4; ++i) {
            int o = (ro + i * 16 + l15) * 32 + cs;   // (row&3)==(l15&3)
            ah[i] = *(const bf16x8*)&Ahs[o];
            al[i] = *(const bf16x8*)&Als[o];
        }
#pragma unroll
        for (int j = 0; j < 4; ++j) {
            int o = (co + j * 16 + l15) * 32 + cs;
            bh[j] = *(const bf16x8*)&Bhs[o];
            bl[j] = *(const bf16x8*)&Bls[o];
        }
#pragma unroll
        for (int i = 0; i < 4; ++i)
#pragma unroll
            for (int j = 0; j < 4; ++j) {
                acc[i][j] = __builtin_amdgcn_mfma_f32_16x16x32_bf16(al[i], bh[j], acc[i][j], 0, 0, 0);
                acc[i][j] = __builtin_amdgcn_mfma_f32_16x16x32_bf16(ah[i], bl[j], acc[i][j], 0, 0, 0);
                acc[i][j] = __builtin_amdgcn_mfma_f32_16x16x32_bf16(ah[i], bh[j], acc[i][j], 0, 0, 0);
            }
        __syncthreads();
    }

    const size_t zoff = (size_t)blockIdx.z * M * N;
#pragma unroll
    for (int i = 0; i < 4; ++i)
#pragma unroll
        for (int j = 0; j < 4; ++j)
#pragma unroll
            for (int r = 0; r < 4; ++r) {
                int row = row0 + ro + i * 16 + (lane >> 4) * 4 + r;
                int col = col0 + co + j * 16 + (lane & 15);
                if (row >= M) continue;
                float v = acc[i][j][r];
                size_t idx = (size_t)row * N + col;
                if (MODE == 1) {
                    Cf[zoff + idx] = v;               // partial, bias added later
                } else if (MODE == 2) {
                    v += bias[col];
                    v = v / (1.0f + __expf(-v));
                    bf16 hh = (bf16)v;
                    Ch[idx] = hh; Cl[idx] = (bf16)(v - (float)hh);
                } else {
                    unsafeAtomicAdd(&Cf[idx], v);     // HW f32 atomic, prefilled dest
                }
            }
}

// ---------------------------------------------------------------------------
// Flash attention, pipelined. Grid: x = hh + 12*b (48), y = w*4+g (16).
// Deferred softmax (bounded logits), single barrier per K-tile, swizzled K
// via pre-swizzled global_load_lds source, V reg-prefetch + 2-way-bank
// transposed write.
// ---------------------------------------------------------------------------
__global__ __launch_bounds__(256, 3) void attn_kernel(
    const bf16* __restrict__ qh_, const bf16* __restrict__ ql_,
    bf16* __restrict__ oh_, bf16* __restrict__ ol_)
{
    const int hh = blockIdx.x % 12, b = blockIdx.x / 12;
    const int w = blockIdx.y >> 2, g = blockIdx.y & 3;
    const int kmax = (5 + w) * 196, nkt = (kmax + 31) / 32;
    const int t = threadIdx.x, lane = t & 63, wv = t >> 6;
    const int tile = g * 4 + wv;                  // 0..15; >12 idle (wave-uniform)
    const int l15 = lane & 15, q8 = lane >> 4;

    __shared__ __align__(16) bf16 Ks_h[2][32 * 64], Ks_l[2][32 * 64];
    __shared__ __align__(16) bf16 Vt_h[2][64 * 40];
    __shared__ __align__(16) bf16 Pl_h[4][16 * 40];

    const size_t bbase = (size_t)b * 1568 * 2304;

    // staging geometry: thread t covers K/V row srow, col chunk sc8.
    const int srow = t >> 3;                      // 0..31 (wave wv: rows wv*8..+7)
    const int sc8 = (t & 7) * 8;
    // K: LDS dest is linear (global_load_lds), so pre-swizzle the SOURCE col.
    const int scsrc = sc8 ^ ((srow & 7) * 8);

    // Q fragments (held in registers for the whole kernel)
    int tcl = tile > 12 ? 12 : tile;
    int qr0 = tcl * 16 + l15; if (qr0 > 195) qr0 = 195;
    const size_t qoff = bbase + (size_t)(784 + w * 196 + qr0) * 2304 + hh * 64 + q8 * 8;
    bf16x8 qfh[2], qfl[2];
#pragma unroll
    for (int p = 0; p < 2; ++p) {
        qfh[p] = *(const bf16x8*)(qh_ + qoff + p * 32);
        qfl[p] = *(const bf16x8*)(ql_ + qoff + p * 32);
    }

    float l_i[4] = {0.f, 0.f, 0.f, 0.f};
    f32x4 oacc[4];
#pragma unroll
    for (int nd = 0; nd < 4; ++nd) oacc[nd] = f32x4{0.f, 0.f, 0.f, 0.f};

    // issue staging for K-tile kt2 into buffer bufn; V -> vreg (not yet in LDS)
    auto stage_issue = [&](int kt2, int bufn, bf16x8& vreg) {
        const size_t kb = bbase + (size_t)(kt2 * 32 + srow) * 2304 + 768 + (size_t)hh * 64;
        load16_lds(qh_ + kb + scsrc, &Ks_h[bufn][wv * 512]);
        load16_lds(ql_ + kb + scsrc, &Ks_l[bufn][wv * 512]);
        vreg = *(const bf16x8*)(qh_ + kb + 768 + sc8);
    };
    // transposed V write, key-XOR swizzled (2-way banks instead of 16-way)
    auto write_V = [&](int bufn, const bf16x8& vreg) {
#pragma unroll
        for (int j = 0; j < 8; ++j) {
            int d = sc8 + j;
            int keyx = srow ^ (((d >> 3) & 3) * 8);
            Vt_h[bufn][d * 40 + keyx] = vreg[j];
        }
    };

    // ---- prologue: stage tile 0 into buffer 0
    {
        bf16x8 v0;
        stage_issue(0, 0, v0);
        write_V(0, v0);                            // data dep inserts vmcnt wait
        asm volatile("s_waitcnt vmcnt(0)" ::: "memory");
        __syncthreads();
    }

    const float CEXP = 0.18033688011112042f;       // 0.125 * log2(e)

    for (int kt = 0; kt < nkt; ++kt) {
        const int cur = kt & 1, nxt = cur ^ 1;
        int kt2 = kt + 1; if (kt2 >= nkt) kt2 = nkt - 1;   // clamp (no OOB)
        bf16x8 vnext;
        stage_issue(kt2, nxt, vnext);              // overlaps with compute below

        if (tile <= 12) {
            bf16x8 kfh[2][2], kfl[2][2], vth[4];
#pragma unroll
            for (int nb = 0; nb < 2; ++nb)
#pragma unroll
                for (int p = 0; p < 2; ++p) {
                    int row = nb * 16 + l15;
                    int c = (p * 32 + q8 * 8) ^ ((row & 7) * 8);
                    kfh[nb][p] = *(const bf16x8*)&Ks_h[cur][row * 64 + c];
                    kfl[nb][p] = *(const bf16x8*)&Ks_l[cur][row * 64 + c];
                }
#pragma unroll
            for (int nd = 0; nd < 4; ++nd) {
                int d = nd * 16 + l15;
                int k8 = (q8 * 8) ^ (((d >> 3) & 3) * 8);
                vth[nd] = *(const bf16x8*)&Vt_h[cur][d * 40 + k8];
            }

            // QK^T: 4 independent depth-3 MFMA chains
            f32x4 s0a = {0.f,0.f,0.f,0.f}, s0b = {0.f,0.f,0.f,0.f};
            f32x4 s1a = {0.f,0.f,0.f,0.f}, s1b = {0.f,0.f,0.f,0.f};
            s0a = __builtin_amdgcn_mfma_f32_16x16x32_bf16(qfl[0], kfh[0][0], s0a, 0, 0, 0);
            s1a = __builtin_amdgcn_mfma_f32_16x16x32_bf16(qfl[0], kfh[1][0], s1a, 0, 0, 0);
            s0b = __builtin_amdgcn_mfma_f32_16x16x32_bf16(qfl[1], kfh[0][1], s0b, 0, 0, 0);
            s1b = __builtin_amdgcn_mfma_f32_16x16x32_bf16(qfl[1], kfh[1][1], s1b, 0, 0, 0);
            s0a = __builtin_amdgcn_mfma_f32_16x16x32_bf16(qfh[0], kfl[0][0], s0a, 0, 0, 0);
            s1a = __builtin_amdgcn_mfma_f32_16x16x32_bf16(qfh[0], kfl[1][0], s1a, 0, 0, 0);
            s0b = __builtin_amdgcn_mfma_f32_16x16x32_bf16(qfh[1], kfl[0][1], s0b, 0, 0, 0);
            s1b = __builtin_amdgcn_mfma_f32_16x16x32_bf16(qfh[1], kfl[1][1], s1b, 0, 0, 0);
            s0a = __builtin_amdgcn_mfma_f32_16x16x32_bf16(qfh[0], kfh[0][0], s0a, 0, 0, 0);
            s1a = __builtin_amdgcn_mfma_f32_16x16x32_bf16(qfh[0], kfh[1][0], s1a, 0, 0, 0);
            s0b = __builtin_amdgcn_mfma_f32_16x16x32_bf16(qfh[1], kfh[0][1], s0b, 0, 0, 0);
            s1b = __builtin_amdgcn_mfma_f32_16x16x32_bf16(qfh[1], kfh[1][1], s1b, 0, 0, 0);
            f32x4 s0 = s0a + s0b, s1 = s1a + s1b;

            // deferred softmax: p = exp(S/8), no max subtraction, no rescale
            const int key0 = kt * 32 + l15;
            const bool m0 = (key0 >= kmax), m1 = (key0 + 16 >= kmax);
#pragma unroll
            for (int r = 0; r < 4; ++r) {
                float p0 = m0 ? 0.0f : exp2f(s0[r] * CEXP);
                float p1 = m1 ? 0.0f : exp2f(s1[r] * CEXP);
                l_i[r] += p0 + p1;
                int pr = q8 * 4 + r;
                Pl_h[wv][pr * 40 + l15] = (bf16)p0;
                Pl_h[wv][pr * 40 + 16 + l15] = (bf16)p1;
            }
            asm volatile("s_waitcnt lgkmcnt(0)" ::: "memory");   // wave-private Pl RAW
            bf16x8 pfh = *(const bf16x8*)&Pl_h[wv][l15 * 40 + q8 * 8];
#pragma unroll
            for (int nd = 0; nd < 4; ++nd)
                oacc[nd] = __builtin_amdgcn_mfma_f32_16x16x32_bf16(pfh, vth[nd], oacc[nd], 0, 0, 0);
        }

        write_V(nxt, vnext);                       // waits vmcnt for vnext only here
        asm volatile("s_waitcnt vmcnt(0)" ::: "memory");
        __syncthreads();
    }

    if (tile <= 12) {
#pragma unroll
        for (int r = 0; r < 4; ++r) {
            float s = l_i[r];
#pragma unroll
            for (int off = 1; off < 16; off <<= 1) s += __shfl_xor(s, off, 64);
            int qr = tile * 16 + q8 * 4 + r;
            if (qr >= 196) continue;
            float inv = 1.0f / s;
            size_t row = (size_t)b * 784 + w * 196 + qr;
#pragma unroll
            for (int nd = 0; nd < 4; ++nd) {
                float ov = oacc[nd][r] * inv;
                bf16 oh = (bf16)ov;
                size_t idx = row * 768 + hh * 64 + nd * 16 + l15;
                oh_[idx] = oh;
                ol_[idx] = (bf16)(ov - (float)oh);
            }
        }
    }
}

// ---------------------------------------------------------------------------
// y = xres + p0 + p1 + b_out (fp32), y2 = LN2(y) planes, dout = y + b2ff
// (prefill for the atomic split-K w2 GEMM). Block per x-row (3136).
// ---------------------------------------------------------------------------
__global__ __launch_bounds__(256) void ln2_resid(
    const float* __restrict__ xres, const float* __restrict__ attP,
    const float* __restrict__ bo,
    const float* __restrict__ g2, const float* __restrict__ b2,
    const float* __restrict__ b2ff,
    float* __restrict__ y, bf16* __restrict__ y2H, bf16* __restrict__ y2L,
    float* __restrict__ dout)
{
    const int row = blockIdx.x;
    const size_t MN = (size_t)3136 * 768;
    const float* xr = xres + (size_t)row * 768;
    const float* a0 = attP + (size_t)row * 768;
    const float* a1 = attP + MN + (size_t)row * 768;
    const int t = threadIdx.x, lane = t & 63, wv = t >> 6;
    __shared__ float red[8];

    float v[3];
    float* yr = y + (size_t)row * 768;
    float* dr = dout + (size_t)row * 768;
#pragma unroll
    for (int i = 0; i < 3; ++i) {
        int c = i * 256 + t;
        v[i] = xr[c] + a0[c] + a1[c] + bo[c];
        yr[c] = v[i];
        dr[c] = v[i] + b2ff[c];
    }
    float s = v[0] + v[1] + v[2];
    float s2 = v[0] * v[0] + v[1] * v[1] + v[2] * v[2];
#pragma unroll
    for (int off = 1; off < 64; off <<= 1) { s += __shfl_xor(s, off, 64); s2 += __shfl_xor(s2, off, 64); }
    if (lane == 0) { red[wv] = s; red[4 + wv] = s2; }
    __syncthreads();
    s = red[0] + red[1] + red[2] + red[3];
    s2 = red[4] + red[5] + red[6] + red[7];
    float mu = s * (1.0f / 768.0f);
    float var = s2 * (1.0f / 768.0f) - mu * mu;
    float rs = rsqrtf(fmaxf(var, 0.0f) + 1e-5f);

    bf16* yh = y2H + (size_t)row * 768;
    bf16* yl = y2L + (size_t)row * 768;
#pragma unroll
    for (int i = 0; i < 3; ++i) {
        int c = i * 256 + t;
        float yv = (v[i] - mu) * rs * g2[c] + b2[c];
        bf16 yvh = (bf16)yv;
        yh[c] = yvh;
        yl[c] = (bf16)(yv - (float)yvh);
    }
}

// ---------------------------------------------------------------------------
extern "C" void kernel_launch(void* const* d_in, const int* in_sizes, int n_in,
                              void* d_out, int out_size, void* d_ws, size_t ws_size,
                              hipStream_t stream)
{
    (void)in_sizes; (void)n_in; (void)out_size; (void)ws_size;
    const float* x        = (const float*)d_in[0];
    const float* memory   = (const float*)d_in[1];
    const float* ln_att_g = (const float*)d_in[2];
    const float* ln_att_b = (const float*)d_in[3];
    const float* w_qkv    = (const float*)d_in[4];
    const float* w_out    = (const float*)d_in[5];
    const float* b_out    = (const float*)d_in[6];
    const float* ln1_g    = (const float*)d_in[7];
    const float* ln1_b    = (const float*)d_in[8];
    const float* ln2_g    = (const float*)d_in[9];
    const float* ln2_b    = (const float*)d_in[10];
    const float* w1       = (const float*)d_in[11];
    const float* b1       = (const float*)d_in[12];
    const float* w2       = (const float*)d_in[13];
    const float* b2       = (const float*)d_in[14];

    // ---- workspace layout (~109.7 MiB, same footprint) ----
    char* ws = (char*)d_ws;
    const size_t SZF  = (size_t)3136 * 768 * 4;
    const size_t SZP  = (size_t)3136 * 768 * 2;
    const size_t SZHP = (size_t)6272 * 768 * 2;
    const size_t SZQP = (size_t)6272 * 2304 * 2;
    const size_t SZFP = (size_t)3136 * 3072 * 2;

    float* xres = (float*)(ws);
    bf16* hH  = (bf16*)(ws + SZF);
    bf16* hL  = (bf16*)(ws + SZF + SZHP);
    bf16* aoH = (bf16*)(ws + SZF);
    bf16* aoL = (bf16*)(ws + SZF + SZP);
    bf16* y2H = (bf16*)(ws + SZF);
    bf16* y2L = (bf16*)(ws + SZF + SZP);
    const size_t OQ = SZF + 2 * SZHP;
    bf16* qkvH = (bf16*)(ws + OQ);
    bf16* qkvL = (bf16*)(ws + OQ + SZQP);
    float* y    = (float*)(ws + OQ);
    float* attP = (float*)(ws + OQ + SZF);   // 2 partials (dead qkv region; ffH overwrites later)
    bf16* ffH  = (bf16*)(ws + OQ + SZF);
    bf16* ffL  = (bf16*)(ws + OQ + SZF + SZFP);
    const size_t OW = OQ + 2 * SZQP;
    bf16* wqH = (bf16*)(ws + OW);
    bf16* wqL = (bf16*)(ws + OW + 3538944);
    bf16* woH = (bf16*)(ws + OW + 2 * 3538944);
    bf16* woL = (bf16*)(ws + OW + 2 * 3538944 + 1179648);
    bf16* w1H = (bf16*)(ws + OW + 2 * 3538944 + 2 * 1179648);
    bf16* w1L = (bf16*)(ws + OW + 2 * 3538944 + 2 * 1179648 + 4718592);
    bf16* w2H = (bf16*)(ws + OW + 2 * 3538944 + 2 * 1179648 + 2 * 4718592);
    bf16* w2L = (bf16*)(ws + OW + 2 * 3538944 + 2 * 1179648 + 3 * 4718592);

    // 0) all weight plane-splits in one dispatch
    split_all<<<2048, 256, 0, stream>>>(w_qkv, wqH, wqL, w_out, woH, woL,
                                        w1, w1H, w1L, w2, w2H, w2L);

    // 1) LN1 + LN_att
    prep_ln<<<6272, 256, 0, stream>>>(x, memory, ln1_g, ln1_b, ln_att_g, ln_att_b, xres, hH, hL);

    // 2) qkv planes = h @ w_qkv^T  (M=6272, N=2304, K=768) — 256x128 tile
    gemm_qkv<<<dim3(18, 25), 256, 0, stream>>>(hH, hL, wqH, wqL, 6272, 2304, 768,
                                               qkvH, qkvL);

    // 3) attention  (grid: x = hh+12*b, y = w*4+g  -> XCD-local K/V sharing)
    attn_kernel<<<dim3(48, 16), 256, 0, stream>>>(qkvH, qkvL, aoH, aoL);

    // 4) att partials = ao @ w_out^T  (M=3136, N=768, K=768, split-K=2) — row-chunked
    gemm_pl<1, 0><<<dim3(6, 25, 2), 256, 0, stream>>>(aoH, aoL, woH, woL, 3136, 768, 768,
                                                      nullptr, nullptr, attP, nullptr, nullptr);

    // 5) y = xres + p0 + p1 + b_out ; y2 planes = LN2(y) ; dout prefill = y + b2
    ln2_resid<<<3136, 256, 0, stream>>>(xres, attP, b_out, ln2_g, ln2_b, b2,
                                        y, y2H, y2L, (float*)d_out);

    // 6) ff planes = silu(y2 @ w1^T + b1)  (M=3136, N=3072, K=768) — col-chunked (w1-heavy)
    gemm_pl<2, 1><<<dim3(24, 25), 256, 0, stream>>>(y2H, y2L, w1H, w1L, 3136, 3072, 768,
                                                    b1, nullptr, nullptr, ffH, ffL);

    // 7) d_out += ff @ w2^T  (M=3136, N=768, K=3072, split-K=4, atomic) — row-chunked
    gemm_pl<3, 0><<<dim3(6, 25, 4), 256, 0, stream>>>(ffH, ffL, w2H, w2L, 3136, 768, 3072,
                                                      nullptr, nullptr, (float*)d_out, nullptr, nullptr);
}

// Round 9
// 423.325 us; speedup vs baseline: 1.2631x; 1.0282x over previous
//
#include <hip/hip_runtime.h>
#include <cstdint>

typedef __bf16 bf16;
typedef __bf16 bf16x4 __attribute__((ext_vector_type(4)));
typedef __bf16 bf16x8 __attribute__((ext_vector_type(8)));
typedef float f32x4 __attribute__((ext_vector_type(4)));

#define AS1 __attribute__((address_space(1)))
#define AS3 __attribute__((address_space(3)))

// Async global->LDS, 16B per lane. LDS dest must be wave-uniform base;
// HW writes lane i at base + i*16 (m97/m104 semantics).
__device__ __forceinline__ void load16_lds(const void* gp, void* lds_base_wave_uniform) {
    __builtin_amdgcn_global_load_lds((AS1 void*)((void*)gp),
                                     (AS3 void*)lds_base_wave_uniform, 16, 0, 0);
}

// ---------------------------------------------------------------------------
// Fused: LN1 -> xres + LN_att -> h planes (blocks 0..6271), and all 4 weight
// plane-splits (blocks 6272..8319, grid-stride float4).
// NOTE: weight params named wp0..wp3 — body declares `float s2` at outermost
// scope, and C++ forbids shadowing a PARAMETER there (R8 compile failure).
// ---------------------------------------------------------------------------
__global__ __launch_bounds__(256) void prep_ln_split(
    const float* __restrict__ x, const float* __restrict__ memory,
    const float* __restrict__ g1, const float* __restrict__ b1,
    const float* __restrict__ ga, const float* __restrict__ ba,
    float* __restrict__ xres, bf16* __restrict__ hH, bf16* __restrict__ hL,
    const float* __restrict__ wp0, bf16* __restrict__ wh0, bf16* __restrict__ wl0,
    const float* __restrict__ wp1, bf16* __restrict__ wh1, bf16* __restrict__ wl1,
    const float* __restrict__ wp2, bf16* __restrict__ wh2, bf16* __restrict__ wl2,
    const float* __restrict__ wp3, bf16* __restrict__ wh3, bf16* __restrict__ wl3)
{
    const int t = threadIdx.x;
    if (blockIdx.x >= 6272) {
        // ---- weight split path (2048 blocks, grid-stride) ----
        const int n0q = 442368, n1q = 147456, n2q = 589824;
        const int total = 1769472;
        const int stride = 2048 * 256;
        for (int i = (blockIdx.x - 6272) * 256 + t; i < total; i += stride) {
            const float* sp; bf16 *hp, *lp; int j = i;
            if (j < n0q) { sp = wp0; hp = wh0; lp = wl0; }
            else if ((j -= n0q) < n1q) { sp = wp1; hp = wh1; lp = wl1; }
            else if ((j -= n1q) < n2q) { sp = wp2; hp = wh2; lp = wl2; }
            else { j -= n2q; sp = wp3; hp = wh3; lp = wl3; }
            float4 v4 = reinterpret_cast<const float4*>(sp)[j];
            bf16x4 hi, lo;
            hi[0] = (bf16)v4.x; lo[0] = (bf16)(v4.x - (float)hi[0]);
            hi[1] = (bf16)v4.y; lo[1] = (bf16)(v4.y - (float)hi[1]);
            hi[2] = (bf16)v4.z; lo[2] = (bf16)(v4.z - (float)hi[2]);
            hi[3] = (bf16)v4.w; lo[3] = (bf16)(v4.w - (float)hi[3]);
            reinterpret_cast<bf16x4*>(hp)[j] = hi;
            reinterpret_cast<bf16x4*>(lp)[j] = lo;
        }
        return;
    }

    // ---- LN path ----
    const int row = blockIdx.x;            // 0..6271
    const int b = row / 1568, l = row - b * 1568;
    const float* src = (l < 784) ? (memory + ((size_t)b * 1024 + l) * 768)
                                 : (x + ((size_t)b * 784 + (l - 784)) * 768);
    const int lane = t & 63, wv = t >> 6;
    __shared__ float red[8];

    float v[3];
#pragma unroll
    for (int i = 0; i < 3; ++i) v[i] = src[i * 256 + t];

    float s = v[0] + v[1] + v[2];
    float s2 = v[0] * v[0] + v[1] * v[1] + v[2] * v[2];
#pragma unroll
    for (int off = 1; off < 64; off <<= 1) { s += __shfl_xor(s, off, 64); s2 += __shfl_xor(s2, off, 64); }
    if (lane == 0) { red[wv] = s; red[4 + wv] = s2; }
    __syncthreads();
    s = red[0] + red[1] + red[2] + red[3];
    s2 = red[4] + red[5] + red[6] + red[7];
    float mu = s * (1.0f / 768.0f);
    float var = s2 * (1.0f / 768.0f) - mu * mu;
    float rs = rsqrtf(fmaxf(var, 0.0f) + 1e-5f);

    float w[3];
#pragma unroll
    for (int i = 0; i < 3; ++i) {
        int c = i * 256 + t;
        w[i] = (v[i] - mu) * rs * g1[c] + b1[c];
    }
    if (l >= 784) {
        float* xr = xres + ((size_t)b * 784 + (l - 784)) * 768;
#pragma unroll
        for (int i = 0; i < 3; ++i) xr[i * 256 + t] = w[i];
    }

    s = w[0] + w[1] + w[2];
    s2 = w[0] * w[0] + w[1] * w[1] + w[2] * w[2];
#pragma unroll
    for (int off = 1; off < 64; off <<= 1) { s += __shfl_xor(s, off, 64); s2 += __shfl_xor(s2, off, 64); }
    __syncthreads();
    if (lane == 0) { red[wv] = s; red[4 + wv] = s2; }
    __syncthreads();
    s = red[0] + red[1] + red[2] + red[3];
    s2 = red[4] + red[5] + red[6] + red[7];
    float mu2 = s * (1.0f / 768.0f);
    float var2 = s2 * (1.0f / 768.0f) - mu2 * mu2;
    float rs2 = rsqrtf(fmaxf(var2, 0.0f) + 1e-5f);

    bf16* hh_ = hH + (size_t)row * 768;
    bf16* hl_ = hL + (size_t)row * 768;
#pragma unroll
    for (int i = 0; i < 3; ++i) {
        int c = i * 256 + t;
        float hv = (w[i] - mu2) * rs2 * ga[c] + ba[c];
        bf16 hvh = (bf16)hv;
        hh_[c] = hvh;
        hl_[c] = (bf16)(hv - (float)hvh);
    }
}

// ---------------------------------------------------------------------------
// QKV GEMM, 256x128 tile, m97 single-buffer schedule, involution staging,
// bijective XCD row-chunking. V-tiles (col0>=1536): output consumed as bf16-hi
// only, so drop the ah*bl term (error ~2^-9 << V's own 2^-8 quantization) and
// skip Bl staging/reads entirely -> 2/3 MFMA, 5/6 staging on 6/18 of blocks.
// ---------------------------------------------------------------------------
__global__ __launch_bounds__(256, 2) void gemm_qkv(
    const bf16* __restrict__ Ah, const bf16* __restrict__ Al,
    const bf16* __restrict__ Bh, const bf16* __restrict__ Bl,
    int M, int N, int K,
    bf16* __restrict__ Ch, bf16* __restrict__ Cl)
{
    __shared__ __align__(16) bf16 Ahs[256 * 32], Als[256 * 32];
    __shared__ __align__(16) bf16 Bhs[128 * 32], Bls[128 * 32];
    const int t = threadIdx.x, lane = t & 63, wv = t >> 6;

    // bijective XCD chunking (m204), row-chunk order
    const int nx = gridDim.x, ny = gridDim.y;
    int orig = blockIdx.x + nx * blockIdx.y;
    int nwg = nx * ny;
    int q = nwg >> 3, rr8 = nwg & 7;
    int xcd = orig & 7, pos = orig >> 3;
    int wgid = (xcd < rr8 ? xcd * (q + 1) : rr8 * (q + 1) + (xcd - rr8) * q) + pos;
    int bx = wgid % nx, by = wgid / nx;

    const int row0 = by * 256, col0 = bx * 128;
    const bool vtile = (col0 >= 1536);       // block-uniform
    const int ro = (wv >> 1) * 128, co = (wv & 1) * 64;
    const int l15 = lane & 15, q8 = lane >> 4;
    const int cs = (q8 ^ (l15 & 3)) * 8;     // involution chunk for fragment reads

    f32x4 acc[8][4] = {};

    for (int k0 = 0; k0 < K; k0 += 32) {
#pragma unroll
        for (int it = 0; it < 4; ++it) {              // A: 256 rows
            int f = it * 256 + t;
            int r = f >> 2;
            int kc = ((f & 3) ^ (r & 3)) * 8;
            int ra = row0 + r; if (ra >= M) ra = M - 1;
            size_t oa = (size_t)ra * K + k0 + kc;
            size_t lb = (size_t)(it * 256 + wv * 64) * 8;
            load16_lds(Ah + oa, Ahs + lb);
            load16_lds(Al + oa, Als + lb);
        }
#pragma unroll
        for (int it = 0; it < 2; ++it) {              // B: 128 rows
            int f = it * 256 + t;
            int r = f >> 2;
            int kc = ((f & 3) ^ (r & 3)) * 8;
            size_t ob = (size_t)(col0 + r) * K + k0 + kc;
            size_t lb = (size_t)(it * 256 + wv * 64) * 8;
            load16_lds(Bh + ob, Bhs + lb);
            if (!vtile) load16_lds(Bl + ob, Bls + lb);
        }
        asm volatile("s_waitcnt vmcnt(0)" ::: "memory");
        __syncthreads();

        bf16x8 bh[4], bl[4];
#pragma unroll
        for (int j = 0; j < 4; ++j) {
            int o = (co + j * 16 + l15) * 32 + cs;
            bh[j] = *(const bf16x8*)&Bhs[o];
            if (!vtile) bl[j] = *(const bf16x8*)&Bls[o];
        }
#pragma unroll
        for (int i = 0; i < 8; ++i) {
            int o = (ro + i * 16 + l15) * 32 + cs;
            bf16x8 ah = *(const bf16x8*)&Ahs[o];
            bf16x8 al = *(const bf16x8*)&Als[o];
#pragma unroll
            for (int j = 0; j < 4; ++j) {
                acc[i][j] = __builtin_amdgcn_mfma_f32_16x16x32_bf16(al, bh[j], acc[i][j], 0, 0, 0);
                if (!vtile)
                    acc[i][j] = __builtin_amdgcn_mfma_f32_16x16x32_bf16(ah, bl[j], acc[i][j], 0, 0, 0);
                acc[i][j] = __builtin_amdgcn_mfma_f32_16x16x32_bf16(ah, bh[j], acc[i][j], 0, 0, 0);
            }
        }
        __syncthreads();
    }

#pragma unroll
    for (int i = 0; i < 8; ++i)
#pragma unroll
        for (int j = 0; j < 4; ++j)
#pragma unroll
            for (int r = 0; r < 4; ++r) {
                int row = row0 + ro + i * 16 + q8 * 4 + r;
                int col = col0 + co + j * 16 + l15;
                if (row >= M) continue;
                float v = acc[i][j][r];
                size_t idx = (size_t)row * N + col;
                bf16 hh = (bf16)v;
                Ch[idx] = hh;
                if (col < 1536) Cl[idx] = (bf16)(v - (float)hh);  // V-lo never read
            }
}

// ---------------------------------------------------------------------------
// Plane GEMM, m97 single-buffer schedule + involution staging + XCD chunking
// (R6-verified). 128x128 tile, BK=32, 4 waves x 64x64. Split-K via gridDim.z.
// MODE 1: fp32 partial -> Cf + z*M*N. 2: silu planes out. 3: atomic += Cf.
// ---------------------------------------------------------------------------
template <int MODE, int ORD>
__global__ __launch_bounds__(256, 2) void gemm_pl(
    const bf16* __restrict__ Ah, const bf16* __restrict__ Al,
    const bf16* __restrict__ Bh, const bf16* __restrict__ Bl,
    int M, int N, int K,
    const float* __restrict__ bias, const float* __restrict__ resid,
    float* __restrict__ Cf, bf16* __restrict__ Ch, bf16* __restrict__ Cl)
{
    __shared__ __align__(16) bf16 Ahs[128 * 32], Als[128 * 32];
    __shared__ __align__(16) bf16 Bhs[128 * 32], Bls[128 * 32];
    const int t = threadIdx.x, lane = t & 63, wv = t >> 6;

    // ---- bijective XCD chunking (m204) ----
    const int nx = gridDim.x, ny = gridDim.y;
    int orig = blockIdx.x + nx * blockIdx.y;
    int nwg = nx * ny;
    int q = nwg >> 3, rr8 = nwg & 7;
    int xcd = orig & 7, pos = orig >> 3;
    int wgid = (xcd < rr8 ? xcd * (q + 1) : rr8 * (q + 1) + (xcd - rr8) * q) + pos;
    int bx, by;
    if (ORD == 0) { bx = wgid % nx; by = wgid / nx; }   // row chunks (A-heavy)
    else          { by = wgid % ny; bx = wgid / ny; }   // col chunks (B-heavy)

    const int row0 = by * 128, col0 = bx * 128;
    const int ro = (wv >> 1) * 64, co = (wv & 1) * 64;
    const int Kc = K / gridDim.z;
    const int kbeg = blockIdx.z * Kc, kend = kbeg + Kc;
    const int l15 = lane & 15, q8 = lane >> 4;
    const int cs = (q8 ^ (l15 & 3)) * 8;     // involution chunk for fragment reads

    f32x4 acc[4][4] = {};

    for (int k0 = kbeg; k0 < kend; k0 += 32) {
#pragma unroll
        for (int it = 0; it < 2; ++it) {
            int f = it * 256 + t;
            int r = f >> 2;                          // tile row (4 lanes per row)
            int kc = ((f & 3) ^ (r & 3)) * 8;        // involution within 64B line
            int ra = row0 + r; if (ra >= M) ra = M - 1;
            size_t oa = (size_t)ra * K + k0 + kc;
            size_t ob = (size_t)(col0 + r) * K + k0 + kc;
            size_t lb = (size_t)(it * 256 + wv * 64) * 8;
            load16_lds(Ah + oa, Ahs + lb);
            load16_lds(Al + oa, Als + lb);
            load16_lds(Bh + ob, Bhs + lb);
            load16_lds(Bl + ob, Bls + lb);
        }
        asm volatile("s_waitcnt vmcnt(0)" ::: "memory");
        __syncthreads();
        bf16x8 ah[4], al[4], bh[4], bl[4];
#pragma unroll
        for (int i = 0; i < 4; ++i) {
            int o = (ro + i * 16 + l15) * 32 + cs;   // (row&3)==(l15&3)
            ah[i] = *(const bf16x8*)&Ahs[o];
            al[i] = *(const bf16x8*)&Als[o];
        }
#pragma unroll
        for (int j = 0; j < 4; ++j) {
            int o = (co + j * 16 + l15) * 32 + cs;
            bh[j] = *(const bf16x8*)&Bhs[o];
            bl[j] = *(const bf16x8*)&Bls[o];
        }
#pragma unroll
        for (int i = 0; i < 4; ++i)
#pragma unroll
            for (int j = 0; j < 4; ++j) {
                acc[i][j] = __builtin_amdgcn_mfma_f32_16x16x32_bf16(al[i], bh[j], acc[i][j], 0, 0, 0);
                acc[i][j] = __builtin_amdgcn_mfma_f32_16x16x32_bf16(ah[i], bl[j], acc[i][j], 0, 0, 0);
                acc[i][j] = __builtin_amdgcn_mfma_f32_16x16x32_bf16(ah[i], bh[j], acc[i][j], 0, 0, 0);
            }
        __syncthreads();
    }

    const size_t zoff = (size_t)blockIdx.z * M * N;
#pragma unroll
    for (int i = 0; i < 4; ++i)
#pragma unroll
        for (int j = 0; j < 4; ++j)
#pragma unroll
            for (int r = 0; r < 4; ++r) {
                int row = row0 + ro + i * 16 + (lane >> 4) * 4 + r;
                int col = col0 + co + j * 16 + (lane & 15);
                if (row >= M) continue;
                float v = acc[i][j][r];
                size_t idx = (size_t)row * N + col;
                if (MODE == 1) {
                    Cf[zoff + idx] = v;               // partial, bias added later
                } else if (MODE == 2) {
                    v += bias[col];
                    v = v / (1.0f + __expf(-v));
                    bf16 hh = (bf16)v;
                    Ch[idx] = hh; Cl[idx] = (bf16)(v - (float)hh);
                } else {
                    unsafeAtomicAdd(&Cf[idx], v);     // HW f32 atomic, prefilled dest
                }
            }
}

// ---------------------------------------------------------------------------
// Flash attention, pipelined. Grid: x = hh + 12*b (48), y = w*4+g (16).
// Deferred softmax (bounded logits), single barrier per K-tile, swizzled K
// via pre-swizzled global_load_lds source, V reg-prefetch + 2-way-bank
// transposed write. setprio(1) around MFMA clusters (m191: +4-7% attn).
// ---------------------------------------------------------------------------
__global__ __launch_bounds__(256, 3) void attn_kernel(
    const bf16* __restrict__ qh_, const bf16* __restrict__ ql_,
    bf16* __restrict__ oh_, bf16* __restrict__ ol_)
{
    const int hh = blockIdx.x % 12, b = blockIdx.x / 12;
    const int w = blockIdx.y >> 2, g = blockIdx.y & 3;
    const int kmax = (5 + w) * 196, nkt = (kmax + 31) / 32;
    const int t = threadIdx.x, lane = t & 63, wv = t >> 6;
    const int tile = g * 4 + wv;                  // 0..15; >12 idle (wave-uniform)
    const int l15 = lane & 15, q8 = lane >> 4;

    __shared__ __align__(16) bf16 Ks_h[2][32 * 64], Ks_l[2][32 * 64];
    __shared__ __align__(16) bf16 Vt_h[2][64 * 40];
    __shared__ __align__(16) bf16 Pl_h[4][16 * 40];

    const size_t bbase = (size_t)b * 1568 * 2304;

    // staging geometry: thread t covers K/V row srow, col chunk sc8.
    const int srow = t >> 3;                      // 0..31 (wave wv: rows wv*8..+7)
    const int sc8 = (t & 7) * 8;
    // K: LDS dest is linear (global_load_lds), so pre-swizzle the SOURCE col.
    const int scsrc = sc8 ^ ((srow & 7) * 8);

    // Q fragments (held in registers for the whole kernel)
    int tcl = tile > 12 ? 12 : tile;
    int qr0 = tcl * 16 + l15; if (qr0 > 195) qr0 = 195;
    const size_t qoff = bbase + (size_t)(784 + w * 196 + qr0) * 2304 + hh * 64 + q8 * 8;
    bf16x8 qfh[2], qfl[2];
#pragma unroll
    for (int p = 0; p < 2; ++p) {
        qfh[p] = *(const bf16x8*)(qh_ + qoff + p * 32);
        qfl[p] = *(const bf16x8*)(ql_ + qoff + p * 32);
    }

    float l_i[4] = {0.f, 0.f, 0.f, 0.f};
    f32x4 oacc[4];
#pragma unroll
    for (int nd = 0; nd < 4; ++nd) oacc[nd] = f32x4{0.f, 0.f, 0.f, 0.f};

    // issue staging for K-tile kt2 into buffer bufn; V -> vreg (not yet in LDS)
    auto stage_issue = [&](int kt2, int bufn, bf16x8& vreg) {
        const size_t kb = bbase + (size_t)(kt2 * 32 + srow) * 2304 + 768 + (size_t)hh * 64;
        load16_lds(qh_ + kb + scsrc, &Ks_h[bufn][wv * 512]);
        load16_lds(ql_ + kb + scsrc, &Ks_l[bufn][wv * 512]);
        vreg = *(const bf16x8*)(qh_ + kb + 768 + sc8);
    };
    // transposed V write, key-XOR swizzled (2-way banks instead of 16-way)
    auto write_V = [&](int bufn, const bf16x8& vreg) {
#pragma unroll
        for (int j = 0; j < 8; ++j) {
            int d = sc8 + j;
            int keyx = srow ^ (((d >> 3) & 3) * 8);
            Vt_h[bufn][d * 40 + keyx] = vreg[j];
        }
    };

    // ---- prologue: stage tile 0 into buffer 0
    {
        bf16x8 v0;
        stage_issue(0, 0, v0);
        write_V(0, v0);                            // data dep inserts vmcnt wait
        asm volatile("s_waitcnt vmcnt(0)" ::: "memory");
        __syncthreads();
    }

    const float CEXP = 0.18033688011112042f;       // 0.125 * log2(e)

    for (int kt = 0; kt < nkt; ++kt) {
        const int cur = kt & 1, nxt = cur ^ 1;
        int kt2 = kt + 1; if (kt2 >= nkt) kt2 = nkt - 1;   // clamp (no OOB)
        bf16x8 vnext;
        stage_issue(kt2, nxt, vnext);              // overlaps with compute below

        if (tile <= 12) {
            bf16x8 kfh[2][2], kfl[2][2], vth[4];
#pragma unroll
            for (int nb = 0; nb < 2; ++nb)
#pragma unroll
                for (int p = 0; p < 2; ++p) {
                    int row = nb * 16 + l15;
                    int c = (p * 32 + q8 * 8) ^ ((row & 7) * 8);
                    kfh[nb][p] = *(const bf16x8*)&Ks_h[cur][row * 64 + c];
                    kfl[nb][p] = *(const bf16x8*)&Ks_l[cur][row * 64 + c];
                }
#pragma unroll
            for (int nd = 0; nd < 4; ++nd) {
                int d = nd * 16 + l15;
                int k8 = (q8 * 8) ^ (((d >> 3) & 3) * 8);
                vth[nd] = *(const bf16x8*)&Vt_h[cur][d * 40 + k8];
            }

            // QK^T: 4 independent depth-3 MFMA chains
            f32x4 s0a = {0.f,0.f,0.f,0.f}, s0b = {0.f,0.f,0.f,0.f};
            f32x4 s1a = {0.f,0.f,0.f,0.f}, s1b = {0.f,0.f,0.f,0.f};
            __builtin_amdgcn_s_setprio(1);
            s0a = __builtin_amdgcn_mfma_f32_16x16x32_bf16(qfl[0], kfh[0][0], s0a, 0, 0, 0);
            s1a = __builtin_amdgcn_mfma_f32_16x16x32_bf16(qfl[0], kfh[1][0], s1a, 0, 0, 0);
            s0b = __builtin_amdgcn_mfma_f32_16x16x32_bf16(qfl[1], kfh[0][1], s0b, 0, 0, 0);
            s1b = __builtin_amdgcn_mfma_f32_16x16x32_bf16(qfl[1], kfh[1][1], s1b, 0, 0, 0);
            s0a = __builtin_amdgcn_mfma_f32_16x16x32_bf16(qfh[0], kfl[0][0], s0a, 0, 0, 0);
            s1a = __builtin_amdgcn_mfma_f32_16x16x32_bf16(qfh[0], kfl[1][0], s1a, 0, 0, 0);
            s0b = __builtin_amdgcn_mfma_f32_16x16x32_bf16(qfh[1], kfl[0][1], s0b, 0, 0, 0);
            s1b = __builtin_amdgcn_mfma_f32_16x16x32_bf16(qfh[1], kfl[1][1], s1b, 0, 0, 0);
            s0a = __builtin_amdgcn_mfma_f32_16x16x32_bf16(qfh[0], kfh[0][0], s0a, 0, 0, 0);
            s1a = __builtin_amdgcn_mfma_f32_16x16x32_bf16(qfh[0], kfh[1][0], s1a, 0, 0, 0);
            s0b = __builtin_amdgcn_mfma_f32_16x16x32_bf16(qfh[1], kfh[0][1], s0b, 0, 0, 0);
            s1b = __builtin_amdgcn_mfma_f32_16x16x32_bf16(qfh[1], kfh[1][1], s1b, 0, 0, 0);
            __builtin_amdgcn_s_setprio(0);
            f32x4 s0 = s0a + s0b, s1 = s1a + s1b;

            // deferred softmax: p = exp(S/8), no max subtraction, no rescale
            const int key0 = kt * 32 + l15;
            const bool m0 = (key0 >= kmax), m1 = (key0 + 16 >= kmax);
#pragma unroll
            for (int r = 0; r < 4; ++r) {
                float p0 = m0 ? 0.0f : exp2f(s0[r] * CEXP);
                float p1 = m1 ? 0.0f : exp2f(s1[r] * CEXP);
                l_i[r] += p0 + p1;
                int pr = q8 * 4 + r;
                Pl_h[wv][pr * 40 + l15] = (bf16)p0;
                Pl_h[wv][pr * 40 + 16 + l15] = (bf16)p1;
            }
            asm volatile("s_waitcnt lgkmcnt(0)" ::: "memory");   // wave-private Pl RAW
            bf16x8 pfh = *(const bf16x8*)&Pl_h[wv][l15 * 40 + q8 * 8];
            __builtin_amdgcn_s_setprio(1);
#pragma unroll
            for (int nd = 0; nd < 4; ++nd)
                oacc[nd] = __builtin_amdgcn_mfma_f32_16x16x32_bf16(pfh, vth[nd], oacc[nd], 0, 0, 0);
            __builtin_amdgcn_s_setprio(0);
        }

        write_V(nxt, vnext);                       // waits vmcnt for vnext only here
        asm volatile("s_waitcnt vmcnt(0)" ::: "memory");
        __syncthreads();
    }

    if (tile <= 12) {
#pragma unroll
        for (int r = 0; r < 4; ++r) {
            float s = l_i[r];
#pragma unroll
            for (int off = 1; off < 16; off <<= 1) s += __shfl_xor(s, off, 64);
            int qr = tile * 16 + q8 * 4 + r;
            if (qr >= 196) continue;
            float inv = 1.0f / s;
            size_t row = (size_t)b * 784 + w * 196 + qr;
#pragma unroll
            for (int nd = 0; nd < 4; ++nd) {
                float ov = oacc[nd][r] * inv;
                bf16 oh = (bf16)ov;
                size_t idx = row * 768 + hh * 64 + nd * 16 + l15;
                oh_[idx] = oh;
                ol_[idx] = (bf16)(ov - (float)oh);
            }
        }
    }
}

// ---------------------------------------------------------------------------
// y = xres + p0 + p1 + b_out (fp32), y2 = LN2(y) planes, dout = y + b2ff
// (prefill for the atomic split-K w2 GEMM). Block per x-row (3136).
// ---------------------------------------------------------------------------
__global__ __launch_bounds__(256) void ln2_resid(
    const float* __restrict__ xres, const float* __restrict__ attP,
    const float* __restrict__ bo,
    const float* __restrict__ g2, const float* __restrict__ b2,
    const float* __restrict__ b2ff,
    float* __restrict__ y, bf16* __restrict__ y2H, bf16* __restrict__ y2L,
    float* __restrict__ dout)
{
    const int row = blockIdx.x;
    const size_t MN = (size_t)3136 * 768;
    const float* xr = xres + (size_t)row * 768;
    const float* a0 = attP + (size_t)row * 768;
    const float* a1 = attP + MN + (size_t)row * 768;
    const int t = threadIdx.x, lane = t & 63, wv = t >> 6;
    __shared__ float red[8];

    float v[3];
    float* yr = y + (size_t)row * 768;
    float* dr = dout + (size_t)row * 768;
#pragma unroll
    for (int i = 0; i < 3; ++i) {
        int c = i * 256 + t;
        v[i] = xr[c] + a0[c] + a1[c] + bo[c];
        yr[c] = v[i];
        dr[c] = v[i] + b2ff[c];
    }
    float s = v[0] + v[1] + v[2];
    float s2 = v[0] * v[0] + v[1] * v[1] + v[2] * v[2];
#pragma unroll
    for (int off = 1; off < 64; off <<= 1) { s += __shfl_xor(s, off, 64); s2 += __shfl_xor(s2, off, 64); }
    if (lane == 0) { red[wv] = s; red[4 + wv] = s2; }
    __syncthreads();
    s = red[0] + red[1] + red[2] + red[3];
    s2 = red[4] + red[5] + red[6] + red[7];
    float mu = s * (1.0f / 768.0f);
    float var = s2 * (1.0f / 768.0f) - mu * mu;
    float rs = rsqrtf(fmaxf(var, 0.0f) + 1e-5f);

    bf16* yh = y2H + (size_t)row * 768;
    bf16* yl = y2L + (size_t)row * 768;
#pragma unroll
    for (int i = 0; i < 3; ++i) {
        int c = i * 256 + t;
        float yv = (v[i] - mu) * rs * g2[c] + b2[c];
        bf16 yvh = (bf16)yv;
        yh[c] = yvh;
        yl[c] = (bf16)(yv - (float)yvh);
    }
}

// ---------------------------------------------------------------------------
extern "C" void kernel_launch(void* const* d_in, const int* in_sizes, int n_in,
                              void* d_out, int out_size, void* d_ws, size_t ws_size,
                              hipStream_t stream)
{
    (void)in_sizes; (void)n_in; (void)out_size; (void)ws_size;
    const float* x        = (const float*)d_in[0];
    const float* memory   = (const float*)d_in[1];
    const float* ln_att_g = (const float*)d_in[2];
    const float* ln_att_b = (const float*)d_in[3];
    const float* w_qkv    = (const float*)d_in[4];
    const float* w_out    = (const float*)d_in[5];
    const float* b_out    = (const float*)d_in[6];
    const float* ln1_g    = (const float*)d_in[7];
    const float* ln1_b    = (const float*)d_in[8];
    const float* ln2_g    = (const float*)d_in[9];
    const float* ln2_b    = (const float*)d_in[10];
    const float* w1       = (const float*)d_in[11];
    const float* b1       = (const float*)d_in[12];
    const float* w2       = (const float*)d_in[13];
    const float* b2       = (const float*)d_in[14];

    // ---- workspace layout (~109.7 MiB, same footprint) ----
    char* ws = (char*)d_ws;
    const size_t SZF  = (size_t)3136 * 768 * 4;
    const size_t SZP  = (size_t)3136 * 768 * 2;
    const size_t SZHP = (size_t)6272 * 768 * 2;
    const size_t SZQP = (size_t)6272 * 2304 * 2;
    const size_t SZFP = (size_t)3136 * 3072 * 2;

    float* xres = (float*)(ws);
    bf16* hH  = (bf16*)(ws + SZF);
    bf16* hL  = (bf16*)(ws + SZF + SZHP);
    bf16* aoH = (bf16*)(ws + SZF);
    bf16* aoL = (bf16*)(ws + SZF + SZP);
    bf16* y2H = (bf16*)(ws + SZF);
    bf16* y2L = (bf16*)(ws + SZF + SZP);
    const size_t OQ = SZF + 2 * SZHP;
    bf16* qkvH = (bf16*)(ws + OQ);
    bf16* qkvL = (bf16*)(ws + OQ + SZQP);
    float* y    = (float*)(ws + OQ);
    float* attP = (float*)(ws + OQ + SZF);   // 2 partials (dead qkv region; ffH overwrites later)
    bf16* ffH  = (bf16*)(ws + OQ + SZF);
    bf16* ffL  = (bf16*)(ws + OQ + SZF + SZFP);
    const size_t OW = OQ + 2 * SZQP;
    bf16* wqH = (bf16*)(ws + OW);
    bf16* wqL = (bf16*)(ws + OW + 3538944);
    bf16* woH = (bf16*)(ws + OW + 2 * 3538944);
    bf16* woL = (bf16*)(ws + OW + 2 * 3538944 + 1179648);
    bf16* w1H = (bf16*)(ws + OW + 2 * 3538944 + 2 * 1179648);
    bf16* w1L = (bf16*)(ws + OW + 2 * 3538944 + 2 * 1179648 + 4718592);
    bf16* w2H = (bf16*)(ws + OW + 2 * 3538944 + 2 * 1179648 + 2 * 4718592);
    bf16* w2L = (bf16*)(ws + OW + 2 * 3538944 + 2 * 1179648 + 3 * 4718592);

    // 0+1) fused: LN1 + LN_att (6272 blocks) and weight plane-splits (2048 blocks)
    prep_ln_split<<<8320, 256, 0, stream>>>(x, memory, ln1_g, ln1_b, ln_att_g, ln_att_b,
                                            xres, hH, hL,
                                            w_qkv, wqH, wqL, w_out, woH, woL,
                                            w1, w1H, w1L, w2, w2H, w2L);

    // 2) qkv planes = h @ w_qkv^T  (M=6272, N=2304, K=768) — 256x128 tile
    gemm_qkv<<<dim3(18, 25), 256, 0, stream>>>(hH, hL, wqH, wqL, 6272, 2304, 768,
                                               qkvH, qkvL);

    // 3) attention  (grid: x = hh+12*b, y = w*4+g  -> XCD-local K/V sharing)
    attn_kernel<<<dim3(48, 16), 256, 0, stream>>>(qkvH, qkvL, aoH, aoL);

    // 4) att partials = ao @ w_out^T  (M=3136, N=768, K=768, split-K=2) — row-chunked
    gemm_pl<1, 0><<<dim3(6, 25, 2), 256, 0, stream>>>(aoH, aoL, woH, woL, 3136, 768, 768,
                                                      nullptr, nullptr, attP, nullptr, nullptr);

    // 5) y = xres + p0 + p1 + b_out ; y2 planes = LN2(y) ; dout prefill = y + b2
    ln2_resid<<<3136, 256, 0, stream>>>(xres, attP, b_out, ln2_g, ln2_b, b2,
                                        y, y2H, y2L, (float*)d_out);

    // 6) ff planes = silu(y2 @ w1^T + b1)  (M=3136, N=3072, K=768) — col-chunked (w1-heavy)
    gemm_pl<2, 1><<<dim3(24, 25), 256, 0, stream>>>(y2H, y2L, w1H, w1L, 3136, 3072, 768,
                                                    b1, nullptr, nullptr, ffH, ffL);

    // 7) d_out += ff @ w2^T  (M=3136, N=768, K=3072, split-K=4, atomic) — row-chunked
    gemm_pl<3, 0><<<dim3(6, 25, 4), 256, 0, stream>>>(ffH, ffL, w2H, w2L, 3136, 768, 3072,
                                                      nullptr, nullptr, (float*)d_out, nullptr, nullptr);
}

// Round 10
// 411.766 us; speedup vs baseline: 1.2985x; 1.0281x over previous
//
#include <hip/hip_runtime.h>
#include <cstdint>

typedef __bf16 bf16;
typedef __bf16 bf16x4 __attribute__((ext_vector_type(4)));
typedef __bf16 bf16x8 __attribute__((ext_vector_type(8)));
typedef float f32x4 __attribute__((ext_vector_type(4)));

#define AS1 __attribute__((address_space(1)))
#define AS3 __attribute__((address_space(3)))

// Async global->LDS, 16B per lane. LDS dest must be wave-uniform base;
// HW writes lane i at base + i*16 (m97/m104 semantics).
__device__ __forceinline__ void load16_lds(const void* gp, void* lds_base_wave_uniform) {
    __builtin_amdgcn_global_load_lds((AS1 void*)((void*)gp),
                                     (AS3 void*)lds_base_wave_uniform, 16, 0, 0);
}

// ---------------------------------------------------------------------------
// Fused: LN1 -> xres + LN_att -> h hi plane (blocks 0..6271), and all 4
// weight plane-splits (blocks 6272..8319, grid-stride float4).
// h lo plane no longer produced: gemm_qkv computes h_hi * (W_hi + W_lo).
// ---------------------------------------------------------------------------
__global__ __launch_bounds__(256) void prep_ln_split(
    const float* __restrict__ x, const float* __restrict__ memory,
    const float* __restrict__ g1, const float* __restrict__ b1,
    const float* __restrict__ ga, const float* __restrict__ ba,
    float* __restrict__ xres, bf16* __restrict__ hH,
    const float* __restrict__ wp0, bf16* __restrict__ wh0, bf16* __restrict__ wl0,
    const float* __restrict__ wp1, bf16* __restrict__ wh1, bf16* __restrict__ wl1,
    const float* __restrict__ wp2, bf16* __restrict__ wh2, bf16* __restrict__ wl2,
    const float* __restrict__ wp3, bf16* __restrict__ wh3, bf16* __restrict__ wl3)
{
    const int t = threadIdx.x;
    if (blockIdx.x >= 6272) {
        // ---- weight split path (2048 blocks, grid-stride) ----
        const int n0q = 442368, n1q = 147456, n2q = 589824;
        const int total = 1769472;
        const int stride = 2048 * 256;
        for (int i = (blockIdx.x - 6272) * 256 + t; i < total; i += stride) {
            const float* sp; bf16 *hp, *lp; int j = i;
            if (j < n0q) { sp = wp0; hp = wh0; lp = wl0; }
            else if ((j -= n0q) < n1q) { sp = wp1; hp = wh1; lp = wl1; }
            else if ((j -= n1q) < n2q) { sp = wp2; hp = wh2; lp = wl2; }
            else { j -= n2q; sp = wp3; hp = wh3; lp = wl3; }
            float4 v4 = reinterpret_cast<const float4*>(sp)[j];
            bf16x4 hi, lo;
            hi[0] = (bf16)v4.x; lo[0] = (bf16)(v4.x - (float)hi[0]);
            hi[1] = (bf16)v4.y; lo[1] = (bf16)(v4.y - (float)hi[1]);
            hi[2] = (bf16)v4.z; lo[2] = (bf16)(v4.z - (float)hi[2]);
            hi[3] = (bf16)v4.w; lo[3] = (bf16)(v4.w - (float)hi[3]);
            reinterpret_cast<bf16x4*>(hp)[j] = hi;
            reinterpret_cast<bf16x4*>(lp)[j] = lo;
        }
        return;
    }

    // ---- LN path ----
    const int row = blockIdx.x;            // 0..6271
    const int b = row / 1568, l = row - b * 1568;
    const float* src = (l < 784) ? (memory + ((size_t)b * 1024 + l) * 768)
                                 : (x + ((size_t)b * 784 + (l - 784)) * 768);
    const int lane = t & 63, wv = t >> 6;
    __shared__ float red[8];

    float v[3];
#pragma unroll
    for (int i = 0; i < 3; ++i) v[i] = src[i * 256 + t];

    float s = v[0] + v[1] + v[2];
    float s2 = v[0] * v[0] + v[1] * v[1] + v[2] * v[2];
#pragma unroll
    for (int off = 1; off < 64; off <<= 1) { s += __shfl_xor(s, off, 64); s2 += __shfl_xor(s2, off, 64); }
    if (lane == 0) { red[wv] = s; red[4 + wv] = s2; }
    __syncthreads();
    s = red[0] + red[1] + red[2] + red[3];
    s2 = red[4] + red[5] + red[6] + red[7];
    float mu = s * (1.0f / 768.0f);
    float var = s2 * (1.0f / 768.0f) - mu * mu;
    float rs = rsqrtf(fmaxf(var, 0.0f) + 1e-5f);

    float w[3];
#pragma unroll
    for (int i = 0; i < 3; ++i) {
        int c = i * 256 + t;
        w[i] = (v[i] - mu) * rs * g1[c] + b1[c];
    }
    if (l >= 784) {
        float* xr = xres + ((size_t)b * 784 + (l - 784)) * 768;
#pragma unroll
        for (int i = 0; i < 3; ++i) xr[i * 256 + t] = w[i];
    }

    s = w[0] + w[1] + w[2];
    s2 = w[0] * w[0] + w[1] * w[1] + w[2] * w[2];
#pragma unroll
    for (int off = 1; off < 64; off <<= 1) { s += __shfl_xor(s, off, 64); s2 += __shfl_xor(s2, off, 64); }
    __syncthreads();
    if (lane == 0) { red[wv] = s; red[4 + wv] = s2; }
    __syncthreads();
    s = red[0] + red[1] + red[2] + red[3];
    s2 = red[4] + red[5] + red[6] + red[7];
    float mu2 = s * (1.0f / 768.0f);
    float var2 = s2 * (1.0f / 768.0f) - mu2 * mu2;
    float rs2 = rsqrtf(fmaxf(var2, 0.0f) + 1e-5f);

    bf16* hh_ = hH + (size_t)row * 768;
#pragma unroll
    for (int i = 0; i < 3; ++i) {
        int c = i * 256 + t;
        float hv = (w[i] - mu2) * rs2 * ga[c] + ba[c];
        hh_[c] = (bf16)hv;
    }
}

// ---------------------------------------------------------------------------
// QKV GEMM, 256x128 tile, m97 single-buffer schedule, involution staging,
// bijective XCD row-chunking. 2-term scheme: qkv = h_hi * (W_hi + W_lo).
// Error = h_lo*W ~ 2^-9 relative (same class as the V-hi-only change, which
// measurably did NOT move absmax). Staging 48->32 KB/step, MFMA 96->64/step,
// LDS 48->32 KB. V output cols (>=1536) still store hi-plane only.
// ---------------------------------------------------------------------------
__global__ __launch_bounds__(256, 2) void gemm_qkv(
    const bf16* __restrict__ Ah,
    const bf16* __restrict__ Bh, const bf16* __restrict__ Bl,
    int M, int N, int K,
    bf16* __restrict__ Ch, bf16* __restrict__ Cl)
{
    __shared__ __align__(16) bf16 Ahs[256 * 32];
    __shared__ __align__(16) bf16 Bhs[128 * 32], Bls[128 * 32];
    const int t = threadIdx.x, lane = t & 63, wv = t >> 6;

    // bijective XCD chunking (m204), row-chunk order
    const int nx = gridDim.x, ny = gridDim.y;
    int orig = blockIdx.x + nx * blockIdx.y;
    int nwg = nx * ny;
    int q = nwg >> 3, rr8 = nwg & 7;
    int xcd = orig & 7, pos = orig >> 3;
    int wgid = (xcd < rr8 ? xcd * (q + 1) : rr8 * (q + 1) + (xcd - rr8) * q) + pos;
    int bx = wgid % nx, by = wgid / nx;

    const int row0 = by * 256, col0 = bx * 128;
    const int ro = (wv >> 1) * 128, co = (wv & 1) * 64;
    const int l15 = lane & 15, q8 = lane >> 4;
    const int cs = (q8 ^ (l15 & 3)) * 8;     // involution chunk for fragment reads

    f32x4 acc[8][4] = {};

    for (int k0 = 0; k0 < K; k0 += 32) {
#pragma unroll
        for (int it = 0; it < 4; ++it) {              // A-hi: 256 rows
            int f = it * 256 + t;
            int r = f >> 2;
            int kc = ((f & 3) ^ (r & 3)) * 8;
            int ra = row0 + r; if (ra >= M) ra = M - 1;
            size_t oa = (size_t)ra * K + k0 + kc;
            size_t lb = (size_t)(it * 256 + wv * 64) * 8;
            load16_lds(Ah + oa, Ahs + lb);
        }
#pragma unroll
        for (int it = 0; it < 2; ++it) {              // B hi+lo: 128 rows
            int f = it * 256 + t;
            int r = f >> 2;
            int kc = ((f & 3) ^ (r & 3)) * 8;
            size_t ob = (size_t)(col0 + r) * K + k0 + kc;
            size_t lb = (size_t)(it * 256 + wv * 64) * 8;
            load16_lds(Bh + ob, Bhs + lb);
            load16_lds(Bl + ob, Bls + lb);
        }
        asm volatile("s_waitcnt vmcnt(0)" ::: "memory");
        __syncthreads();

        bf16x8 bh[4], bl[4];
#pragma unroll
        for (int j = 0; j < 4; ++j) {
            int o = (co + j * 16 + l15) * 32 + cs;
            bh[j] = *(const bf16x8*)&Bhs[o];
            bl[j] = *(const bf16x8*)&Bls[o];
        }
#pragma unroll
        for (int i = 0; i < 8; ++i) {
            int o = (ro + i * 16 + l15) * 32 + cs;
            bf16x8 ah = *(const bf16x8*)&Ahs[o];
#pragma unroll
            for (int j = 0; j < 4; ++j) {
                acc[i][j] = __builtin_amdgcn_mfma_f32_16x16x32_bf16(ah, bl[j], acc[i][j], 0, 0, 0);
                acc[i][j] = __builtin_amdgcn_mfma_f32_16x16x32_bf16(ah, bh[j], acc[i][j], 0, 0, 0);
            }
        }
        __syncthreads();
    }

#pragma unroll
    for (int i = 0; i < 8; ++i)
#pragma unroll
        for (int j = 0; j < 4; ++j)
#pragma unroll
            for (int r = 0; r < 4; ++r) {
                int row = row0 + ro + i * 16 + q8 * 4 + r;
                int col = col0 + co + j * 16 + l15;
                if (row >= M) continue;
                float v = acc[i][j][r];
                size_t idx = (size_t)row * N + col;
                bf16 hh = (bf16)v;
                Ch[idx] = hh;
                if (col < 1536) Cl[idx] = (bf16)(v - (float)hh);  // V-lo never read
            }
}

// ---------------------------------------------------------------------------
// Plane GEMM, m97 single-buffer schedule + involution staging + XCD chunking
// (R6-verified). 128x128 tile, BK=32, 4 waves x 64x64. Split-K via gridDim.z.
// MODE 1: fp32 partial -> Cf + z*M*N. 2: silu planes out. 3: atomic += Cf.
// ---------------------------------------------------------------------------
template <int MODE, int ORD>
__global__ __launch_bounds__(256, 2) void gemm_pl(
    const bf16* __restrict__ Ah, const bf16* __restrict__ Al,
    const bf16* __restrict__ Bh, const bf16* __restrict__ Bl,
    int M, int N, int K,
    const float* __restrict__ bias, const float* __restrict__ resid,
    float* __restrict__ Cf, bf16* __restrict__ Ch, bf16* __restrict__ Cl)
{
    __shared__ __align__(16) bf16 Ahs[128 * 32], Als[128 * 32];
    __shared__ __align__(16) bf16 Bhs[128 * 32], Bls[128 * 32];
    const int t = threadIdx.x, lane = t & 63, wv = t >> 6;

    // ---- bijective XCD chunking (m204) ----
    const int nx = gridDim.x, ny = gridDim.y;
    int orig = blockIdx.x + nx * blockIdx.y;
    int nwg = nx * ny;
    int q = nwg >> 3, rr8 = nwg & 7;
    int xcd = orig & 7, pos = orig >> 3;
    int wgid = (xcd < rr8 ? xcd * (q + 1) : rr8 * (q + 1) + (xcd - rr8) * q) + pos;
    int bx, by;
    if (ORD == 0) { bx = wgid % nx; by = wgid / nx; }   // row chunks (A-heavy)
    else          { by = wgid % ny; bx = wgid / ny; }   // col chunks (B-heavy)

    const int row0 = by * 128, col0 = bx * 128;
    const int ro = (wv >> 1) * 64, co = (wv & 1) * 64;
    const int Kc = K / gridDim.z;
    const int kbeg = blockIdx.z * Kc, kend = kbeg + Kc;
    const int l15 = lane & 15, q8 = lane >> 4;
    const int cs = (q8 ^ (l15 & 3)) * 8;     // involution chunk for fragment reads

    f32x4 acc[4][4] = {};

    for (int k0 = kbeg; k0 < kend; k0 += 32) {
#pragma unroll
        for (int it = 0; it < 2; ++it) {
            int f = it * 256 + t;
            int r = f >> 2;                          // tile row (4 lanes per row)
            int kc = ((f & 3) ^ (r & 3)) * 8;        // involution within 64B line
            int ra = row0 + r; if (ra >= M) ra = M - 1;
            size_t oa = (size_t)ra * K + k0 + kc;
            size_t ob = (size_t)(col0 + r) * K + k0 + kc;
            size_t lb = (size_t)(it * 256 + wv * 64) * 8;
            load16_lds(Ah + oa, Ahs + lb);
            load16_lds(Al + oa, Als + lb);
            load16_lds(Bh + ob, Bhs + lb);
            load16_lds(Bl + ob, Bls + lb);
        }
        asm volatile("s_waitcnt vmcnt(0)" ::: "memory");
        __syncthreads();
        bf16x8 ah[4], al[4], bh[4], bl[4];
#pragma unroll
        for (int i = 0; i < 4; ++i) {
            int o = (ro + i * 16 + l15) * 32 + cs;   // (row&3)==(l15&3)
            ah[i] = *(const bf16x8*)&Ahs[o];
            al[i] = *(const bf16x8*)&Als[o];
        }
#pragma unroll
        for (int j = 0; j < 4; ++j) {
            int o = (co + j * 16 + l15) * 32 + cs;
            bh[j] = *(const bf16x8*)&Bhs[o];
            bl[j] = *(const bf16x8*)&Bls[o];
        }
#pragma unroll
        for (int i = 0; i < 4; ++i)
#pragma unroll
            for (int j = 0; j < 4; ++j) {
                acc[i][j] = __builtin_amdgcn_mfma_f32_16x16x32_bf16(al[i], bh[j], acc[i][j], 0, 0, 0);
                acc[i][j] = __builtin_amdgcn_mfma_f32_16x16x32_bf16(ah[i], bl[j], acc[i][j], 0, 0, 0);
                acc[i][j] = __builtin_amdgcn_mfma_f32_16x16x32_bf16(ah[i], bh[j], acc[i][j], 0, 0, 0);
            }
        __syncthreads();
    }

    const size_t zoff = (size_t)blockIdx.z * M * N;
#pragma unroll
    for (int i = 0; i < 4; ++i)
#pragma unroll
        for (int j = 0; j < 4; ++j)
#pragma unroll
            for (int r = 0; r < 4; ++r) {
                int row = row0 + ro + i * 16 + (lane >> 4) * 4 + r;
                int col = col0 + co + j * 16 + (lane & 15);
                if (row >= M) continue;
                float v = acc[i][j][r];
                size_t idx = (size_t)row * N + col;
                if (MODE == 1) {
                    Cf[zoff + idx] = v;               // partial, bias added later
                } else if (MODE == 2) {
                    v += bias[col];
                    v = v / (1.0f + __expf(-v));
                    bf16 hh = (bf16)v;
                    Ch[idx] = hh; Cl[idx] = (bf16)(v - (float)hh);
                } else {
                    unsafeAtomicAdd(&Cf[idx], v);     // HW f32 atomic, prefilled dest
                }
            }
}

// ---------------------------------------------------------------------------
// Flash attention, pipelined. Grid: x = hh + 12*b (48), y = w*4+g (16).
// Deferred softmax (bounded logits), single barrier per K-tile, swizzled K
// via pre-swizzled global_load_lds source, V reg-prefetch + 2-way-bank
// transposed write. setprio(1) around MFMA clusters (m191: +4-7% attn).
// ---------------------------------------------------------------------------
__global__ __launch_bounds__(256, 3) void attn_kernel(
    const bf16* __restrict__ qh_, const bf16* __restrict__ ql_,
    bf16* __restrict__ oh_, bf16* __restrict__ ol_)
{
    const int hh = blockIdx.x % 12, b = blockIdx.x / 12;
    const int w = blockIdx.y >> 2, g = blockIdx.y & 3;
    const int kmax = (5 + w) * 196, nkt = (kmax + 31) / 32;
    const int t = threadIdx.x, lane = t & 63, wv = t >> 6;
    const int tile = g * 4 + wv;                  // 0..15; >12 idle (wave-uniform)
    const int l15 = lane & 15, q8 = lane >> 4;

    __shared__ __align__(16) bf16 Ks_h[2][32 * 64], Ks_l[2][32 * 64];
    __shared__ __align__(16) bf16 Vt_h[2][64 * 40];
    __shared__ __align__(16) bf16 Pl_h[4][16 * 40];

    const size_t bbase = (size_t)b * 1568 * 2304;

    // staging geometry: thread t covers K/V row srow, col chunk sc8.
    const int srow = t >> 3;                      // 0..31 (wave wv: rows wv*8..+7)
    const int sc8 = (t & 7) * 8;
    // K: LDS dest is linear (global_load_lds), so pre-swizzle the SOURCE col.
    const int scsrc = sc8 ^ ((srow & 7) * 8);

    // Q fragments (held in registers for the whole kernel)
    int tcl = tile > 12 ? 12 : tile;
    int qr0 = tcl * 16 + l15; if (qr0 > 195) qr0 = 195;
    const size_t qoff = bbase + (size_t)(784 + w * 196 + qr0) * 2304 + hh * 64 + q8 * 8;
    bf16x8 qfh[2], qfl[2];
#pragma unroll
    for (int p = 0; p < 2; ++p) {
        qfh[p] = *(const bf16x8*)(qh_ + qoff + p * 32);
        qfl[p] = *(const bf16x8*)(ql_ + qoff + p * 32);
    }

    float l_i[4] = {0.f, 0.f, 0.f, 0.f};
    f32x4 oacc[4];
#pragma unroll
    for (int nd = 0; nd < 4; ++nd) oacc[nd] = f32x4{0.f, 0.f, 0.f, 0.f};

    // issue staging for K-tile kt2 into buffer bufn; V -> vreg (not yet in LDS)
    auto stage_issue = [&](int kt2, int bufn, bf16x8& vreg) {
        const size_t kb = bbase + (size_t)(kt2 * 32 + srow) * 2304 + 768 + (size_t)hh * 64;
        load16_lds(qh_ + kb + scsrc, &Ks_h[bufn][wv * 512]);
        load16_lds(ql_ + kb + scsrc, &Ks_l[bufn][wv * 512]);
        vreg = *(const bf16x8*)(qh_ + kb + 768 + sc8);
    };
    // transposed V write, key-XOR swizzled (2-way banks instead of 16-way)
    auto write_V = [&](int bufn, const bf16x8& vreg) {
#pragma unroll
        for (int j = 0; j < 8; ++j) {
            int d = sc8 + j;
            int keyx = srow ^ (((d >> 3) & 3) * 8);
            Vt_h[bufn][d * 40 + keyx] = vreg[j];
        }
    };

    // ---- prologue: stage tile 0 into buffer 0
    {
        bf16x8 v0;
        stage_issue(0, 0, v0);
        write_V(0, v0);                            // data dep inserts vmcnt wait
        asm volatile("s_waitcnt vmcnt(0)" ::: "memory");
        __syncthreads();
    }

    const float CEXP = 0.18033688011112042f;       // 0.125 * log2(e)

    for (int kt = 0; kt < nkt; ++kt) {
        const int cur = kt & 1, nxt = cur ^ 1;
        int kt2 = kt + 1; if (kt2 >= nkt) kt2 = nkt - 1;   // clamp (no OOB)
        bf16x8 vnext;
        stage_issue(kt2, nxt, vnext);              // overlaps with compute below

        if (tile <= 12) {
            bf16x8 kfh[2][2], kfl[2][2], vth[4];
#pragma unroll
            for (int nb = 0; nb < 2; ++nb)
#pragma unroll
                for (int p = 0; p < 2; ++p) {
                    int row = nb * 16 + l15;
                    int c = (p * 32 + q8 * 8) ^ ((row & 7) * 8);
                    kfh[nb][p] = *(const bf16x8*)&Ks_h[cur][row * 64 + c];
                    kfl[nb][p] = *(const bf16x8*)&Ks_l[cur][row * 64 + c];
                }
#pragma unroll
            for (int nd = 0; nd < 4; ++nd) {
                int d = nd * 16 + l15;
                int k8 = (q8 * 8) ^ (((d >> 3) & 3) * 8);
                vth[nd] = *(const bf16x8*)&Vt_h[cur][d * 40 + k8];
            }

            // QK^T: 4 independent depth-3 MFMA chains
            f32x4 s0a = {0.f,0.f,0.f,0.f}, s0b = {0.f,0.f,0.f,0.f};
            f32x4 s1a = {0.f,0.f,0.f,0.f}, s1b = {0.f,0.f,0.f,0.f};
            __builtin_amdgcn_s_setprio(1);
            s0a = __builtin_amdgcn_mfma_f32_16x16x32_bf16(qfl[0], kfh[0][0], s0a, 0, 0, 0);
            s1a = __builtin_amdgcn_mfma_f32_16x16x32_bf16(qfl[0], kfh[1][0], s1a, 0, 0, 0);
            s0b = __builtin_amdgcn_mfma_f32_16x16x32_bf16(qfl[1], kfh[0][1], s0b, 0, 0, 0);
            s1b = __builtin_amdgcn_mfma_f32_16x16x32_bf16(qfl[1], kfh[1][1], s1b, 0, 0, 0);
            s0a = __builtin_amdgcn_mfma_f32_16x16x32_bf16(qfh[0], kfl[0][0], s0a, 0, 0, 0);
            s1a = __builtin_amdgcn_mfma_f32_16x16x32_bf16(qfh[0], kfl[1][0], s1a, 0, 0, 0);
            s0b = __builtin_amdgcn_mfma_f32_16x16x32_bf16(qfh[1], kfl[0][1], s0b, 0, 0, 0);
            s1b = __builtin_amdgcn_mfma_f32_16x16x32_bf16(qfh[1], kfl[1][1], s1b, 0, 0, 0);
            s0a = __builtin_amdgcn_mfma_f32_16x16x32_bf16(qfh[0], kfh[0][0], s0a, 0, 0, 0);
            s1a = __builtin_amdgcn_mfma_f32_16x16x32_bf16(qfh[0], kfh[1][0], s1a, 0, 0, 0);
            s0b = __builtin_amdgcn_mfma_f32_16x16x32_bf16(qfh[1], kfh[0][1], s0b, 0, 0, 0);
            s1b = __builtin_amdgcn_mfma_f32_16x16x32_bf16(qfh[1], kfh[1][1], s1b, 0, 0, 0);
            __builtin_amdgcn_s_setprio(0);
            f32x4 s0 = s0a + s0b, s1 = s1a + s1b;

            // deferred softmax: p = exp(S/8), no max subtraction, no rescale
            const int key0 = kt * 32 + l15;
            const bool m0 = (key0 >= kmax), m1 = (key0 + 16 >= kmax);
#pragma unroll
            for (int r = 0; r < 4; ++r) {
                float p0 = m0 ? 0.0f : exp2f(s0[r] * CEXP);
                float p1 = m1 ? 0.0f : exp2f(s1[r] * CEXP);
                l_i[r] += p0 + p1;
                int pr = q8 * 4 + r;
                Pl_h[wv][pr * 40 + l15] = (bf16)p0;
                Pl_h[wv][pr * 40 + 16 + l15] = (bf16)p1;
            }
            asm volatile("s_waitcnt lgkmcnt(0)" ::: "memory");   // wave-private Pl RAW
            bf16x8 pfh = *(const bf16x8*)&Pl_h[wv][l15 * 40 + q8 * 8];
            __builtin_amdgcn_s_setprio(1);
#pragma unroll
            for (int nd = 0; nd < 4; ++nd)
                oacc[nd] = __builtin_amdgcn_mfma_f32_16x16x32_bf16(pfh, vth[nd], oacc[nd], 0, 0, 0);
            __builtin_amdgcn_s_setprio(0);
        }

        write_V(nxt, vnext);                       // waits vmcnt for vnext only here
        asm volatile("s_waitcnt vmcnt(0)" ::: "memory");
        __syncthreads();
    }

    if (tile <= 12) {
#pragma unroll
        for (int r = 0; r < 4; ++r) {
            float s = l_i[r];
#pragma unroll
            for (int off = 1; off < 16; off <<= 1) s += __shfl_xor(s, off, 64);
            int qr = tile * 16 + q8 * 4 + r;
            if (qr >= 196) continue;
            float inv = 1.0f / s;
            size_t row = (size_t)b * 784 + w * 196 + qr;
#pragma unroll
            for (int nd = 0; nd < 4; ++nd) {
                float ov = oacc[nd][r] * inv;
                bf16 oh = (bf16)ov;
                size_t idx = row * 768 + hh * 64 + nd * 16 + l15;
                oh_[idx] = oh;
                ol_[idx] = (bf16)(ov - (float)oh);
            }
        }
    }
}

// ---------------------------------------------------------------------------
// y = xres + p0 + p1 + b_out (fp32), y2 = LN2(y) planes, dout = y + b2ff
// (prefill for the atomic split-K w2 GEMM). Block per x-row (3136).
// ---------------------------------------------------------------------------
__global__ __launch_bounds__(256) void ln2_resid(
    const float* __restrict__ xres, const float* __restrict__ attP,
    const float* __restrict__ bo,
    const float* __restrict__ g2, const float* __restrict__ b2,
    const float* __restrict__ b2ff,
    float* __restrict__ y, bf16* __restrict__ y2H, bf16* __restrict__ y2L,
    float* __restrict__ dout)
{
    const int row = blockIdx.x;
    const size_t MN = (size_t)3136 * 768;
    const float* xr = xres + (size_t)row * 768;
    const float* a0 = attP + (size_t)row * 768;
    const float* a1 = attP + MN + (size_t)row * 768;
    const int t = threadIdx.x, lane = t & 63, wv = t >> 6;
    __shared__ float red[8];

    float v[3];
    float* yr = y + (size_t)row * 768;
    float* dr = dout + (size_t)row * 768;
#pragma unroll
    for (int i = 0; i < 3; ++i) {
        int c = i * 256 + t;
        v[i] = xr[c] + a0[c] + a1[c] + bo[c];
        yr[c] = v[i];
        dr[c] = v[i] + b2ff[c];
    }
    float s = v[0] + v[1] + v[2];
    float s2 = v[0] * v[0] + v[1] * v[1] + v[2] * v[2];
#pragma unroll
    for (int off = 1; off < 64; off <<= 1) { s += __shfl_xor(s, off, 64); s2 += __shfl_xor(s2, off, 64); }
    if (lane == 0) { red[wv] = s; red[4 + wv] = s2; }
    __syncthreads();
    s = red[0] + red[1] + red[2] + red[3];
    s2 = red[4] + red[5] + red[6] + red[7];
    float mu = s * (1.0f / 768.0f);
    float var = s2 * (1.0f / 768.0f) - mu * mu;
    float rs = rsqrtf(fmaxf(var, 0.0f) + 1e-5f);

    bf16* yh = y2H + (size_t)row * 768;
    bf16* yl = y2L + (size_t)row * 768;
#pragma unroll
    for (int i = 0; i < 3; ++i) {
        int c = i * 256 + t;
        float yv = (v[i] - mu) * rs * g2[c] + b2[c];
        bf16 yvh = (bf16)yv;
        yh[c] = yvh;
        yl[c] = (bf16)(yv - (float)yvh);
    }
}

// ---------------------------------------------------------------------------
extern "C" void kernel_launch(void* const* d_in, const int* in_sizes, int n_in,
                              void* d_out, int out_size, void* d_ws, size_t ws_size,
                              hipStream_t stream)
{
    (void)in_sizes; (void)n_in; (void)out_size; (void)ws_size;
    const float* x        = (const float*)d_in[0];
    const float* memory   = (const float*)d_in[1];
    const float* ln_att_g = (const float*)d_in[2];
    const float* ln_att_b = (const float*)d_in[3];
    const float* w_qkv    = (const float*)d_in[4];
    const float* w_out    = (const float*)d_in[5];
    const float* b_out    = (const float*)d_in[6];
    const float* ln1_g    = (const float*)d_in[7];
    const float* ln1_b    = (const float*)d_in[8];
    const float* ln2_g    = (const float*)d_in[9];
    const float* ln2_b    = (const float*)d_in[10];
    const float* w1       = (const float*)d_in[11];
    const float* b1       = (const float*)d_in[12];
    const float* w2       = (const float*)d_in[13];
    const float* b2       = (const float*)d_in[14];

    // ---- workspace layout (~109.7 MiB, same footprint) ----
    char* ws = (char*)d_ws;
    const size_t SZF  = (size_t)3136 * 768 * 4;
    const size_t SZP  = (size_t)3136 * 768 * 2;
    const size_t SZHP = (size_t)6272 * 768 * 2;
    const size_t SZQP = (size_t)6272 * 2304 * 2;
    const size_t SZFP = (size_t)3136 * 3072 * 2;

    float* xres = (float*)(ws);
    bf16* hH  = (bf16*)(ws + SZF);
    bf16* aoH = (bf16*)(ws + SZF);
    bf16* aoL = (bf16*)(ws + SZF + SZP);
    bf16* y2H = (bf16*)(ws + SZF);
    bf16* y2L = (bf16*)(ws + SZF + SZP);
    const size_t OQ = SZF + 2 * SZHP;
    bf16* qkvH = (bf16*)(ws + OQ);
    bf16* qkvL = (bf16*)(ws + OQ + SZQP);
    float* y    = (float*)(ws + OQ);
    float* attP = (float*)(ws + OQ + SZF);   // 2 partials (dead qkv region; ffH overwrites later)
    bf16* ffH  = (bf16*)(ws + OQ + SZF);
    bf16* ffL  = (bf16*)(ws + OQ + SZF + SZFP);
    const size_t OW = OQ + 2 * SZQP;
    bf16* wqH = (bf16*)(ws + OW);
    bf16* wqL = (bf16*)(ws + OW + 3538944);
    bf16* woH = (bf16*)(ws + OW + 2 * 3538944);
    bf16* woL = (bf16*)(ws + OW + 2 * 3538944 + 1179648);
    bf16* w1H = (bf16*)(ws + OW + 2 * 3538944 + 2 * 1179648);
    bf16* w1L = (bf16*)(ws + OW + 2 * 3538944 + 2 * 1179648 + 4718592);
    bf16* w2H = (bf16*)(ws + OW + 2 * 3538944 + 2 * 1179648 + 2 * 4718592);
    bf16* w2L = (bf16*)(ws + OW + 2 * 3538944 + 2 * 1179648 + 3 * 4718592);

    // 0+1) fused: LN1 + LN_att hi-plane (6272 blocks) and weight splits (2048 blocks)
    prep_ln_split<<<8320, 256, 0, stream>>>(x, memory, ln1_g, ln1_b, ln_att_g, ln_att_b,
                                            xres, hH,
                                            w_qkv, wqH, wqL, w_out, woH, woL,
                                            w1, w1H, w1L, w2, w2H, w2L);

    // 2) qkv planes = h_hi @ (w_qkv_hi + w_qkv_lo)^T  (M=6272, N=2304, K=768)
    gemm_qkv<<<dim3(18, 25), 256, 0, stream>>>(hH, wqH, wqL, 6272, 2304, 768,
                                               qkvH, qkvL);

    // 3) attention  (grid: x = hh+12*b, y = w*4+g  -> XCD-local K/V sharing)
    attn_kernel<<<dim3(48, 16), 256, 0, stream>>>(qkvH, qkvL, aoH, aoL);

    // 4) att partials = ao @ w_out^T  (M=3136, N=768, K=768, split-K=2) — row-chunked
    gemm_pl<1, 0><<<dim3(6, 25, 2), 256, 0, stream>>>(aoH, aoL, woH, woL, 3136, 768, 768,
                                                      nullptr, nullptr, attP, nullptr, nullptr);

    // 5) y = xres + p0 + p1 + b_out ; y2 planes = LN2(y) ; dout prefill = y + b2
    ln2_resid<<<3136, 256, 0, stream>>>(xres, attP, b_out, ln2_g, ln2_b, b2,
                                        y, y2H, y2L, (float*)d_out);

    // 6) ff planes = silu(y2 @ w1^T + b1)  (M=3136, N=3072, K=768) — col-chunked (w1-heavy)
    gemm_pl<2, 1><<<dim3(24, 25), 256, 0, stream>>>(y2H, y2L, w1H, w1L, 3136, 3072, 768,
                                                    b1, nullptr, nullptr, ffH, ffL);

    // 7) d_out += ff @ w2^T  (M=3136, N=768, K=3072, split-K=4, atomic) — row-chunked
    gemm_pl<3, 0><<<dim3(6, 25, 4), 256, 0, stream>>>(ffH, ffL, w2H, w2L, 3136, 768, 3072,
                                                      nullptr, nullptr, (float*)d_out, nullptr, nullptr);
}

// Round 11
// 375.465 us; speedup vs baseline: 1.4241x; 1.0967x over previous
//
#include <hip/hip_runtime.h>
#include <cstdint>

typedef __bf16 bf16;
typedef __bf16 bf16x4 __attribute__((ext_vector_type(4)));
typedef __bf16 bf16x8 __attribute__((ext_vector_type(8)));
typedef float f32x4 __attribute__((ext_vector_type(4)));

#define AS1 __attribute__((address_space(1)))
#define AS3 __attribute__((address_space(3)))

// Async global->LDS, 16B per lane. LDS dest must be wave-uniform base;
// HW writes lane i at base + i*16 (m97/m104 semantics).
__device__ __forceinline__ void load16_lds(const void* gp, void* lds_base_wave_uniform) {
    __builtin_amdgcn_global_load_lds((AS1 void*)((void*)gp),
                                     (AS3 void*)lds_base_wave_uniform, 16, 0, 0);
}

// ---------------------------------------------------------------------------
// Fused: LN1 -> xres + LN_att -> h hi plane (blocks 0..6271), and all 4
// weight plane-splits (blocks 6272..8319, grid-stride float4).
// 2-term scheme everywhere: activations single bf16 plane, weights hi+lo.
// ---------------------------------------------------------------------------
__global__ __launch_bounds__(256) void prep_ln_split(
    const float* __restrict__ x, const float* __restrict__ memory,
    const float* __restrict__ g1, const float* __restrict__ b1,
    const float* __restrict__ ga, const float* __restrict__ ba,
    float* __restrict__ xres, bf16* __restrict__ hH,
    const float* __restrict__ wp0, bf16* __restrict__ wh0, bf16* __restrict__ wl0,
    const float* __restrict__ wp1, bf16* __restrict__ wh1, bf16* __restrict__ wl1,
    const float* __restrict__ wp2, bf16* __restrict__ wh2, bf16* __restrict__ wl2,
    const float* __restrict__ wp3, bf16* __restrict__ wh3, bf16* __restrict__ wl3)
{
    const int t = threadIdx.x;
    if (blockIdx.x >= 6272) {
        // ---- weight split path (2048 blocks, grid-stride) ----
        const int n0q = 442368, n1q = 147456, n2q = 589824;
        const int total = 1769472;
        const int stride = 2048 * 256;
        for (int i = (blockIdx.x - 6272) * 256 + t; i < total; i += stride) {
            const float* sp; bf16 *hp, *lp; int j = i;
            if (j < n0q) { sp = wp0; hp = wh0; lp = wl0; }
            else if ((j -= n0q) < n1q) { sp = wp1; hp = wh1; lp = wl1; }
            else if ((j -= n1q) < n2q) { sp = wp2; hp = wh2; lp = wl2; }
            else { j -= n2q; sp = wp3; hp = wh3; lp = wl3; }
            float4 v4 = reinterpret_cast<const float4*>(sp)[j];
            bf16x4 hi, lo;
            hi[0] = (bf16)v4.x; lo[0] = (bf16)(v4.x - (float)hi[0]);
            hi[1] = (bf16)v4.y; lo[1] = (bf16)(v4.y - (float)hi[1]);
            hi[2] = (bf16)v4.z; lo[2] = (bf16)(v4.z - (float)hi[2]);
            hi[3] = (bf16)v4.w; lo[3] = (bf16)(v4.w - (float)hi[3]);
            reinterpret_cast<bf16x4*>(hp)[j] = hi;
            reinterpret_cast<bf16x4*>(lp)[j] = lo;
        }
        return;
    }

    // ---- LN path ----
    const int row = blockIdx.x;            // 0..6271
    const int b = row / 1568, l = row - b * 1568;
    const float* src = (l < 784) ? (memory + ((size_t)b * 1024 + l) * 768)
                                 : (x + ((size_t)b * 784 + (l - 784)) * 768);
    const int lane = t & 63, wv = t >> 6;
    __shared__ float red[8];

    float v[3];
#pragma unroll
    for (int i = 0; i < 3; ++i) v[i] = src[i * 256 + t];

    float s = v[0] + v[1] + v[2];
    float s2 = v[0] * v[0] + v[1] * v[1] + v[2] * v[2];
#pragma unroll
    for (int off = 1; off < 64; off <<= 1) { s += __shfl_xor(s, off, 64); s2 += __shfl_xor(s2, off, 64); }
    if (lane == 0) { red[wv] = s; red[4 + wv] = s2; }
    __syncthreads();
    s = red[0] + red[1] + red[2] + red[3];
    s2 = red[4] + red[5] + red[6] + red[7];
    float mu = s * (1.0f / 768.0f);
    float var = s2 * (1.0f / 768.0f) - mu * mu;
    float rs = rsqrtf(fmaxf(var, 0.0f) + 1e-5f);

    float w[3];
#pragma unroll
    for (int i = 0; i < 3; ++i) {
        int c = i * 256 + t;
        w[i] = (v[i] - mu) * rs * g1[c] + b1[c];
    }
    if (l >= 784) {
        float* xr = xres + ((size_t)b * 784 + (l - 784)) * 768;
#pragma unroll
        for (int i = 0; i < 3; ++i) xr[i * 256 + t] = w[i];
    }

    s = w[0] + w[1] + w[2];
    s2 = w[0] * w[0] + w[1] * w[1] + w[2] * w[2];
#pragma unroll
    for (int off = 1; off < 64; off <<= 1) { s += __shfl_xor(s, off, 64); s2 += __shfl_xor(s2, off, 64); }
    __syncthreads();
    if (lane == 0) { red[wv] = s; red[4 + wv] = s2; }
    __syncthreads();
    s = red[0] + red[1] + red[2] + red[3];
    s2 = red[4] + red[5] + red[6] + red[7];
    float mu2 = s * (1.0f / 768.0f);
    float var2 = s2 * (1.0f / 768.0f) - mu2 * mu2;
    float rs2 = rsqrtf(fmaxf(var2, 0.0f) + 1e-5f);

    bf16* hh_ = hH + (size_t)row * 768;
#pragma unroll
    for (int i = 0; i < 3; ++i) {
        int c = i * 256 + t;
        float hv = (w[i] - mu2) * rs2 * ga[c] + ba[c];
        hh_[c] = (bf16)hv;
    }
}

// ---------------------------------------------------------------------------
// QKV GEMM, 256x128 tile, m97 single-buffer schedule, involution staging,
// bijective XCD row-chunking. 2-term: qkv = h_hi * (W_hi + W_lo).
// V output cols (>=1536) store hi-plane only.
// ---------------------------------------------------------------------------
__global__ __launch_bounds__(256, 2) void gemm_qkv(
    const bf16* __restrict__ Ah,
    const bf16* __restrict__ Bh, const bf16* __restrict__ Bl,
    int M, int N, int K,
    bf16* __restrict__ Ch, bf16* __restrict__ Cl)
{
    __shared__ __align__(16) bf16 Ahs[256 * 32];
    __shared__ __align__(16) bf16 Bhs[128 * 32], Bls[128 * 32];
    const int t = threadIdx.x, lane = t & 63, wv = t >> 6;

    // bijective XCD chunking (m204), row-chunk order
    const int nx = gridDim.x, ny = gridDim.y;
    int orig = blockIdx.x + nx * blockIdx.y;
    int nwg = nx * ny;
    int q = nwg >> 3, rr8 = nwg & 7;
    int xcd = orig & 7, pos = orig >> 3;
    int wgid = (xcd < rr8 ? xcd * (q + 1) : rr8 * (q + 1) + (xcd - rr8) * q) + pos;
    int bx = wgid % nx, by = wgid / nx;

    const int row0 = by * 256, col0 = bx * 128;
    const int ro = (wv >> 1) * 128, co = (wv & 1) * 64;
    const int l15 = lane & 15, q8 = lane >> 4;
    const int cs = (q8 ^ (l15 & 3)) * 8;     // involution chunk for fragment reads

    f32x4 acc[8][4] = {};

    for (int k0 = 0; k0 < K; k0 += 32) {
#pragma unroll
        for (int it = 0; it < 4; ++it) {              // A-hi: 256 rows
            int f = it * 256 + t;
            int r = f >> 2;
            int kc = ((f & 3) ^ (r & 3)) * 8;
            int ra = row0 + r; if (ra >= M) ra = M - 1;
            size_t oa = (size_t)ra * K + k0 + kc;
            size_t lb = (size_t)(it * 256 + wv * 64) * 8;
            load16_lds(Ah + oa, Ahs + lb);
        }
#pragma unroll
        for (int it = 0; it < 2; ++it) {              // B hi+lo: 128 rows
            int f = it * 256 + t;
            int r = f >> 2;
            int kc = ((f & 3) ^ (r & 3)) * 8;
            size_t ob = (size_t)(col0 + r) * K + k0 + kc;
            size_t lb = (size_t)(it * 256 + wv * 64) * 8;
            load16_lds(Bh + ob, Bhs + lb);
            load16_lds(Bl + ob, Bls + lb);
        }
        asm volatile("s_waitcnt vmcnt(0)" ::: "memory");
        __syncthreads();

        bf16x8 bh[4], bl[4];
#pragma unroll
        for (int j = 0; j < 4; ++j) {
            int o = (co + j * 16 + l15) * 32 + cs;
            bh[j] = *(const bf16x8*)&Bhs[o];
            bl[j] = *(const bf16x8*)&Bls[o];
        }
#pragma unroll
        for (int i = 0; i < 8; ++i) {
            int o = (ro + i * 16 + l15) * 32 + cs;
            bf16x8 ah = *(const bf16x8*)&Ahs[o];
#pragma unroll
            for (int j = 0; j < 4; ++j) {
                acc[i][j] = __builtin_amdgcn_mfma_f32_16x16x32_bf16(ah, bl[j], acc[i][j], 0, 0, 0);
                acc[i][j] = __builtin_amdgcn_mfma_f32_16x16x32_bf16(ah, bh[j], acc[i][j], 0, 0, 0);
            }
        }
        __syncthreads();
    }

#pragma unroll
    for (int i = 0; i < 8; ++i)
#pragma unroll
        for (int j = 0; j < 4; ++j)
#pragma unroll
            for (int r = 0; r < 4; ++r) {
                int row = row0 + ro + i * 16 + q8 * 4 + r;
                int col = col0 + co + j * 16 + l15;
                if (row >= M) continue;
                float v = acc[i][j][r];
                size_t idx = (size_t)row * N + col;
                bf16 hh = (bf16)v;
                Ch[idx] = hh;
                if (col < 1536) Cl[idx] = (bf16)(v - (float)hh);  // V-lo never read
            }
}

// ---------------------------------------------------------------------------
// Plane GEMM, 2-term scheme (R9/R10-validated): C = A_hi * (B_hi + B_lo)^T.
// m97 single-buffer schedule + involution staging + XCD chunking.
// 128x128 tile, BK=32, 4 waves x 64x64. Split-K via gridDim.z.
// MODE 1: fp32 partial -> Cf + z*M*N. 2: silu -> single bf16 plane Ch.
// 3: atomic fp32 += into prefilled Cf.
// ---------------------------------------------------------------------------
template <int MODE, int ORD>
__global__ __launch_bounds__(256, 2) void gemm_pl(
    const bf16* __restrict__ Ah,
    const bf16* __restrict__ Bh, const bf16* __restrict__ Bl,
    int M, int N, int K,
    const float* __restrict__ bias,
    float* __restrict__ Cf, bf16* __restrict__ Ch)
{
    __shared__ __align__(16) bf16 Ahs[128 * 32];
    __shared__ __align__(16) bf16 Bhs[128 * 32], Bls[128 * 32];
    const int t = threadIdx.x, lane = t & 63, wv = t >> 6;

    // ---- bijective XCD chunking (m204) ----
    const int nx = gridDim.x, ny = gridDim.y;
    int orig = blockIdx.x + nx * blockIdx.y;
    int nwg = nx * ny;
    int q = nwg >> 3, rr8 = nwg & 7;
    int xcd = orig & 7, pos = orig >> 3;
    int wgid = (xcd < rr8 ? xcd * (q + 1) : rr8 * (q + 1) + (xcd - rr8) * q) + pos;
    int bx, by;
    if (ORD == 0) { bx = wgid % nx; by = wgid / nx; }   // row chunks (A-heavy)
    else          { by = wgid % ny; bx = wgid / ny; }   // col chunks (B-heavy)

    const int row0 = by * 128, col0 = bx * 128;
    const int ro = (wv >> 1) * 64, co = (wv & 1) * 64;
    const int Kc = K / gridDim.z;
    const int kbeg = blockIdx.z * Kc, kend = kbeg + Kc;
    const int l15 = lane & 15, q8 = lane >> 4;
    const int cs = (q8 ^ (l15 & 3)) * 8;     // involution chunk for fragment reads

    f32x4 acc[4][4] = {};

    for (int k0 = kbeg; k0 < kend; k0 += 32) {
#pragma unroll
        for (int it = 0; it < 2; ++it) {
            int f = it * 256 + t;
            int r = f >> 2;                          // tile row (4 lanes per row)
            int kc = ((f & 3) ^ (r & 3)) * 8;        // involution within 64B line
            int ra = row0 + r; if (ra >= M) ra = M - 1;
            size_t oa = (size_t)ra * K + k0 + kc;
            size_t ob = (size_t)(col0 + r) * K + k0 + kc;
            size_t lb = (size_t)(it * 256 + wv * 64) * 8;
            load16_lds(Ah + oa, Ahs + lb);
            load16_lds(Bh + ob, Bhs + lb);
            load16_lds(Bl + ob, Bls + lb);
        }
        asm volatile("s_waitcnt vmcnt(0)" ::: "memory");
        __syncthreads();
        bf16x8 ah[4], bh[4], bl[4];
#pragma unroll
        for (int i = 0; i < 4; ++i) {
            int o = (ro + i * 16 + l15) * 32 + cs;   // (row&3)==(l15&3)
            ah[i] = *(const bf16x8*)&Ahs[o];
        }
#pragma unroll
        for (int j = 0; j < 4; ++j) {
            int o = (co + j * 16 + l15) * 32 + cs;
            bh[j] = *(const bf16x8*)&Bhs[o];
            bl[j] = *(const bf16x8*)&Bls[o];
        }
#pragma unroll
        for (int i = 0; i < 4; ++i)
#pragma unroll
            for (int j = 0; j < 4; ++j) {
                acc[i][j] = __builtin_amdgcn_mfma_f32_16x16x32_bf16(ah[i], bl[j], acc[i][j], 0, 0, 0);
                acc[i][j] = __builtin_amdgcn_mfma_f32_16x16x32_bf16(ah[i], bh[j], acc[i][j], 0, 0, 0);
            }
        __syncthreads();
    }

    const size_t zoff = (size_t)blockIdx.z * M * N;
#pragma unroll
    for (int i = 0; i < 4; ++i)
#pragma unroll
        for (int j = 0; j < 4; ++j)
#pragma unroll
            for (int r = 0; r < 4; ++r) {
                int row = row0 + ro + i * 16 + (lane >> 4) * 4 + r;
                int col = col0 + co + j * 16 + (lane & 15);
                if (row >= M) continue;
                float v = acc[i][j][r];
                size_t idx = (size_t)row * N + col;
                if (MODE == 1) {
                    Cf[zoff + idx] = v;               // partial, bias added later
                } else if (MODE == 2) {
                    v += bias[col];
                    v = v / (1.0f + __expf(-v));
                    Ch[idx] = (bf16)v;                // single plane
                } else {
                    unsafeAtomicAdd(&Cf[idx], v);     // HW f32 atomic, prefilled dest
                }
            }
}

// ---------------------------------------------------------------------------
// Flash attention, pipelined. Grid: x = hh + 12*b (48), y = w*4+g (16).
// Deferred softmax (bounded logits), single barrier per K-tile, swizzled K
// via pre-swizzled global_load_lds source, V reg-prefetch + 2-way-bank
// transposed write. setprio(1) around MFMA clusters. Output: single bf16
// plane (2-term scheme downstream).
// ---------------------------------------------------------------------------
__global__ __launch_bounds__(256, 3) void attn_kernel(
    const bf16* __restrict__ qh_, const bf16* __restrict__ ql_,
    bf16* __restrict__ oh_)
{
    const int hh = blockIdx.x % 12, b = blockIdx.x / 12;
    const int w = blockIdx.y >> 2, g = blockIdx.y & 3;
    const int kmax = (5 + w) * 196, nkt = (kmax + 31) / 32;
    const int t = threadIdx.x, lane = t & 63, wv = t >> 6;
    const int tile = g * 4 + wv;                  // 0..15; >12 idle (wave-uniform)
    const int l15 = lane & 15, q8 = lane >> 4;

    __shared__ __align__(16) bf16 Ks_h[2][32 * 64], Ks_l[2][32 * 64];
    __shared__ __align__(16) bf16 Vt_h[2][64 * 40];
    __shared__ __align__(16) bf16 Pl_h[4][16 * 40];

    const size_t bbase = (size_t)b * 1568 * 2304;

    // staging geometry: thread t covers K/V row srow, col chunk sc8.
    const int srow = t >> 3;                      // 0..31 (wave wv: rows wv*8..+7)
    const int sc8 = (t & 7) * 8;
    // K: LDS dest is linear (global_load_lds), so pre-swizzle the SOURCE col.
    const int scsrc = sc8 ^ ((srow & 7) * 8);

    // Q fragments (held in registers for the whole kernel)
    int tcl = tile > 12 ? 12 : tile;
    int qr0 = tcl * 16 + l15; if (qr0 > 195) qr0 = 195;
    const size_t qoff = bbase + (size_t)(784 + w * 196 + qr0) * 2304 + hh * 64 + q8 * 8;
    bf16x8 qfh[2], qfl[2];
#pragma unroll
    for (int p = 0; p < 2; ++p) {
        qfh[p] = *(const bf16x8*)(qh_ + qoff + p * 32);
        qfl[p] = *(const bf16x8*)(ql_ + qoff + p * 32);
    }

    float l_i[4] = {0.f, 0.f, 0.f, 0.f};
    f32x4 oacc[4];
#pragma unroll
    for (int nd = 0; nd < 4; ++nd) oacc[nd] = f32x4{0.f, 0.f, 0.f, 0.f};

    // issue staging for K-tile kt2 into buffer bufn; V -> vreg (not yet in LDS)
    auto stage_issue = [&](int kt2, int bufn, bf16x8& vreg) {
        const size_t kb = bbase + (size_t)(kt2 * 32 + srow) * 2304 + 768 + (size_t)hh * 64;
        load16_lds(qh_ + kb + scsrc, &Ks_h[bufn][wv * 512]);
        load16_lds(ql_ + kb + scsrc, &Ks_l[bufn][wv * 512]);
        vreg = *(const bf16x8*)(qh_ + kb + 768 + sc8);
    };
    // transposed V write, key-XOR swizzled (2-way banks instead of 16-way)
    auto write_V = [&](int bufn, const bf16x8& vreg) {
#pragma unroll
        for (int j = 0; j < 8; ++j) {
            int d = sc8 + j;
            int keyx = srow ^ (((d >> 3) & 3) * 8);
            Vt_h[bufn][d * 40 + keyx] = vreg[j];
        }
    };

    // ---- prologue: stage tile 0 into buffer 0
    {
        bf16x8 v0;
        stage_issue(0, 0, v0);
        write_V(0, v0);                            // data dep inserts vmcnt wait
        asm volatile("s_waitcnt vmcnt(0)" ::: "memory");
        __syncthreads();
    }

    const float CEXP = 0.18033688011112042f;       // 0.125 * log2(e)

    for (int kt = 0; kt < nkt; ++kt) {
        const int cur = kt & 1, nxt = cur ^ 1;
        int kt2 = kt + 1; if (kt2 >= nkt) kt2 = nkt - 1;   // clamp (no OOB)
        bf16x8 vnext;
        stage_issue(kt2, nxt, vnext);              // overlaps with compute below

        if (tile <= 12) {
            bf16x8 kfh[2][2], kfl[2][2], vth[4];
#pragma unroll
            for (int nb = 0; nb < 2; ++nb)
#pragma unroll
                for (int p = 0; p < 2; ++p) {
                    int row = nb * 16 + l15;
                    int c = (p * 32 + q8 * 8) ^ ((row & 7) * 8);
                    kfh[nb][p] = *(const bf16x8*)&Ks_h[cur][row * 64 + c];
                    kfl[nb][p] = *(const bf16x8*)&Ks_l[cur][row * 64 + c];
                }
#pragma unroll
            for (int nd = 0; nd < 4; ++nd) {
                int d = nd * 16 + l15;
                int k8 = (q8 * 8) ^ (((d >> 3) & 3) * 8);
                vth[nd] = *(const bf16x8*)&Vt_h[cur][d * 40 + k8];
            }

            // QK^T: 4 independent depth-3 MFMA chains
            f32x4 s0a = {0.f,0.f,0.f,0.f}, s0b = {0.f,0.f,0.f,0.f};
            f32x4 s1a = {0.f,0.f,0.f,0.f}, s1b = {0.f,0.f,0.f,0.f};
            __builtin_amdgcn_s_setprio(1);
            s0a = __builtin_amdgcn_mfma_f32_16x16x32_bf16(qfl[0], kfh[0][0], s0a, 0, 0, 0);
            s1a = __builtin_amdgcn_mfma_f32_16x16x32_bf16(qfl[0], kfh[1][0], s1a, 0, 0, 0);
            s0b = __builtin_amdgcn_mfma_f32_16x16x32_bf16(qfl[1], kfh[0][1], s0b, 0, 0, 0);
            s1b = __builtin_amdgcn_mfma_f32_16x16x32_bf16(qfl[1], kfh[1][1], s1b, 0, 0, 0);
            s0a = __builtin_amdgcn_mfma_f32_16x16x32_bf16(qfh[0], kfl[0][0], s0a, 0, 0, 0);
            s1a = __builtin_amdgcn_mfma_f32_16x16x32_bf16(qfh[0], kfl[1][0], s1a, 0, 0, 0);
            s0b = __builtin_amdgcn_mfma_f32_16x16x32_bf16(qfh[1], kfl[0][1], s0b, 0, 0, 0);
            s1b = __builtin_amdgcn_mfma_f32_16x16x32_bf16(qfh[1], kfl[1][1], s1b, 0, 0, 0);
            s0a = __builtin_amdgcn_mfma_f32_16x16x32_bf16(qfh[0], kfh[0][0], s0a, 0, 0, 0);
            s1a = __builtin_amdgcn_mfma_f32_16x16x32_bf16(qfh[0], kfh[1][0], s1a, 0, 0, 0);
            s0b = __builtin_amdgcn_mfma_f32_16x16x32_bf16(qfh[1], kfh[0][1], s0b, 0, 0, 0);
            s1b = __builtin_amdgcn_mfma_f32_16x16x32_bf16(qfh[1], kfh[1][1], s1b, 0, 0, 0);
            __builtin_amdgcn_s_setprio(0);
            f32x4 s0 = s0a + s0b, s1 = s1a + s1b;

            // deferred softmax: p = exp(S/8), no max subtraction, no rescale
            const int key0 = kt * 32 + l15;
            const bool m0 = (key0 >= kmax), m1 = (key0 + 16 >= kmax);
#pragma unroll
            for (int r = 0; r < 4; ++r) {
                float p0 = m0 ? 0.0f : exp2f(s0[r] * CEXP);
                float p1 = m1 ? 0.0f : exp2f(s1[r] * CEXP);
                l_i[r] += p0 + p1;
                int pr = q8 * 4 + r;
                Pl_h[wv][pr * 40 + l15] = (bf16)p0;
                Pl_h[wv][pr * 40 + 16 + l15] = (bf16)p1;
            }
            asm volatile("s_waitcnt lgkmcnt(0)" ::: "memory");   // wave-private Pl RAW
            bf16x8 pfh = *(const bf16x8*)&Pl_h[wv][l15 * 40 + q8 * 8];
            __builtin_amdgcn_s_setprio(1);
#pragma unroll
            for (int nd = 0; nd < 4; ++nd)
                oacc[nd] = __builtin_amdgcn_mfma_f32_16x16x32_bf16(pfh, vth[nd], oacc[nd], 0, 0, 0);
            __builtin_amdgcn_s_setprio(0);
        }

        write_V(nxt, vnext);                       // waits vmcnt for vnext only here
        asm volatile("s_waitcnt vmcnt(0)" ::: "memory");
        __syncthreads();
    }

    if (tile <= 12) {
#pragma unroll
        for (int r = 0; r < 4; ++r) {
            float s = l_i[r];
#pragma unroll
            for (int off = 1; off < 16; off <<= 1) s += __shfl_xor(s, off, 64);
            int qr = tile * 16 + q8 * 4 + r;
            if (qr >= 196) continue;
            float inv = 1.0f / s;
            size_t row = (size_t)b * 784 + w * 196 + qr;
#pragma unroll
            for (int nd = 0; nd < 4; ++nd) {
                float ov = oacc[nd][r] * inv;
                size_t idx = row * 768 + hh * 64 + nd * 16 + l15;
                oh_[idx] = (bf16)ov;
            }
        }
    }
}

// ---------------------------------------------------------------------------
// y = xres + p0 + p1 + b_out (fp32), y2 = LN2(y) single bf16 plane,
// dout prefill = y + b2ff. Block per x-row (3136).
// ---------------------------------------------------------------------------
__global__ __launch_bounds__(256) void ln2_resid(
    const float* __restrict__ xres, const float* __restrict__ attP,
    const float* __restrict__ bo,
    const float* __restrict__ g2, const float* __restrict__ b2,
    const float* __restrict__ b2ff,
    float* __restrict__ y, bf16* __restrict__ y2H,
    float* __restrict__ dout)
{
    const int row = blockIdx.x;
    const size_t MN = (size_t)3136 * 768;
    const float* xr = xres + (size_t)row * 768;
    const float* a0 = attP + (size_t)row * 768;
    const float* a1 = attP + MN + (size_t)row * 768;
    const int t = threadIdx.x, lane = t & 63, wv = t >> 6;
    __shared__ float red[8];

    float v[3];
    float* yr = y + (size_t)row * 768;
    float* dr = dout + (size_t)row * 768;
#pragma unroll
    for (int i = 0; i < 3; ++i) {
        int c = i * 256 + t;
        v[i] = xr[c] + a0[c] + a1[c] + bo[c];
        yr[c] = v[i];
        dr[c] = v[i] + b2ff[c];
    }
    float s = v[0] + v[1] + v[2];
    float s2 = v[0] * v[0] + v[1] * v[1] + v[2] * v[2];
#pragma unroll
    for (int off = 1; off < 64; off <<= 1) { s += __shfl_xor(s, off, 64); s2 += __shfl_xor(s2, off, 64); }
    if (lane == 0) { red[wv] = s; red[4 + wv] = s2; }
    __syncthreads();
    s = red[0] + red[1] + red[2] + red[3];
    s2 = red[4] + red[5] + red[6] + red[7];
    float mu = s * (1.0f / 768.0f);
    float var = s2 * (1.0f / 768.0f) - mu * mu;
    float rs = rsqrtf(fmaxf(var, 0.0f) + 1e-5f);

    bf16* yh = y2H + (size_t)row * 768;
#pragma unroll
    for (int i = 0; i < 3; ++i) {
        int c = i * 256 + t;
        float yv = (v[i] - mu) * rs * g2[c] + b2[c];
        yh[c] = (bf16)yv;
    }
}

// ---------------------------------------------------------------------------
extern "C" void kernel_launch(void* const* d_in, const int* in_sizes, int n_in,
                              void* d_out, int out_size, void* d_ws, size_t ws_size,
                              hipStream_t stream)
{
    (void)in_sizes; (void)n_in; (void)out_size; (void)ws_size;
    const float* x        = (const float*)d_in[0];
    const float* memory   = (const float*)d_in[1];
    const float* ln_att_g = (const float*)d_in[2];
    const float* ln_att_b = (const float*)d_in[3];
    const float* w_qkv    = (const float*)d_in[4];
    const float* w_out    = (const float*)d_in[5];
    const float* b_out    = (const float*)d_in[6];
    const float* ln1_g    = (const float*)d_in[7];
    const float* ln1_b    = (const float*)d_in[8];
    const float* ln2_g    = (const float*)d_in[9];
    const float* ln2_b    = (const float*)d_in[10];
    const float* w1       = (const float*)d_in[11];
    const float* b1       = (const float*)d_in[12];
    const float* w2       = (const float*)d_in[13];
    const float* b2       = (const float*)d_in[14];

    // ---- workspace layout (~109.7 MiB footprint kept) ----
    char* ws = (char*)d_ws;
    const size_t SZF  = (size_t)3136 * 768 * 4;
    const size_t SZP  = (size_t)3136 * 768 * 2;
    const size_t SZHP = (size_t)6272 * 768 * 2;
    const size_t SZQP = (size_t)6272 * 2304 * 2;
    const size_t SZFP = (size_t)3136 * 3072 * 2;

    float* xres = (float*)(ws);
    bf16* hH  = (bf16*)(ws + SZF);
    bf16* aoH = (bf16*)(ws + SZF);
    bf16* y2H = (bf16*)(ws + SZF);
    const size_t OQ = SZF + 2 * SZHP;
    bf16* qkvH = (bf16*)(ws + OQ);
    bf16* qkvL = (bf16*)(ws + OQ + SZQP);
    float* y    = (float*)(ws + OQ);
    float* attP = (float*)(ws + OQ + SZF);   // 2 partials (dead qkv region; ffH overwrites later)
    bf16* ffH  = (bf16*)(ws + OQ + SZF);
    const size_t OW = OQ + 2 * SZQP;
    bf16* wqH = (bf16*)(ws + OW);
    bf16* wqL = (bf16*)(ws + OW + 3538944);
    bf16* woH = (bf16*)(ws + OW + 2 * 3538944);
    bf16* woL = (bf16*)(ws + OW + 2 * 3538944 + 1179648);
    bf16* w1H = (bf16*)(ws + OW + 2 * 3538944 + 2 * 1179648);
    bf16* w1L = (bf16*)(ws + OW + 2 * 3538944 + 2 * 1179648 + 4718592);
    bf16* w2H = (bf16*)(ws + OW + 2 * 3538944 + 2 * 1179648 + 2 * 4718592);
    bf16* w2L = (bf16*)(ws + OW + 2 * 3538944 + 2 * 1179648 + 3 * 4718592);

    // NOTE: aoH shares region with hH (hH dead after qkv GEMM);
    //       y2H shares region too (aoH dead after w_out GEMM). Same as before,
    //       where aoH/y2H aliased the same base.

    // 0+1) fused: LN1 + LN_att hi-plane (6272 blocks) and weight splits (2048 blocks)
    prep_ln_split<<<8320, 256, 0, stream>>>(x, memory, ln1_g, ln1_b, ln_att_g, ln_att_b,
                                            xres, hH,
                                            w_qkv, wqH, wqL, w_out, woH, woL,
                                            w1, w1H, w1L, w2, w2H, w2L);

    // 2) qkv planes = h_hi @ (w_qkv_hi + w_qkv_lo)^T  (M=6272, N=2304, K=768)
    gemm_qkv<<<dim3(18, 25), 256, 0, stream>>>(hH, wqH, wqL, 6272, 2304, 768,
                                               qkvH, qkvL);

    // 3) attention  (grid: x = hh+12*b, y = w*4+g  -> XCD-local K/V sharing)
    attn_kernel<<<dim3(48, 16), 256, 0, stream>>>(qkvH, qkvL, aoH);

    // 4) att partials = ao_hi @ (w_out_hi + w_out_lo)^T  (split-K=2) — row-chunked
    gemm_pl<1, 0><<<dim3(6, 25, 2), 256, 0, stream>>>(aoH, woH, woL, 3136, 768, 768,
                                                      nullptr, attP, nullptr);

    // 5) y = xres + p0 + p1 + b_out ; y2_hi = LN2(y) ; dout prefill = y + b2
    ln2_resid<<<3136, 256, 0, stream>>>(xres, attP, b_out, ln2_g, ln2_b, b2,
                                        y, y2H, (float*)d_out);

    // 6) ff_hi = silu(y2_hi @ (w1_hi + w1_lo)^T + b1)  — col-chunked (w1-heavy)
    gemm_pl<2, 1><<<dim3(24, 25), 256, 0, stream>>>(y2H, w1H, w1L, 3136, 3072, 768,
                                                    b1, nullptr, ffH);

    // 7) d_out += ff_hi @ (w2_hi + w2_lo)^T  (split-K=4, atomic) — row-chunked
    gemm_pl<3, 0><<<dim3(6, 25, 4), 256, 0, stream>>>(ffH, w2H, w2L, 3136, 768, 3072,
                                                      nullptr, (float*)d_out, nullptr);
}

// Round 12
// 364.697 us; speedup vs baseline: 1.4661x; 1.0295x over previous
//
#include <hip/hip_runtime.h>
#include <cstdint>

typedef __bf16 bf16;
typedef __bf16 bf16x4 __attribute__((ext_vector_type(4)));
typedef __bf16 bf16x8 __attribute__((ext_vector_type(8)));
typedef float f32x4 __attribute__((ext_vector_type(4)));

#define AS1 __attribute__((address_space(1)))
#define AS3 __attribute__((address_space(3)))

// Async global->LDS, 16B per lane. LDS dest must be wave-uniform base;
// HW writes lane i at base + i*16 (m97/m104 semantics).
__device__ __forceinline__ void load16_lds(const void* gp, void* lds_base_wave_uniform) {
    __builtin_amdgcn_global_load_lds((AS1 void*)((void*)gp),
                                     (AS3 void*)lds_base_wave_uniform, 16, 0, 0);
}

// ---------------------------------------------------------------------------
// Fused: LN1 -> xres + LN_att -> h hi plane (blocks 0..6271), and all 4
// weight plane-splits (blocks 6272..8319, grid-stride float4).
// 2-term scheme everywhere: activations single bf16 plane, weights hi+lo.
// ---------------------------------------------------------------------------
__global__ __launch_bounds__(256) void prep_ln_split(
    const float* __restrict__ x, const float* __restrict__ memory,
    const float* __restrict__ g1, const float* __restrict__ b1,
    const float* __restrict__ ga, const float* __restrict__ ba,
    float* __restrict__ xres, bf16* __restrict__ hH,
    const float* __restrict__ wp0, bf16* __restrict__ wh0, bf16* __restrict__ wl0,
    const float* __restrict__ wp1, bf16* __restrict__ wh1, bf16* __restrict__ wl1,
    const float* __restrict__ wp2, bf16* __restrict__ wh2, bf16* __restrict__ wl2,
    const float* __restrict__ wp3, bf16* __restrict__ wh3, bf16* __restrict__ wl3)
{
    const int t = threadIdx.x;
    if (blockIdx.x >= 6272) {
        // ---- weight split path (2048 blocks, grid-stride) ----
        const int n0q = 442368, n1q = 147456, n2q = 589824;
        const int total = 1769472;
        const int stride = 2048 * 256;
        for (int i = (blockIdx.x - 6272) * 256 + t; i < total; i += stride) {
            const float* sp; bf16 *hp, *lp; int j = i;
            if (j < n0q) { sp = wp0; hp = wh0; lp = wl0; }
            else if ((j -= n0q) < n1q) { sp = wp1; hp = wh1; lp = wl1; }
            else if ((j -= n1q) < n2q) { sp = wp2; hp = wh2; lp = wl2; }
            else { j -= n2q; sp = wp3; hp = wh3; lp = wl3; }
            float4 v4 = reinterpret_cast<const float4*>(sp)[j];
            bf16x4 hi, lo;
            hi[0] = (bf16)v4.x; lo[0] = (bf16)(v4.x - (float)hi[0]);
            hi[1] = (bf16)v4.y; lo[1] = (bf16)(v4.y - (float)hi[1]);
            hi[2] = (bf16)v4.z; lo[2] = (bf16)(v4.z - (float)hi[2]);
            hi[3] = (bf16)v4.w; lo[3] = (bf16)(v4.w - (float)hi[3]);
            reinterpret_cast<bf16x4*>(hp)[j] = hi;
            reinterpret_cast<bf16x4*>(lp)[j] = lo;
        }
        return;
    }

    // ---- LN path ----
    const int row = blockIdx.x;            // 0..6271
    const int b = row / 1568, l = row - b * 1568;
    const float* src = (l < 784) ? (memory + ((size_t)b * 1024 + l) * 768)
                                 : (x + ((size_t)b * 784 + (l - 784)) * 768);
    const int lane = t & 63, wv = t >> 6;
    __shared__ float red[8];

    float v[3];
#pragma unroll
    for (int i = 0; i < 3; ++i) v[i] = src[i * 256 + t];

    float s = v[0] + v[1] + v[2];
    float s2 = v[0] * v[0] + v[1] * v[1] + v[2] * v[2];
#pragma unroll
    for (int off = 1; off < 64; off <<= 1) { s += __shfl_xor(s, off, 64); s2 += __shfl_xor(s2, off, 64); }
    if (lane == 0) { red[wv] = s; red[4 + wv] = s2; }
    __syncthreads();
    s = red[0] + red[1] + red[2] + red[3];
    s2 = red[4] + red[5] + red[6] + red[7];
    float mu = s * (1.0f / 768.0f);
    float var = s2 * (1.0f / 768.0f) - mu * mu;
    float rs = rsqrtf(fmaxf(var, 0.0f) + 1e-5f);

    float w[3];
#pragma unroll
    for (int i = 0; i < 3; ++i) {
        int c = i * 256 + t;
        w[i] = (v[i] - mu) * rs * g1[c] + b1[c];
    }
    if (l >= 784) {
        float* xr = xres + ((size_t)b * 784 + (l - 784)) * 768;
#pragma unroll
        for (int i = 0; i < 3; ++i) xr[i * 256 + t] = w[i];
    }

    s = w[0] + w[1] + w[2];
    s2 = w[0] * w[0] + w[1] * w[1] + w[2] * w[2];
#pragma unroll
    for (int off = 1; off < 64; off <<= 1) { s += __shfl_xor(s, off, 64); s2 += __shfl_xor(s2, off, 64); }
    __syncthreads();
    if (lane == 0) { red[wv] = s; red[4 + wv] = s2; }
    __syncthreads();
    s = red[0] + red[1] + red[2] + red[3];
    s2 = red[4] + red[5] + red[6] + red[7];
    float mu2 = s * (1.0f / 768.0f);
    float var2 = s2 * (1.0f / 768.0f) - mu2 * mu2;
    float rs2 = rsqrtf(fmaxf(var2, 0.0f) + 1e-5f);

    bf16* hh_ = hH + (size_t)row * 768;
#pragma unroll
    for (int i = 0; i < 3; ++i) {
        int c = i * 256 + t;
        float hv = (w[i] - mu2) * rs2 * ga[c] + ba[c];
        hh_[c] = (bf16)hv;
    }
}

// ---------------------------------------------------------------------------
// QKV GEMM, 256x128 tile, m97 single-buffer schedule, involution staging,
// bijective XCD row-chunking. 2-term: qkv = h_hi * (W_hi + W_lo).
// lo-plane output only for Q cols (<768): K is single-plane in attn (R12),
// V was already single-plane.
// ---------------------------------------------------------------------------
__global__ __launch_bounds__(256, 2) void gemm_qkv(
    const bf16* __restrict__ Ah,
    const bf16* __restrict__ Bh, const bf16* __restrict__ Bl,
    int M, int N, int K,
    bf16* __restrict__ Ch, bf16* __restrict__ Cl)
{
    __shared__ __align__(16) bf16 Ahs[256 * 32];
    __shared__ __align__(16) bf16 Bhs[128 * 32], Bls[128 * 32];
    const int t = threadIdx.x, lane = t & 63, wv = t >> 6;

    // bijective XCD chunking (m204), row-chunk order
    const int nx = gridDim.x, ny = gridDim.y;
    int orig = blockIdx.x + nx * blockIdx.y;
    int nwg = nx * ny;
    int q = nwg >> 3, rr8 = nwg & 7;
    int xcd = orig & 7, pos = orig >> 3;
    int wgid = (xcd < rr8 ? xcd * (q + 1) : rr8 * (q + 1) + (xcd - rr8) * q) + pos;
    int bx = wgid % nx, by = wgid / nx;

    const int row0 = by * 256, col0 = bx * 128;
    const int ro = (wv >> 1) * 128, co = (wv & 1) * 64;
    const int l15 = lane & 15, q8 = lane >> 4;
    const int cs = (q8 ^ (l15 & 3)) * 8;     // involution chunk for fragment reads

    f32x4 acc[8][4] = {};

    for (int k0 = 0; k0 < K; k0 += 32) {
#pragma unroll
        for (int it = 0; it < 4; ++it) {              // A-hi: 256 rows
            int f = it * 256 + t;
            int r = f >> 2;
            int kc = ((f & 3) ^ (r & 3)) * 8;
            int ra = row0 + r; if (ra >= M) ra = M - 1;
            size_t oa = (size_t)ra * K + k0 + kc;
            size_t lb = (size_t)(it * 256 + wv * 64) * 8;
            load16_lds(Ah + oa, Ahs + lb);
        }
#pragma unroll
        for (int it = 0; it < 2; ++it) {              // B hi+lo: 128 rows
            int f = it * 256 + t;
            int r = f >> 2;
            int kc = ((f & 3) ^ (r & 3)) * 8;
            size_t ob = (size_t)(col0 + r) * K + k0 + kc;
            size_t lb = (size_t)(it * 256 + wv * 64) * 8;
            load16_lds(Bh + ob, Bhs + lb);
            load16_lds(Bl + ob, Bls + lb);
        }
        asm volatile("s_waitcnt vmcnt(0)" ::: "memory");
        __syncthreads();

        bf16x8 bh[4], bl[4];
#pragma unroll
        for (int j = 0; j < 4; ++j) {
            int o = (co + j * 16 + l15) * 32 + cs;
            bh[j] = *(const bf16x8*)&Bhs[o];
            bl[j] = *(const bf16x8*)&Bls[o];
        }
#pragma unroll
        for (int i = 0; i < 8; ++i) {
            int o = (ro + i * 16 + l15) * 32 + cs;
            bf16x8 ah = *(const bf16x8*)&Ahs[o];
#pragma unroll
            for (int j = 0; j < 4; ++j) {
                acc[i][j] = __builtin_amdgcn_mfma_f32_16x16x32_bf16(ah, bl[j], acc[i][j], 0, 0, 0);
                acc[i][j] = __builtin_amdgcn_mfma_f32_16x16x32_bf16(ah, bh[j], acc[i][j], 0, 0, 0);
            }
        }
        __syncthreads();
    }

#pragma unroll
    for (int i = 0; i < 8; ++i)
#pragma unroll
        for (int j = 0; j < 4; ++j)
#pragma unroll
            for (int r = 0; r < 4; ++r) {
                int row = row0 + ro + i * 16 + q8 * 4 + r;
                int col = col0 + co + j * 16 + l15;
                if (row >= M) continue;
                float v = acc[i][j][r];
                size_t idx = (size_t)row * N + col;
                bf16 hh = (bf16)v;
                Ch[idx] = hh;
                if (col < 768) Cl[idx] = (bf16)(v - (float)hh);  // Q-lo only
            }
}

// ---------------------------------------------------------------------------
// Plane GEMM, 2-term scheme: C = A_hi * (B_hi + B_lo)^T.
// m97 single-buffer schedule + involution staging + XCD chunking.
// 128x128 tile, BK=32, 4 waves x 64x64. Split-K via gridDim.z.
// MODE 1: fp32 partial -> Cf + z*M*N. 2: silu -> single bf16 plane Ch.
// 3: atomic fp32 += into prefilled Cf.
// ---------------------------------------------------------------------------
template <int MODE, int ORD>
__global__ __launch_bounds__(256, 2) void gemm_pl(
    const bf16* __restrict__ Ah,
    const bf16* __restrict__ Bh, const bf16* __restrict__ Bl,
    int M, int N, int K,
    const float* __restrict__ bias,
    float* __restrict__ Cf, bf16* __restrict__ Ch)
{
    __shared__ __align__(16) bf16 Ahs[128 * 32];
    __shared__ __align__(16) bf16 Bhs[128 * 32], Bls[128 * 32];
    const int t = threadIdx.x, lane = t & 63, wv = t >> 6;

    // ---- bijective XCD chunking (m204) ----
    const int nx = gridDim.x, ny = gridDim.y;
    int orig = blockIdx.x + nx * blockIdx.y;
    int nwg = nx * ny;
    int q = nwg >> 3, rr8 = nwg & 7;
    int xcd = orig & 7, pos = orig >> 3;
    int wgid = (xcd < rr8 ? xcd * (q + 1) : rr8 * (q + 1) + (xcd - rr8) * q) + pos;
    int bx, by;
    if (ORD == 0) { bx = wgid % nx; by = wgid / nx; }   // row chunks (A-heavy)
    else          { by = wgid % ny; bx = wgid / ny; }   // col chunks (B-heavy)

    const int row0 = by * 128, col0 = bx * 128;
    const int ro = (wv >> 1) * 64, co = (wv & 1) * 64;
    const int Kc = K / gridDim.z;
    const int kbeg = blockIdx.z * Kc, kend = kbeg + Kc;
    const int l15 = lane & 15, q8 = lane >> 4;
    const int cs = (q8 ^ (l15 & 3)) * 8;     // involution chunk for fragment reads

    f32x4 acc[4][4] = {};

    for (int k0 = kbeg; k0 < kend; k0 += 32) {
#pragma unroll
        for (int it = 0; it < 2; ++it) {
            int f = it * 256 + t;
            int r = f >> 2;                          // tile row (4 lanes per row)
            int kc = ((f & 3) ^ (r & 3)) * 8;        // involution within 64B line
            int ra = row0 + r; if (ra >= M) ra = M - 1;
            size_t oa = (size_t)ra * K + k0 + kc;
            size_t ob = (size_t)(col0 + r) * K + k0 + kc;
            size_t lb = (size_t)(it * 256 + wv * 64) * 8;
            load16_lds(Ah + oa, Ahs + lb);
            load16_lds(Bh + ob, Bhs + lb);
            load16_lds(Bl + ob, Bls + lb);
        }
        asm volatile("s_waitcnt vmcnt(0)" ::: "memory");
        __syncthreads();
        bf16x8 ah[4], bh[4], bl[4];
#pragma unroll
        for (int i = 0; i < 4; ++i) {
            int o = (ro + i * 16 + l15) * 32 + cs;   // (row&3)==(l15&3)
            ah[i] = *(const bf16x8*)&Ahs[o];
        }
#pragma unroll
        for (int j = 0; j < 4; ++j) {
            int o = (co + j * 16 + l15) * 32 + cs;
            bh[j] = *(const bf16x8*)&Bhs[o];
            bl[j] = *(const bf16x8*)&Bls[o];
        }
#pragma unroll
        for (int i = 0; i < 4; ++i)
#pragma unroll
            for (int j = 0; j < 4; ++j) {
                acc[i][j] = __builtin_amdgcn_mfma_f32_16x16x32_bf16(ah[i], bl[j], acc[i][j], 0, 0, 0);
                acc[i][j] = __builtin_amdgcn_mfma_f32_16x16x32_bf16(ah[i], bh[j], acc[i][j], 0, 0, 0);
            }
        __syncthreads();
    }

    const size_t zoff = (size_t)blockIdx.z * M * N;
#pragma unroll
    for (int i = 0; i < 4; ++i)
#pragma unroll
        for (int j = 0; j < 4; ++j)
#pragma unroll
            for (int r = 0; r < 4; ++r) {
                int row = row0 + ro + i * 16 + (lane >> 4) * 4 + r;
                int col = col0 + co + j * 16 + (lane & 15);
                if (row >= M) continue;
                float v = acc[i][j][r];
                size_t idx = (size_t)row * N + col;
                if (MODE == 1) {
                    Cf[zoff + idx] = v;               // partial, bias added later
                } else if (MODE == 2) {
                    v += bias[col];
                    v = v / (1.0f + __expf(-v));
                    Ch[idx] = (bf16)v;                // single plane
                } else {
                    unsafeAtomicAdd(&Cf[idx], v);     // HW f32 atomic, prefilled dest
                }
            }
}

// ---------------------------------------------------------------------------
// Flash attention, pipelined. Grid: x = hh + 12*b (48), y = w*4+g (16).
// Deferred softmax, single barrier per K-tile, swizzled K via pre-swizzled
// global_load_lds source, V reg-prefetch + 2-way-bank transposed write,
// setprio around MFMA clusters. R12: K single-plane (S = (q_hi+q_lo)*k_hi,
// error ~0.001 on logits — validated class) -> 2 staging loads, 8 LDS reads,
// 12 MFMA per iter; LDS 31.7 -> 23.5 KB.
// ---------------------------------------------------------------------------
__global__ __launch_bounds__(256, 3) void attn_kernel(
    const bf16* __restrict__ qh_, const bf16* __restrict__ ql_,
    bf16* __restrict__ oh_)
{
    const int hh = blockIdx.x % 12, b = blockIdx.x / 12;
    const int w = blockIdx.y >> 2, g = blockIdx.y & 3;
    const int kmax = (5 + w) * 196, nkt = (kmax + 31) / 32;
    const int t = threadIdx.x, lane = t & 63, wv = t >> 6;
    const int tile = g * 4 + wv;                  // 0..15; >12 idle (wave-uniform)
    const int l15 = lane & 15, q8 = lane >> 4;

    __shared__ __align__(16) bf16 Ks_h[2][32 * 64];
    __shared__ __align__(16) bf16 Vt_h[2][64 * 40];
    __shared__ __align__(16) bf16 Pl_h[4][16 * 40];

    const size_t bbase = (size_t)b * 1568 * 2304;

    // staging geometry: thread t covers K/V row srow, col chunk sc8.
    const int srow = t >> 3;                      // 0..31 (wave wv: rows wv*8..+7)
    const int sc8 = (t & 7) * 8;
    // K: LDS dest is linear (global_load_lds), so pre-swizzle the SOURCE col.
    const int scsrc = sc8 ^ ((srow & 7) * 8);

    // Q fragments (held in registers for the whole kernel)
    int tcl = tile > 12 ? 12 : tile;
    int qr0 = tcl * 16 + l15; if (qr0 > 195) qr0 = 195;
    const size_t qoff = bbase + (size_t)(784 + w * 196 + qr0) * 2304 + hh * 64 + q8 * 8;
    bf16x8 qfh[2], qfl[2];
#pragma unroll
    for (int p = 0; p < 2; ++p) {
        qfh[p] = *(const bf16x8*)(qh_ + qoff + p * 32);
        qfl[p] = *(const bf16x8*)(ql_ + qoff + p * 32);
    }

    float l_i[4] = {0.f, 0.f, 0.f, 0.f};
    f32x4 oacc[4];
#pragma unroll
    for (int nd = 0; nd < 4; ++nd) oacc[nd] = f32x4{0.f, 0.f, 0.f, 0.f};

    // issue staging for K-tile kt2 into buffer bufn; V -> vreg (not yet in LDS)
    auto stage_issue = [&](int kt2, int bufn, bf16x8& vreg) {
        const size_t kb = bbase + (size_t)(kt2 * 32 + srow) * 2304 + 768 + (size_t)hh * 64;
        load16_lds(qh_ + kb + scsrc, &Ks_h[bufn][wv * 512]);
        vreg = *(const bf16x8*)(qh_ + kb + 768 + sc8);
    };
    // transposed V write, key-XOR swizzled (2-way banks instead of 16-way)
    auto write_V = [&](int bufn, const bf16x8& vreg) {
#pragma unroll
        for (int j = 0; j < 8; ++j) {
            int d = sc8 + j;
            int keyx = srow ^ (((d >> 3) & 3) * 8);
            Vt_h[bufn][d * 40 + keyx] = vreg[j];
        }
    };

    // ---- prologue: stage tile 0 into buffer 0
    {
        bf16x8 v0;
        stage_issue(0, 0, v0);
        write_V(0, v0);                            // data dep inserts vmcnt wait
        asm volatile("s_waitcnt vmcnt(0)" ::: "memory");
        __syncthreads();
    }

    const float CEXP = 0.18033688011112042f;       // 0.125 * log2(e)

    for (int kt = 0; kt < nkt; ++kt) {
        const int cur = kt & 1, nxt = cur ^ 1;
        int kt2 = kt + 1; if (kt2 >= nkt) kt2 = nkt - 1;   // clamp (no OOB)
        bf16x8 vnext;
        stage_issue(kt2, nxt, vnext);              // overlaps with compute below

        if (tile <= 12) {
            bf16x8 kfh[2][2], vth[4];
#pragma unroll
            for (int nb = 0; nb < 2; ++nb)
#pragma unroll
                for (int p = 0; p < 2; ++p) {
                    int row = nb * 16 + l15;
                    int c = (p * 32 + q8 * 8) ^ ((row & 7) * 8);
                    kfh[nb][p] = *(const bf16x8*)&Ks_h[cur][row * 64 + c];
                }
#pragma unroll
            for (int nd = 0; nd < 4; ++nd) {
                int d = nd * 16 + l15;
                int k8 = (q8 * 8) ^ (((d >> 3) & 3) * 8);
                vth[nd] = *(const bf16x8*)&Vt_h[cur][d * 40 + k8];
            }

            // QK^T: S = (q_hi + q_lo) * k_hi — 4 independent depth-2 chains
            f32x4 s0a = {0.f,0.f,0.f,0.f}, s0b = {0.f,0.f,0.f,0.f};
            f32x4 s1a = {0.f,0.f,0.f,0.f}, s1b = {0.f,0.f,0.f,0.f};
            __builtin_amdgcn_s_setprio(1);
            s0a = __builtin_amdgcn_mfma_f32_16x16x32_bf16(qfl[0], kfh[0][0], s0a, 0, 0, 0);
            s1a = __builtin_amdgcn_mfma_f32_16x16x32_bf16(qfl[0], kfh[1][0], s1a, 0, 0, 0);
            s0b = __builtin_amdgcn_mfma_f32_16x16x32_bf16(qfl[1], kfh[0][1], s0b, 0, 0, 0);
            s1b = __builtin_amdgcn_mfma_f32_16x16x32_bf16(qfl[1], kfh[1][1], s1b, 0, 0, 0);
            s0a = __builtin_amdgcn_mfma_f32_16x16x32_bf16(qfh[0], kfh[0][0], s0a, 0, 0, 0);
            s1a = __builtin_amdgcn_mfma_f32_16x16x32_bf16(qfh[0], kfh[1][0], s1a, 0, 0, 0);
            s0b = __builtin_amdgcn_mfma_f32_16x16x32_bf16(qfh[1], kfh[0][1], s0b, 0, 0, 0);
            s1b = __builtin_amdgcn_mfma_f32_16x16x32_bf16(qfh[1], kfh[1][1], s1b, 0, 0, 0);
            __builtin_amdgcn_s_setprio(0);
            f32x4 s0 = s0a + s0b, s1 = s1a + s1b;

            // deferred softmax: p = exp(S/8), no max subtraction, no rescale
            const int key0 = kt * 32 + l15;
            const bool m0 = (key0 >= kmax), m1 = (key0 + 16 >= kmax);
#pragma unroll
            for (int r = 0; r < 4; ++r) {
                float p0 = m0 ? 0.0f : exp2f(s0[r] * CEXP);
                float p1 = m1 ? 0.0f : exp2f(s1[r] * CEXP);
                l_i[r] += p0 + p1;
                int pr = q8 * 4 + r;
                Pl_h[wv][pr * 40 + l15] = (bf16)p0;
                Pl_h[wv][pr * 40 + 16 + l15] = (bf16)p1;
            }
            asm volatile("s_waitcnt lgkmcnt(0)" ::: "memory");   // wave-private Pl RAW
            bf16x8 pfh = *(const bf16x8*)&Pl_h[wv][l15 * 40 + q8 * 8];
            __builtin_amdgcn_s_setprio(1);
#pragma unroll
            for (int nd = 0; nd < 4; ++nd)
                oacc[nd] = __builtin_amdgcn_mfma_f32_16x16x32_bf16(pfh, vth[nd], oacc[nd], 0, 0, 0);
            __builtin_amdgcn_s_setprio(0);
        }

        write_V(nxt, vnext);                       // waits vmcnt for vnext only here
        asm volatile("s_waitcnt vmcnt(0)" ::: "memory");
        __syncthreads();
    }

    if (tile <= 12) {
#pragma unroll
        for (int r = 0; r < 4; ++r) {
            float s = l_i[r];
#pragma unroll
            for (int off = 1; off < 16; off <<= 1) s += __shfl_xor(s, off, 64);
            int qr = tile * 16 + q8 * 4 + r;
            if (qr >= 196) continue;
            float inv = 1.0f / s;
            size_t row = (size_t)b * 784 + w * 196 + qr;
#pragma unroll
            for (int nd = 0; nd < 4; ++nd) {
                float ov = oacc[nd][r] * inv;
                size_t idx = row * 768 + hh * 64 + nd * 16 + l15;
                oh_[idx] = (bf16)ov;
            }
        }
    }
}

// ---------------------------------------------------------------------------
// y = xres + p0 + p1 + b_out (fp32), y2 = LN2(y) single bf16 plane,
// dout prefill = y + b2ff. Block per x-row (3136).
// ---------------------------------------------------------------------------
__global__ __launch_bounds__(256) void ln2_resid(
    const float* __restrict__ xres, const float* __restrict__ attP,
    const float* __restrict__ bo,
    const float* __restrict__ g2, const float* __restrict__ b2,
    const float* __restrict__ b2ff,
    float* __restrict__ y, bf16* __restrict__ y2H,
    float* __restrict__ dout)
{
    const int row = blockIdx.x;
    const size_t MN = (size_t)3136 * 768;
    const float* xr = xres + (size_t)row * 768;
    const float* a0 = attP + (size_t)row * 768;
    const float* a1 = attP + MN + (size_t)row * 768;
    const int t = threadIdx.x, lane = t & 63, wv = t >> 6;
    __shared__ float red[8];

    float v[3];
    float* yr = y + (size_t)row * 768;
    float* dr = dout + (size_t)row * 768;
#pragma unroll
    for (int i = 0; i < 3; ++i) {
        int c = i * 256 + t;
        v[i] = xr[c] + a0[c] + a1[c] + bo[c];
        yr[c] = v[i];
        dr[c] = v[i] + b2ff[c];
    }
    float s = v[0] + v[1] + v[2];
    float s2 = v[0] * v[0] + v[1] * v[1] + v[2] * v[2];
#pragma unroll
    for (int off = 1; off < 64; off <<= 1) { s += __shfl_xor(s, off, 64); s2 += __shfl_xor(s2, off, 64); }
    if (lane == 0) { red[wv] = s; red[4 + wv] = s2; }
    __syncthreads();
    s = red[0] + red[1] + red[2] + red[3];
    s2 = red[4] + red[5] + red[6] + red[7];
    float mu = s * (1.0f / 768.0f);
    float var = s2 * (1.0f / 768.0f) - mu * mu;
    float rs = rsqrtf(fmaxf(var, 0.0f) + 1e-5f);

    bf16* yh = y2H + (size_t)row * 768;
#pragma unroll
    for (int i = 0; i < 3; ++i) {
        int c = i * 256 + t;
        float yv = (v[i] - mu) * rs * g2[c] + b2[c];
        yh[c] = (bf16)yv;
    }
}

// ---------------------------------------------------------------------------
extern "C" void kernel_launch(void* const* d_in, const int* in_sizes, int n_in,
                              void* d_out, int out_size, void* d_ws, size_t ws_size,
                              hipStream_t stream)
{
    (void)in_sizes; (void)n_in; (void)out_size; (void)ws_size;
    const float* x        = (const float*)d_in[0];
    const float* memory   = (const float*)d_in[1];
    const float* ln_att_g = (const float*)d_in[2];
    const float* ln_att_b = (const float*)d_in[3];
    const float* w_qkv    = (const float*)d_in[4];
    const float* w_out    = (const float*)d_in[5];
    const float* b_out    = (const float*)d_in[6];
    const float* ln1_g    = (const float*)d_in[7];
    const float* ln1_b    = (const float*)d_in[8];
    const float* ln2_g    = (const float*)d_in[9];
    const float* ln2_b    = (const float*)d_in[10];
    const float* w1       = (const float*)d_in[11];
    const float* b1       = (const float*)d_in[12];
    const float* w2       = (const float*)d_in[13];
    const float* b2       = (const float*)d_in[14];

    // ---- workspace layout (~109.7 MiB footprint kept) ----
    char* ws = (char*)d_ws;
    const size_t SZF  = (size_t)3136 * 768 * 4;
    const size_t SZP  = (size_t)3136 * 768 * 2;
    const size_t SZHP = (size_t)6272 * 768 * 2;
    const size_t SZQP = (size_t)6272 * 2304 * 2;
    const size_t SZFP = (size_t)3136 * 3072 * 2;

    float* xres = (float*)(ws);
    bf16* hH  = (bf16*)(ws + SZF);
    bf16* aoH = (bf16*)(ws + SZF);
    bf16* y2H = (bf16*)(ws + SZF);
    const size_t OQ = SZF + 2 * SZHP;
    bf16* qkvH = (bf16*)(ws + OQ);
    bf16* qkvL = (bf16*)(ws + OQ + SZQP);
    float* y    = (float*)(ws + OQ);
    float* attP = (float*)(ws + OQ + SZF);   // 2 partials (dead qkv region; ffH overwrites later)
    bf16* ffH  = (bf16*)(ws + OQ + SZF);
    const size_t OW = OQ + 2 * SZQP;
    bf16* wqH = (bf16*)(ws + OW);
    bf16* wqL = (bf16*)(ws + OW + 3538944);
    bf16* woH = (bf16*)(ws + OW + 2 * 3538944);
    bf16* woL = (bf16*)(ws + OW + 2 * 3538944 + 1179648);
    bf16* w1H = (bf16*)(ws + OW + 2 * 3538944 + 2 * 1179648);
    bf16* w1L = (bf16*)(ws + OW + 2 * 3538944 + 2 * 1179648 + 4718592);
    bf16* w2H = (bf16*)(ws + OW + 2 * 3538944 + 2 * 1179648 + 2 * 4718592);
    bf16* w2L = (bf16*)(ws + OW + 2 * 3538944 + 2 * 1179648 + 3 * 4718592);

    // 0+1) fused: LN1 + LN_att hi-plane (6272 blocks) and weight splits (2048 blocks)
    prep_ln_split<<<8320, 256, 0, stream>>>(x, memory, ln1_g, ln1_b, ln_att_g, ln_att_b,
                                            xres, hH,
                                            w_qkv, wqH, wqL, w_out, woH, woL,
                                            w1, w1H, w1L, w2, w2H, w2L);

    // 2) qkv = h_hi @ (w_qkv_hi + w_qkv_lo)^T  (M=6272, N=2304, K=768)
    gemm_qkv<<<dim3(18, 25), 256, 0, stream>>>(hH, wqH, wqL, 6272, 2304, 768,
                                               qkvH, qkvL);

    // 3) attention  (grid: x = hh+12*b, y = w*4+g  -> XCD-local K/V sharing)
    attn_kernel<<<dim3(48, 16), 256, 0, stream>>>(qkvH, qkvL, aoH);

    // 4) att partials = ao_hi @ (w_out_hi + w_out_lo)^T  (split-K=2) — row-chunked
    gemm_pl<1, 0><<<dim3(6, 25, 2), 256, 0, stream>>>(aoH, woH, woL, 3136, 768, 768,
                                                      nullptr, attP, nullptr);

    // 5) y = xres + p0 + p1 + b_out ; y2_hi = LN2(y) ; dout prefill = y + b2
    ln2_resid<<<3136, 256, 0, stream>>>(xres, attP, b_out, ln2_g, ln2_b, b2,
                                        y, y2H, (float*)d_out);

    // 6) ff_hi = silu(y2_hi @ (w1_hi + w1_lo)^T + b1)  — col-chunked (w1-heavy)
    gemm_pl<2, 1><<<dim3(24, 25), 256, 0, stream>>>(y2H, w1H, w1L, 3136, 3072, 768,
                                                    b1, nullptr, ffH);

    // 7) d_out += ff_hi @ (w2_hi + w2_lo)^T  (split-K=4, atomic) — row-chunked
    gemm_pl<3, 0><<<dim3(6, 25, 4), 256, 0, stream>>>(ffH, w2H, w2L, 3136, 768, 3072,
                                                      nullptr, (float*)d_out, nullptr);
}